// Round 1
// baseline (1576.728 us; speedup 1.0000x reference)
//
#include <hip/hip_runtime.h>
#include <math.h>

#define SCAN_B 1024

static inline int ceil_div_i(long long a, int b) { return (int)((a + b - 1) / b); }

// ---------------- CSR construction ----------------

__global__ __launch_bounds__(256) void k_count(const int* __restrict__ dst, int E,
                                               int* __restrict__ cnt) {
    int i = blockIdx.x * blockDim.x + threadIdx.x;
    if (i < E) atomicAdd(&cnt[dst[i]], 1);
}

__global__ __launch_bounds__(256) void k_dinv(const int* __restrict__ cnt,
                                              float* __restrict__ dinv, int N) {
    int i = blockIdx.x * blockDim.x + threadIdx.x;
    if (i < N) dinv[i] = (float)(1.0 / sqrt((double)(cnt[i] + 1)));
}

// block-level exclusive scan: 256 threads x 4 elements = 1024 per block
__global__ __launch_bounds__(256) void k_scan1(const int* __restrict__ cnt,
                                               int* __restrict__ rowptr,
                                               int* __restrict__ bsum, int N) {
    __shared__ int s[256];
    int tid = threadIdx.x;
    int base = blockIdx.x * SCAN_B + tid * 4;
    int a0 = (base + 0 < N) ? cnt[base + 0] : 0;
    int a1 = (base + 1 < N) ? cnt[base + 1] : 0;
    int a2 = (base + 2 < N) ? cnt[base + 2] : 0;
    int a3 = (base + 3 < N) ? cnt[base + 3] : 0;
    int tsum = a0 + a1 + a2 + a3;
    s[tid] = tsum;
    __syncthreads();
    for (int off = 1; off < 256; off <<= 1) {
        int val = 0;
        if (tid >= off) val = s[tid - off];
        __syncthreads();
        if (tid >= off) s[tid] += val;
        __syncthreads();
    }
    int texcl = s[tid] - tsum;
    if (tid == 255) bsum[blockIdx.x] = s[255];
    if (base + 0 < N) rowptr[base + 0] = texcl;
    if (base + 1 < N) rowptr[base + 1] = texcl + a0;
    if (base + 2 < N) rowptr[base + 2] = texcl + a0 + a1;
    if (base + 3 < N) rowptr[base + 3] = texcl + a0 + a1 + a2;
}

// single-block exclusive scan of block sums (NB <= 256)
__global__ __launch_bounds__(256) void k_scan2(int* __restrict__ bsum, int NB) {
    __shared__ int s[256];
    int tid = threadIdx.x;
    int v = (tid < NB) ? bsum[tid] : 0;
    s[tid] = v;
    __syncthreads();
    for (int off = 1; off < 256; off <<= 1) {
        int val = 0;
        if (tid >= off) val = s[tid - off];
        __syncthreads();
        if (tid >= off) s[tid] += val;
        __syncthreads();
    }
    if (tid < NB) bsum[tid] = s[tid] - v;
}

__global__ __launch_bounds__(256) void k_scan3(int* __restrict__ rowptr,
                                               const int* __restrict__ bsum, int N, int E) {
    int i = blockIdx.x * blockDim.x + threadIdx.x;
    if (i < N) rowptr[i] += bsum[i >> 10];
    if (i == 0) rowptr[N] = E;
}

__global__ __launch_bounds__(256) void k_fill(const int* __restrict__ src,
                                              const int* __restrict__ dst, int E,
                                              const int* __restrict__ rowptr,
                                              int* __restrict__ fill,
                                              const float* __restrict__ dinv,
                                              int* __restrict__ col,
                                              float* __restrict__ ew) {
    int e = blockIdx.x * blockDim.x + threadIdx.x;
    if (e >= E) return;
    int s = src[e], d = dst[e];
    int pos = atomicAdd(&fill[d], 1);
    int idx = rowptr[d] + pos;
    col[idx] = s;
    ew[idx] = dinv[s] * dinv[d];
}

// ---------------- dense GEMM: C[N,Fout] = A[N,Fin] @ W[Fin,Fout] ----------------
// thread computes 4 node-rows of one output column; W reads coalesced, A broadcast.

__global__ __launch_bounds__(256) void k_gemm(const float* __restrict__ A,
                                              const float* __restrict__ W,
                                              float* __restrict__ C,
                                              int N, int Fin, int Fout) {
    int t = blockIdx.x * blockDim.x + threadIdx.x;
    int f = t % Fout;
    int v0 = (t / Fout) * 4;
    if (v0 >= N) return;
    const float* a = A + (size_t)v0 * Fin;
    float acc0 = 0.f, acc1 = 0.f, acc2 = 0.f, acc3 = 0.f;
    if (v0 + 3 < N) {
        for (int k = 0; k < Fin; k++) {
            float w = W[(size_t)k * Fout + f];
            acc0 = fmaf(a[k], w, acc0);
            acc1 = fmaf(a[Fin + k], w, acc1);
            acc2 = fmaf(a[2 * Fin + k], w, acc2);
            acc3 = fmaf(a[3 * Fin + k], w, acc3);
        }
        C[(size_t)(v0 + 0) * Fout + f] = acc0;
        C[(size_t)(v0 + 1) * Fout + f] = acc1;
        C[(size_t)(v0 + 2) * Fout + f] = acc2;
        C[(size_t)(v0 + 3) * Fout + f] = acc3;
    } else {
        for (int r = 0; r < 4 && v0 + r < N; r++) {
            float acc = 0.f;
            for (int k = 0; k < Fin; k++)
                acc = fmaf(a[(size_t)r * Fin + k], W[(size_t)k * Fout + f], acc);
            C[(size_t)(v0 + r) * Fout + f] = acc;
        }
    }
}

// ---------------- aggregation: out = relu(dinv^2*T[v] + sum_j ew*T[col] + b) ----------------

__global__ __launch_bounds__(256) void k_agg(const float* __restrict__ T,
                                             const int* __restrict__ rowptr,
                                             const int* __restrict__ col,
                                             const float* __restrict__ ew,
                                             const float* __restrict__ dinv,
                                             const float* __restrict__ bias,
                                             float* __restrict__ out, int N, int F) {
    long long t = (long long)blockIdx.x * blockDim.x + threadIdx.x;
    if (t >= (long long)N * F) return;
    int f = (int)(t % F);
    int v = (int)(t / F);
    float dv = dinv[v];
    float acc = dv * dv * T[(size_t)v * F + f];
    int beg = rowptr[v], end = rowptr[v + 1];
    for (int j = beg; j < end; j++) {
        acc = fmaf(ew[j], T[(size_t)col[j] * F + f], acc);
    }
    acc += bias[f];
    out[t] = fmaxf(acc, 0.f);
}

// conv3 variant: fused aggregation + relu + segment-max pool (batch sorted, values >= 0)
__global__ __launch_bounds__(256) void k_agg_pool(const float* __restrict__ T,
                                                  const int* __restrict__ rowptr,
                                                  const int* __restrict__ col,
                                                  const float* __restrict__ ew,
                                                  const float* __restrict__ dinv,
                                                  const float* __restrict__ bias,
                                                  const int* __restrict__ batch,
                                                  float* __restrict__ G, int N, int F) {
    long long t = (long long)blockIdx.x * blockDim.x + threadIdx.x;
    if (t >= (long long)N * F) return;
    int f = (int)(t % F);
    int v = (int)(t / F);
    float dv = dinv[v];
    float acc = dv * dv * T[(size_t)v * F + f];
    int beg = rowptr[v], end = rowptr[v + 1];
    for (int j = beg; j < end; j++) {
        acc = fmaf(ew[j], T[(size_t)col[j] * F + f], acc);
    }
    float r = fmaxf(acc + bias[f], 0.f);
    int g = batch[v];
    atomicMax((int*)&G[(size_t)g * F + f], __float_as_int(r));
}

// ---------------- FC: C[M,Nout] = A[M,K] @ W[K,Nout] + b, optional relu ----------------

__global__ __launch_bounds__(256) void k_fc(const float* __restrict__ A,
                                            const float* __restrict__ W,
                                            const float* __restrict__ b,
                                            float* __restrict__ C,
                                            int M, int K, int Nout, int do_relu) {
    int t = blockIdx.x * blockDim.x + threadIdx.x;
    if (t >= M * Nout) return;
    int oc = t % Nout;
    int m = t / Nout;
    const float* a = A + (size_t)m * K;
    float acc = b[oc];
    for (int k = 0; k < K; k++) acc = fmaf(a[k], W[(size_t)k * Nout + oc], acc);
    if (do_relu) acc = fmaxf(acc, 0.f);
    C[t] = acc;
}

// ---------------- launch ----------------

extern "C" void kernel_launch(void* const* d_in, const int* in_sizes, int n_in,
                              void* d_out, int out_size, void* d_ws, size_t ws_size,
                              hipStream_t stream) {
    const float* x     = (const float*)d_in[0];
    const int*   ei    = (const int*)d_in[1];
    const int*   batch = (const int*)d_in[2];
    const float* W1 = (const float*)d_in[3];
    const float* b1 = (const float*)d_in[4];
    const float* W2 = (const float*)d_in[5];
    const float* b2 = (const float*)d_in[6];
    const float* W3 = (const float*)d_in[7];
    const float* b3 = (const float*)d_in[8];
    const float* Wg1 = (const float*)d_in[9];
    const float* bg1 = (const float*)d_in[10];
    const float* Wg2 = (const float*)d_in[11];
    const float* bg2 = (const float*)d_in[12];

    const int N  = in_sizes[2];          // 50000
    const int E  = in_sizes[1] / 2;      // 800000
    const int F1 = in_sizes[4];          // 75
    const int F2 = in_sizes[6];          // 150
    const int F3 = in_sizes[8];          // 300
    const int H1 = in_sizes[10];         // 1024
    const int OC = in_sizes[12];         // 128
    const int NG = out_size / OC;        // 256
    const int FIN = in_sizes[3] / F1;    // 75

    const int* src = ei;
    const int* dst = ei + E;

    // workspace carve-out
    char* base = (char*)d_ws;
    size_t off = 0;
    auto alloc = [&](size_t bytes) -> void* {
        void* p = base + off;
        off = (off + bytes + 255) & ~(size_t)255;
        return p;
    };
    int*   cnt    = (int*)alloc((size_t)N * 4);
    int*   fill   = (int*)alloc((size_t)N * 4);
    int*   rowptr = (int*)alloc((size_t)(N + 1) * 4);
    float* dinv   = (float*)alloc((size_t)N * 4);
    int*   bsum   = (int*)alloc(256 * 4);
    int*   col    = (int*)alloc((size_t)E * 4);
    float* ew     = (float*)alloc((size_t)E * 4);
    float* Gb     = (float*)alloc((size_t)NG * F3 * 4);
    float* g1     = (float*)alloc((size_t)NG * H1 * 4);
    // arena A holds T1,A1 then A2; arena B holds T2 then T3
    size_t rA = (size_t)N * (size_t)((2 * F1 > F2) ? 2 * F1 : F2);   // 150N floats
    size_t rB = (size_t)N * (size_t)((F2 > F3) ? F2 : F3);           // 300N floats
    float* poolA = (float*)alloc(rA * 4);
    float* poolB = (float*)alloc(rB * 4);
    float* T1 = poolA;
    float* A1 = poolA + (size_t)N * F1;
    float* T2 = poolB;
    float* A2 = poolA;
    float* T3 = poolB;

    hipMemsetAsync(cnt, 0, (size_t)N * 4, stream);
    hipMemsetAsync(fill, 0, (size_t)N * 4, stream);
    hipMemsetAsync(Gb, 0, (size_t)NG * F3 * 4, stream);

    k_count<<<ceil_div_i(E, 256), 256, 0, stream>>>(dst, E, cnt);
    k_dinv<<<ceil_div_i(N, 256), 256, 0, stream>>>(cnt, dinv, N);

    int NB = ceil_div_i(N, SCAN_B);
    k_scan1<<<NB, 256, 0, stream>>>(cnt, rowptr, bsum, N);
    k_scan2<<<1, 256, 0, stream>>>(bsum, NB);
    k_scan3<<<ceil_div_i(N, 256), 256, 0, stream>>>(rowptr, bsum, N, E);
    k_fill<<<ceil_div_i(E, 256), 256, 0, stream>>>(src, dst, E, rowptr, fill, dinv, col, ew);

    // conv1: T1 = X @ W1 ; A1 = relu(agg(T1) + b1)
    {
        long long th = (long long)ceil_div_i(N, 4) * F1;
        k_gemm<<<ceil_div_i(th, 256), 256, 0, stream>>>(x, W1, T1, N, FIN, F1);
        long long ta = (long long)N * F1;
        k_agg<<<ceil_div_i(ta, 256), 256, 0, stream>>>(T1, rowptr, col, ew, dinv, b1, A1, N, F1);
    }
    // conv2: T2 = A1 @ W2 ; A2 = relu(agg(T2) + b2)
    {
        long long th = (long long)ceil_div_i(N, 4) * F2;
        k_gemm<<<ceil_div_i(th, 256), 256, 0, stream>>>(A1, W2, T2, N, F1, F2);
        long long ta = (long long)N * F2;
        k_agg<<<ceil_div_i(ta, 256), 256, 0, stream>>>(T2, rowptr, col, ew, dinv, b2, A2, N, F2);
    }
    // conv3: T3 = A2 @ W3 ; G = segmax(relu(agg(T3) + b3))
    {
        long long th = (long long)ceil_div_i(N, 4) * F3;
        k_gemm<<<ceil_div_i(th, 256), 256, 0, stream>>>(A2, W3, T3, N, F2, F3);
        long long ta = (long long)N * F3;
        k_agg_pool<<<ceil_div_i(ta, 256), 256, 0, stream>>>(T3, rowptr, col, ew, dinv, b3,
                                                            batch, Gb, N, F3);
    }
    // fc_g1: g1 = relu(G @ Wg1 + bg1)
    k_fc<<<ceil_div_i(NG * H1, 256), 256, 0, stream>>>(Gb, Wg1, bg1, g1, NG, F3, H1, 1);
    // fc_g2: out = g1 @ Wg2 + bg2
    k_fc<<<ceil_div_i(NG * OC, 256), 256, 0, stream>>>(g1, Wg2, bg2, (float*)d_out, NG, H1, OC, 0);
}

// Round 2
// 1467.495 us; speedup vs baseline: 1.0744x; 1.0744x over previous
//
#include <hip/hip_runtime.h>
#include <math.h>

#define SCAN_B 1024
#define RT 64      // GEMM row tile
#define CT 64      // GEMM col tile
#define KC 32      // GEMM k chunk
#define MAXKP 160  // max K rounded up to KC (K<=150 -> 160)
#define PAD_A 4    // LDS pad for A^T tile (keeps float4 alignment, 4-way write conflict only)

static inline int ceil_div_i(long long a, int b) { return (int)((a + b - 1) / b); }

// ---------------- CSR construction ----------------

__global__ __launch_bounds__(256) void k_count(const int* __restrict__ dst, int E,
                                               int* __restrict__ cnt) {
    int i = blockIdx.x * blockDim.x + threadIdx.x;
    if (i < E) atomicAdd(&cnt[dst[i]], 1);
}

__global__ __launch_bounds__(256) void k_dinv(const int* __restrict__ cnt,
                                              float* __restrict__ dinv, int N) {
    int i = blockIdx.x * blockDim.x + threadIdx.x;
    if (i < N) dinv[i] = (float)(1.0 / sqrt((double)(cnt[i] + 1)));
}

__global__ __launch_bounds__(256) void k_scan1(const int* __restrict__ cnt,
                                               int* __restrict__ rowptr,
                                               int* __restrict__ bsum, int N) {
    __shared__ int s[256];
    int tid = threadIdx.x;
    int base = blockIdx.x * SCAN_B + tid * 4;
    int a0 = (base + 0 < N) ? cnt[base + 0] : 0;
    int a1 = (base + 1 < N) ? cnt[base + 1] : 0;
    int a2 = (base + 2 < N) ? cnt[base + 2] : 0;
    int a3 = (base + 3 < N) ? cnt[base + 3] : 0;
    int tsum = a0 + a1 + a2 + a3;
    s[tid] = tsum;
    __syncthreads();
    for (int off = 1; off < 256; off <<= 1) {
        int val = 0;
        if (tid >= off) val = s[tid - off];
        __syncthreads();
        if (tid >= off) s[tid] += val;
        __syncthreads();
    }
    int texcl = s[tid] - tsum;
    if (tid == 255) bsum[blockIdx.x] = s[255];
    if (base + 0 < N) rowptr[base + 0] = texcl;
    if (base + 1 < N) rowptr[base + 1] = texcl + a0;
    if (base + 2 < N) rowptr[base + 2] = texcl + a0 + a1;
    if (base + 3 < N) rowptr[base + 3] = texcl + a0 + a1 + a2;
}

__global__ __launch_bounds__(256) void k_scan2(int* __restrict__ bsum, int NB) {
    __shared__ int s[256];
    int tid = threadIdx.x;
    int v = (tid < NB) ? bsum[tid] : 0;
    s[tid] = v;
    __syncthreads();
    for (int off = 1; off < 256; off <<= 1) {
        int val = 0;
        if (tid >= off) val = s[tid - off];
        __syncthreads();
        if (tid >= off) s[tid] += val;
        __syncthreads();
    }
    if (tid < NB) bsum[tid] = s[tid] - v;
}

__global__ __launch_bounds__(256) void k_scan3(int* __restrict__ rowptr,
                                               const int* __restrict__ bsum, int N, int E) {
    int i = blockIdx.x * blockDim.x + threadIdx.x;
    if (i < N) rowptr[i] += bsum[i >> 10];
    if (i == 0) rowptr[N] = E;
}

__global__ __launch_bounds__(256) void k_fill(const int* __restrict__ src,
                                              const int* __restrict__ dst, int E,
                                              const int* __restrict__ rowptr,
                                              int* __restrict__ fill,
                                              const float* __restrict__ dinv,
                                              int* __restrict__ col,
                                              float* __restrict__ ew) {
    int e = blockIdx.x * blockDim.x + threadIdx.x;
    if (e >= E) return;
    int s = src[e], d = dst[e];
    int pos = atomicAdd(&fill[d], 1);
    int idx = rowptr[d] + pos;
    col[idx] = s;
    ew[idx] = dinv[s] * dinv[d];
}

// ---------------- gather: T[v] = dinv[v]^2 * X[v] + sum_j ew[j]*X[col[j]] ----------------
// (A-hat applied BEFORE the weight matmul; exact reassociation of the reference)

template <int VW>
__global__ __launch_bounds__(256) void k_gather(const float* __restrict__ X,
                                                const int* __restrict__ rowptr,
                                                const int* __restrict__ col,
                                                const float* __restrict__ ew,
                                                const float* __restrict__ dinv,
                                                float* __restrict__ T, int N, int F) {
    int t = blockIdx.x * blockDim.x + threadIdx.x;
    int FV = F / VW;
    if (t >= N * FV) return;
    int v = t / FV;
    int fi = (t % FV) * VW;
    float dv = dinv[v];
    float s = dv * dv;
    float acc[VW];
    {
        const float* xv = X + (size_t)v * F + fi;
#pragma unroll
        for (int u = 0; u < VW; u++) acc[u] = s * xv[u];
    }
    int beg = rowptr[v], end = rowptr[v + 1];
    for (int j = beg; j < end; j++) {
        int c = col[j];
        float w = ew[j];
        const float* xr = X + (size_t)c * F + fi;
        if (VW == 2) {
            float2 x2 = *(const float2*)xr;
            acc[0] = fmaf(w, x2.x, acc[0]);
            acc[VW - 1] = fmaf(w, x2.y, acc[VW - 1]);
        } else {
#pragma unroll
            for (int u = 0; u < VW; u++) acc[u] = fmaf(w, xr[u], acc[u]);
        }
    }
    float* tv = T + (size_t)v * F + fi;
#pragma unroll
    for (int u = 0; u < VW; u++) tv[u] = acc[u];
}

// ---------------- tiled GEMM: out = epilogue(A[N,K] @ W[K,Fout] + bias) ----------------
// 64x64 tile / 256 threads / 4x4 micro-tile. W col-slab resident in LDS, A^T staged per chunk.
// mode 0: C[row] = relu(. + bias)   mode 1: atomicMax pool into G[batch[row]]

__global__ __launch_bounds__(256) void k_gemm_tiled(const float* __restrict__ A,
                                                    const float* __restrict__ W,
                                                    const float* __restrict__ bias,
                                                    float* __restrict__ C,
                                                    const int* __restrict__ batch,
                                                    float* __restrict__ G,
                                                    int N, int K, int Fout, int mode) {
    __shared__ __align__(16) float sW[MAXKP * CT];
    __shared__ __align__(16) float sA[KC * (RT + PAD_A)];
    const int t = threadIdx.x;
    const int r0 = blockIdx.x * RT;
    const int c0 = blockIdx.y * CT;
    const int KP = (K + KC - 1) / KC * KC;

    // stage the whole K x CT slab of W (zero-padded to KP rows / CT cols)
    for (int i = t; i < KP * CT; i += 256) {
        int k = i >> 6, c = i & 63;
        float w = 0.f;
        if (k < K && c0 + c < Fout) w = W[(size_t)k * Fout + c0 + c];
        sW[i] = w;
    }

    const int tx = t & 15, ty = t >> 4;
    float acc[4][4] = {{0.f}};

    for (int kk = 0; kk < K; kk += KC) {
        // stage A^T chunk: sA[k][row], k fastest in global read for coalescing
        for (int i = t; i < KC * RT; i += 256) {
            int k = i & (KC - 1), row = i >> 5;
            float a = 0.f;
            int gk = kk + k, gr = r0 + row;
            if (gk < K && gr < N) a = A[(size_t)gr * K + gk];
            sA[k * (RT + PAD_A) + row] = a;
        }
        __syncthreads();
#pragma unroll 8
        for (int k = 0; k < KC; ++k) {
            float4 av = *(const float4*)&sA[k * (RT + PAD_A) + ty * 4];
            float4 wv = *(const float4*)&sW[(kk + k) * CT + tx * 4];
            acc[0][0] = fmaf(av.x, wv.x, acc[0][0]);
            acc[0][1] = fmaf(av.x, wv.y, acc[0][1]);
            acc[0][2] = fmaf(av.x, wv.z, acc[0][2]);
            acc[0][3] = fmaf(av.x, wv.w, acc[0][3]);
            acc[1][0] = fmaf(av.y, wv.x, acc[1][0]);
            acc[1][1] = fmaf(av.y, wv.y, acc[1][1]);
            acc[1][2] = fmaf(av.y, wv.z, acc[1][2]);
            acc[1][3] = fmaf(av.y, wv.w, acc[1][3]);
            acc[2][0] = fmaf(av.z, wv.x, acc[2][0]);
            acc[2][1] = fmaf(av.z, wv.y, acc[2][1]);
            acc[2][2] = fmaf(av.z, wv.z, acc[2][2]);
            acc[2][3] = fmaf(av.z, wv.w, acc[2][3]);
            acc[3][0] = fmaf(av.w, wv.x, acc[3][0]);
            acc[3][1] = fmaf(av.w, wv.y, acc[3][1]);
            acc[3][2] = fmaf(av.w, wv.z, acc[3][2]);
            acc[3][3] = fmaf(av.w, wv.w, acc[3][3]);
        }
        __syncthreads();
    }

    // epilogue: bias + relu, then store or pool
#pragma unroll
    for (int rr = 0; rr < 4; rr++) {
        int row = r0 + ty * 4 + rr;
        if (row >= N) continue;
        int g = (mode == 1) ? batch[row] : 0;
#pragma unroll
        for (int cc = 0; cc < 4; cc++) {
            int c = c0 + tx * 4 + cc;
            if (c >= Fout) continue;
            float v = fmaxf(acc[rr][cc] + bias[c], 0.f);
            if (mode == 0) {
                C[(size_t)row * Fout + c] = v;
            } else {
                atomicMax((int*)&G[(size_t)g * Fout + c], __float_as_int(v));
            }
        }
    }
}

// ---------------- FC: C[M,Nout] = A[M,K] @ W[K,Nout] + b, optional relu ----------------

__global__ __launch_bounds__(256) void k_fc(const float* __restrict__ A,
                                            const float* __restrict__ W,
                                            const float* __restrict__ b,
                                            float* __restrict__ C,
                                            int M, int K, int Nout, int do_relu) {
    int t = blockIdx.x * blockDim.x + threadIdx.x;
    if (t >= M * Nout) return;
    int oc = t % Nout;
    int m = t / Nout;
    const float* a = A + (size_t)m * K;
    float acc = b[oc];
    for (int k = 0; k < K; k++) acc = fmaf(a[k], W[(size_t)k * Nout + oc], acc);
    if (do_relu) acc = fmaxf(acc, 0.f);
    C[t] = acc;
}

// ---------------- launch ----------------

extern "C" void kernel_launch(void* const* d_in, const int* in_sizes, int n_in,
                              void* d_out, int out_size, void* d_ws, size_t ws_size,
                              hipStream_t stream) {
    const float* x     = (const float*)d_in[0];
    const int*   ei    = (const int*)d_in[1];
    const int*   batch = (const int*)d_in[2];
    const float* W1 = (const float*)d_in[3];
    const float* b1 = (const float*)d_in[4];
    const float* W2 = (const float*)d_in[5];
    const float* b2 = (const float*)d_in[6];
    const float* W3 = (const float*)d_in[7];
    const float* b3 = (const float*)d_in[8];
    const float* Wg1 = (const float*)d_in[9];
    const float* bg1 = (const float*)d_in[10];
    const float* Wg2 = (const float*)d_in[11];
    const float* bg2 = (const float*)d_in[12];

    const int N  = in_sizes[2];          // 50000
    const int E  = in_sizes[1] / 2;      // 800000
    const int F1 = in_sizes[4];          // 75
    const int F2 = in_sizes[6];          // 150
    const int F3 = in_sizes[8];          // 300
    const int H1 = in_sizes[10];         // 1024
    const int OC = in_sizes[12];         // 128
    const int NG = out_size / OC;        // 256
    const int FIN = in_sizes[3] / F1;    // 75

    const int* src = ei;
    const int* dst = ei + E;

    char* base = (char*)d_ws;
    size_t off = 0;
    auto alloc = [&](size_t bytes) -> void* {
        void* p = base + off;
        off = (off + bytes + 255) & ~(size_t)255;
        return p;
    };
    int*   cnt    = (int*)alloc((size_t)N * 4);
    int*   fill   = (int*)alloc((size_t)N * 4);
    int*   rowptr = (int*)alloc((size_t)(N + 1) * 4);
    float* dinv   = (float*)alloc((size_t)N * 4);
    int*   bsum   = (int*)alloc(256 * 4);
    int*   col    = (int*)alloc((size_t)E * 4);
    float* ew     = (float*)alloc((size_t)E * 4);
    float* Gb     = (float*)alloc((size_t)NG * F3 * 4);
    float* g1     = (float*)alloc((size_t)NG * H1 * 4);
    float* bufA   = (float*)alloc((size_t)N * FIN * 4);  // T1g, later T2g (75N)
    float* bufB   = (float*)alloc((size_t)N * F1 * 4);   // H1 (75N)
    float* bufC   = (float*)alloc((size_t)N * F2 * 4);   // H2 (150N)
    float* bufD   = (float*)alloc((size_t)N * F2 * 4);   // T3g (150N)

    hipMemsetAsync(cnt, 0, (size_t)N * 4, stream);
    hipMemsetAsync(fill, 0, (size_t)N * 4, stream);
    hipMemsetAsync(Gb, 0, (size_t)NG * F3 * 4, stream);

    // ---- CSR ----
    k_count<<<ceil_div_i(E, 256), 256, 0, stream>>>(dst, E, cnt);
    k_dinv<<<ceil_div_i(N, 256), 256, 0, stream>>>(cnt, dinv, N);
    int NB = ceil_div_i(N, SCAN_B);
    k_scan1<<<NB, 256, 0, stream>>>(cnt, rowptr, bsum, N);
    k_scan2<<<1, 256, 0, stream>>>(bsum, NB);
    k_scan3<<<ceil_div_i(N, 256), 256, 0, stream>>>(rowptr, bsum, N, E);
    k_fill<<<ceil_div_i(E, 256), 256, 0, stream>>>(src, dst, E, rowptr, fill, dinv, col, ew);

    dim3 blk(256);

    // conv1: T = A-hat @ X (F=75), H1 = relu(T @ W1 + b1)
    k_gather<1><<<ceil_div_i((long long)N * FIN, 256), blk, 0, stream>>>(
        x, rowptr, col, ew, dinv, bufA, N, FIN);
    {
        dim3 g(ceil_div_i(N, RT), ceil_div_i(F1, CT));
        k_gemm_tiled<<<g, blk, 0, stream>>>(bufA, W1, b1, bufB, nullptr, nullptr,
                                            N, FIN, F1, 0);
    }
    // conv2: T = A-hat @ H1 (F=75), H2 = relu(T @ W2 + b2)
    k_gather<1><<<ceil_div_i((long long)N * F1, 256), blk, 0, stream>>>(
        bufB, rowptr, col, ew, dinv, bufA, N, F1);
    {
        dim3 g(ceil_div_i(N, RT), ceil_div_i(F2, CT));
        k_gemm_tiled<<<g, blk, 0, stream>>>(bufA, W2, b2, bufC, nullptr, nullptr,
                                            N, F1, F2, 0);
    }
    // conv3: T = A-hat @ H2 (F=150), G = segmax(relu(T @ W3 + b3))
    k_gather<2><<<ceil_div_i((long long)N * (F2 / 2), 256), blk, 0, stream>>>(
        bufC, rowptr, col, ew, dinv, bufD, N, F2);
    {
        dim3 g(ceil_div_i(N, RT), ceil_div_i(F3, CT));
        k_gemm_tiled<<<g, blk, 0, stream>>>(bufD, W3, b3, nullptr, batch, Gb,
                                            N, F2, F3, 1);
    }
    // fc_g1 / fc_g2
    k_fc<<<ceil_div_i(NG * H1, 256), 256, 0, stream>>>(Gb, Wg1, bg1, g1, NG, F3, H1, 1);
    k_fc<<<ceil_div_i(NG * OC, 256), 256, 0, stream>>>(g1, Wg2, bg2, (float*)d_out, NG, H1, OC, 0);
}

// Round 3
// 1095.562 us; speedup vs baseline: 1.4392x; 1.3395x over previous
//
#include <hip/hip_runtime.h>
#include <math.h>

#define SCAN_B 1024
#define RT 128     // GEMM row tile
#define CT 128     // GEMM col tile
#define KC 16      // GEMM k chunk
#define SA_STRIDE (RT + 4)   // 132: sA bank pattern (4k+row)%32 -> 2-way (free)

static inline int ceil_div_i(long long a, int b) { return (int)((a + b - 1) / b); }

// ---------------- CSR construction ----------------

__global__ __launch_bounds__(256) void k_count(const int* __restrict__ dst, int E,
                                               int* __restrict__ cnt) {
    int i = blockIdx.x * blockDim.x + threadIdx.x;
    if (i < E) atomicAdd(&cnt[dst[i]], 1);
}

__global__ __launch_bounds__(256) void k_dinv(const int* __restrict__ cnt,
                                              float* __restrict__ dinv, int N) {
    int i = blockIdx.x * blockDim.x + threadIdx.x;
    if (i < N) dinv[i] = (float)(1.0 / sqrt((double)(cnt[i] + 1)));
}

__global__ __launch_bounds__(256) void k_scan1(const int* __restrict__ cnt,
                                               int* __restrict__ rowptr,
                                               int* __restrict__ bsum, int N) {
    __shared__ int s[256];
    int tid = threadIdx.x;
    int base = blockIdx.x * SCAN_B + tid * 4;
    int a0 = (base + 0 < N) ? cnt[base + 0] : 0;
    int a1 = (base + 1 < N) ? cnt[base + 1] : 0;
    int a2 = (base + 2 < N) ? cnt[base + 2] : 0;
    int a3 = (base + 3 < N) ? cnt[base + 3] : 0;
    int tsum = a0 + a1 + a2 + a3;
    s[tid] = tsum;
    __syncthreads();
    for (int off = 1; off < 256; off <<= 1) {
        int val = 0;
        if (tid >= off) val = s[tid - off];
        __syncthreads();
        if (tid >= off) s[tid] += val;
        __syncthreads();
    }
    int texcl = s[tid] - tsum;
    if (tid == 255) bsum[blockIdx.x] = s[255];
    if (base + 0 < N) rowptr[base + 0] = texcl;
    if (base + 1 < N) rowptr[base + 1] = texcl + a0;
    if (base + 2 < N) rowptr[base + 2] = texcl + a0 + a1;
    if (base + 3 < N) rowptr[base + 3] = texcl + a0 + a1 + a2;
}

__global__ __launch_bounds__(256) void k_scan2(int* __restrict__ bsum, int NB) {
    __shared__ int s[256];
    int tid = threadIdx.x;
    int v = (tid < NB) ? bsum[tid] : 0;
    s[tid] = v;
    __syncthreads();
    for (int off = 1; off < 256; off <<= 1) {
        int val = 0;
        if (tid >= off) val = s[tid - off];
        __syncthreads();
        if (tid >= off) s[tid] += val;
        __syncthreads();
    }
    if (tid < NB) bsum[tid] = s[tid] - v;
}

__global__ __launch_bounds__(256) void k_scan3(int* __restrict__ rowptr,
                                               const int* __restrict__ bsum, int N, int E) {
    int i = blockIdx.x * blockDim.x + threadIdx.x;
    if (i < N) rowptr[i] += bsum[i >> 10];
    if (i == 0) rowptr[N] = E;
}

__global__ __launch_bounds__(256) void k_fill(const int* __restrict__ src,
                                              const int* __restrict__ dst, int E,
                                              const int* __restrict__ rowptr,
                                              int* __restrict__ fill,
                                              const float* __restrict__ dinv,
                                              int* __restrict__ col,
                                              float* __restrict__ ew) {
    int e = blockIdx.x * blockDim.x + threadIdx.x;
    if (e >= E) return;
    int s = src[e], d = dst[e];
    int pos = atomicAdd(&fill[d], 1);
    int idx = rowptr[d] + pos;
    col[idx] = s;
    ew[idx] = dinv[s] * dinv[d];
}

// ---------------- gather: T[v] = dinv[v]^2 * X[v] + sum_j ew[j]*X[col[j]] ----------------

template <int VW>
__global__ __launch_bounds__(256) void k_gather(const float* __restrict__ X,
                                                const int* __restrict__ rowptr,
                                                const int* __restrict__ col,
                                                const float* __restrict__ ew,
                                                const float* __restrict__ dinv,
                                                float* __restrict__ T, int N, int F) {
    int t = blockIdx.x * blockDim.x + threadIdx.x;
    int FV = F / VW;
    if (t >= N * FV) return;
    int v = t / FV;
    int fi = (t % FV) * VW;
    float dv = dinv[v];
    float s = dv * dv;
    float acc[VW];
    {
        const float* xv = X + (size_t)v * F + fi;
#pragma unroll
        for (int u = 0; u < VW; u++) acc[u] = s * xv[u];
    }
    int beg = rowptr[v], end = rowptr[v + 1];
    for (int j = beg; j < end; j++) {
        int c = col[j];
        float w = ew[j];
        const float* xr = X + (size_t)c * F + fi;
        if (VW == 2) {
            float2 x2 = *(const float2*)xr;
            acc[0] = fmaf(w, x2.x, acc[0]);
            acc[VW - 1] = fmaf(w, x2.y, acc[VW - 1]);
        } else {
#pragma unroll
            for (int u = 0; u < VW; u++) acc[u] = fmaf(w, xr[u], acc[u]);
        }
    }
    float* tv = T + (size_t)v * F + fi;
#pragma unroll
    for (int u = 0; u < VW; u++) tv[u] = acc[u];
}

// ---------------- tiled GEMM: C = relu(A[N,K] @ W[K,Fout] + bias) ----------------
// 128x128 tile / 256 threads / 8x8 micro-tile / KC=16.
// sA transposed [KC][RT+4]: write banks (4k+row)%32 -> 2-way (free); float4 reads.
// sW [KC][CT]: coalesced staging, float4 reads.

__global__ __launch_bounds__(256) void k_gemm_tiled(const float* __restrict__ A,
                                                    const float* __restrict__ W,
                                                    const float* __restrict__ bias,
                                                    float* __restrict__ C,
                                                    int N, int K, int Fout) {
    __shared__ __align__(16) float sA[KC * SA_STRIDE];
    __shared__ __align__(16) float sW[KC * CT];
    const int t = threadIdx.x;
    const int r0 = blockIdx.x * RT;
    const int c0 = blockIdx.y * CT;
    const int tx = t & 15;       // 16 col groups * 8 cols
    const int ty = t >> 4;       // 16 row groups * 8 rows

    float acc[8][8];
#pragma unroll
    for (int i = 0; i < 8; i++)
#pragma unroll
        for (int j = 0; j < 8; j++) acc[i][j] = 0.f;

    for (int kk = 0; kk < K; kk += KC) {
        // stage A^T chunk: 2048 elems, k fastest in global (coalesced 64B runs)
#pragma unroll
        for (int it = 0; it < 8; it++) {
            int i = it * 256 + t;
            int k = i & (KC - 1), row = i >> 4;
            float a = 0.f;
            int gk = kk + k, gr = r0 + row;
            if (gk < K && gr < N) a = A[(size_t)gr * K + gk];
            sA[k * SA_STRIDE + row] = a;
        }
        // stage W chunk: 2048 elems, fully coalesced
#pragma unroll
        for (int it = 0; it < 8; it++) {
            int i = it * 256 + t;
            int k = i >> 7, c = i & 127;
            float w = 0.f;
            int gk = kk + k, gc = c0 + c;
            if (gk < K && gc < Fout) w = W[(size_t)gk * Fout + gc];
            sW[k * CT + c] = w;
        }
        __syncthreads();
#pragma unroll
        for (int k = 0; k < KC; ++k) {
            float4 av0 = *(const float4*)&sA[k * SA_STRIDE + ty * 8];
            float4 av1 = *(const float4*)&sA[k * SA_STRIDE + ty * 8 + 4];
            float4 wv0 = *(const float4*)&sW[k * CT + tx * 8];
            float4 wv1 = *(const float4*)&sW[k * CT + tx * 8 + 4];
            float ar[8] = {av0.x, av0.y, av0.z, av0.w, av1.x, av1.y, av1.z, av1.w};
            float wr[8] = {wv0.x, wv0.y, wv0.z, wv0.w, wv1.x, wv1.y, wv1.z, wv1.w};
#pragma unroll
            for (int i = 0; i < 8; i++)
#pragma unroll
                for (int j = 0; j < 8; j++) acc[i][j] = fmaf(ar[i], wr[j], acc[i][j]);
        }
        __syncthreads();
    }

    // epilogue: bias + relu + store
    const bool vec4 = ((Fout & 3) == 0) && (c0 + tx * 8 + 7 < Fout);
#pragma unroll
    for (int rr = 0; rr < 8; rr++) {
        int row = r0 + ty * 8 + rr;
        if (row >= N) continue;
        float* crow = C + (size_t)row * Fout;
        if (vec4) {
            int c = c0 + tx * 8;
            float4 o0, o1;
            o0.x = fmaxf(acc[rr][0] + bias[c + 0], 0.f);
            o0.y = fmaxf(acc[rr][1] + bias[c + 1], 0.f);
            o0.z = fmaxf(acc[rr][2] + bias[c + 2], 0.f);
            o0.w = fmaxf(acc[rr][3] + bias[c + 3], 0.f);
            o1.x = fmaxf(acc[rr][4] + bias[c + 4], 0.f);
            o1.y = fmaxf(acc[rr][5] + bias[c + 5], 0.f);
            o1.z = fmaxf(acc[rr][6] + bias[c + 6], 0.f);
            o1.w = fmaxf(acc[rr][7] + bias[c + 7], 0.f);
            *(float4*)&crow[c] = o0;
            *(float4*)&crow[c + 4] = o1;
        } else {
#pragma unroll
            for (int cc = 0; cc < 8; cc++) {
                int c = c0 + tx * 8 + cc;
                if (c < Fout) crow[c] = fmaxf(acc[rr][cc] + bias[c], 0.f);
            }
        }
    }
}

// ---------------- per-graph max pool (batch sorted -> contiguous ranges) ----------------

__device__ __forceinline__ int d_lower_bound(const int* __restrict__ a, int n, int key) {
    int lo = 0, hi = n;
    while (lo < hi) {
        int mid = (lo + hi) >> 1;
        if (a[mid] < key) lo = mid + 1; else hi = mid;
    }
    return lo;
}

__global__ __launch_bounds__(320) void k_pool(const float* __restrict__ T,
                                              const int* __restrict__ batch,
                                              float* __restrict__ G, int N, int F) {
    int g = blockIdx.x;
    int c = threadIdx.x;
    if (c >= F) return;
    int start = d_lower_bound(batch, N, g);
    int end = d_lower_bound(batch, N, g + 1);
    float m = 0.f;  // inputs are relu'd (>=0)
    for (int r = start; r < end; ++r) m = fmaxf(m, T[(size_t)r * F + c]);
    G[(size_t)g * F + c] = m;
}

// ---------------- FC: C[M,Nout] = A[M,K] @ W[K,Nout] + b (float4 over oc) ----------------

__global__ __launch_bounds__(256) void k_fc4(const float* __restrict__ A,
                                             const float* __restrict__ W,
                                             const float* __restrict__ b,
                                             float* __restrict__ C,
                                             int M, int K, int Nout, int do_relu) {
    int t = blockIdx.x * blockDim.x + threadIdx.x;
    int NV = Nout >> 2;
    if (t >= M * NV) return;
    int oc = (t % NV) * 4;
    int m = t / NV;
    const float* a = A + (size_t)m * K;
    float4 acc = *(const float4*)&b[oc];
    for (int k = 0; k < K; k++) {
        float av = a[k];
        float4 wv = *(const float4*)&W[(size_t)k * Nout + oc];
        acc.x = fmaf(av, wv.x, acc.x);
        acc.y = fmaf(av, wv.y, acc.y);
        acc.z = fmaf(av, wv.z, acc.z);
        acc.w = fmaf(av, wv.w, acc.w);
    }
    if (do_relu) {
        acc.x = fmaxf(acc.x, 0.f);
        acc.y = fmaxf(acc.y, 0.f);
        acc.z = fmaxf(acc.z, 0.f);
        acc.w = fmaxf(acc.w, 0.f);
    }
    *(float4*)&C[(size_t)m * Nout + oc] = acc;
}

// ---------------- launch ----------------

extern "C" void kernel_launch(void* const* d_in, const int* in_sizes, int n_in,
                              void* d_out, int out_size, void* d_ws, size_t ws_size,
                              hipStream_t stream) {
    const float* x     = (const float*)d_in[0];
    const int*   ei    = (const int*)d_in[1];
    const int*   batch = (const int*)d_in[2];
    const float* W1 = (const float*)d_in[3];
    const float* b1 = (const float*)d_in[4];
    const float* W2 = (const float*)d_in[5];
    const float* b2 = (const float*)d_in[6];
    const float* W3 = (const float*)d_in[7];
    const float* b3 = (const float*)d_in[8];
    const float* Wg1 = (const float*)d_in[9];
    const float* bg1 = (const float*)d_in[10];
    const float* Wg2 = (const float*)d_in[11];
    const float* bg2 = (const float*)d_in[12];

    const int N  = in_sizes[2];          // 50000
    const int E  = in_sizes[1] / 2;      // 800000
    const int F1 = in_sizes[4];          // 75
    const int F2 = in_sizes[6];          // 150
    const int F3 = in_sizes[8];          // 300
    const int H1 = in_sizes[10];         // 1024
    const int OC = in_sizes[12];         // 128
    const int NG = out_size / OC;        // 256
    const int FIN = in_sizes[3] / F1;    // 75

    const int* src = ei;
    const int* dst = ei + E;

    char* base = (char*)d_ws;
    size_t off = 0;
    auto alloc = [&](size_t bytes) -> void* {
        void* p = base + off;
        off = (off + bytes + 255) & ~(size_t)255;
        return p;
    };
    int*   cnt    = (int*)alloc((size_t)N * 4);
    int*   fill   = (int*)alloc((size_t)N * 4);
    int*   rowptr = (int*)alloc((size_t)(N + 1) * 4);
    float* dinv   = (float*)alloc((size_t)N * 4);
    int*   bsum   = (int*)alloc(256 * 4);
    int*   col    = (int*)alloc((size_t)E * 4);
    float* ew     = (float*)alloc((size_t)E * 4);
    float* Gb     = (float*)alloc((size_t)NG * F3 * 4);
    float* g1     = (float*)alloc((size_t)NG * H1 * 4);
    // three 30MB arenas X,Y,Z (contiguous); T3 (60MB) spans Y+Z
    size_t SL = (size_t)N * F2;                    // 7.5M floats = 30MB
    float* big = (float*)alloc(3 * SL * 4);
    float* Xa = big;
    float* Ya = big + SL;
    float* Za = big + 2 * SL;
    // liveness: T1g=X, H1=Y, T2g=X, H2=Z, T3g=X, T3=Y(+Z)
    float* T1g = Xa;
    float* H1b = Ya;
    float* T2g = Xa;
    float* H2b = Za;
    float* T3g = Xa;
    float* T3  = Ya;

    hipMemsetAsync(cnt, 0, (size_t)N * 4, stream);
    hipMemsetAsync(fill, 0, (size_t)N * 4, stream);

    // ---- CSR ----
    k_count<<<ceil_div_i(E, 256), 256, 0, stream>>>(dst, E, cnt);
    k_dinv<<<ceil_div_i(N, 256), 256, 0, stream>>>(cnt, dinv, N);
    int NB = ceil_div_i(N, SCAN_B);
    k_scan1<<<NB, 256, 0, stream>>>(cnt, rowptr, bsum, N);
    k_scan2<<<1, 256, 0, stream>>>(bsum, NB);
    k_scan3<<<ceil_div_i(N, 256), 256, 0, stream>>>(rowptr, bsum, N, E);
    k_fill<<<ceil_div_i(E, 256), 256, 0, stream>>>(src, dst, E, rowptr, fill, dinv, col, ew);

    dim3 blk(256);

    // conv1
    k_gather<1><<<ceil_div_i((long long)N * FIN, 256), blk, 0, stream>>>(
        x, rowptr, col, ew, dinv, T1g, N, FIN);
    {
        dim3 g(ceil_div_i(N, RT), ceil_div_i(F1, CT));
        k_gemm_tiled<<<g, blk, 0, stream>>>(T1g, W1, b1, H1b, N, FIN, F1);
    }
    // conv2
    k_gather<1><<<ceil_div_i((long long)N * F1, 256), blk, 0, stream>>>(
        H1b, rowptr, col, ew, dinv, T2g, N, F1);
    {
        dim3 g(ceil_div_i(N, RT), ceil_div_i(F2, CT));
        k_gemm_tiled<<<g, blk, 0, stream>>>(T2g, W2, b2, H2b, N, F1, F2);
    }
    // conv3
    k_gather<2><<<ceil_div_i((long long)N * (F2 / 2), 256), blk, 0, stream>>>(
        H2b, rowptr, col, ew, dinv, T3g, N, F2);
    {
        dim3 g(ceil_div_i(N, RT), ceil_div_i(F3, CT));
        k_gemm_tiled<<<g, blk, 0, stream>>>(T3g, W3, b3, T3, N, F2, F3);
    }
    // pool (no atomics; batch sorted)
    k_pool<<<NG, 320, 0, stream>>>(T3, batch, Gb, N, F3);

    // fc_g1 / fc_g2
    k_fc4<<<ceil_div_i((long long)NG * (H1 / 4), 256), 256, 0, stream>>>(
        Gb, Wg1, bg1, g1, NG, F3, H1, 1);
    k_fc4<<<ceil_div_i((long long)NG * (OC / 4), 256), 256, 0, stream>>>(
        g1, Wg2, bg2, (float*)d_out, NG, H1, OC, 0);
}

// Round 4
// 850.448 us; speedup vs baseline: 1.8540x; 1.2882x over previous
//
#include <hip/hip_runtime.h>
#include <math.h>

#define SCAN_B 1024
#define RT 128     // GEMM row tile
#define CT 128     // GEMM col tile
#define KC 16      // GEMM k chunk
#define SA_STRIDE (RT + 4)   // 132: sA bank pattern (4k+row)%32 -> 2-way (free)

static inline int ceil_div_i(long long a, int b) { return (int)((a + b - 1) / b); }

// ---------------- CSR construction ----------------

__global__ __launch_bounds__(256) void k_count(const int* __restrict__ dst, int E,
                                               int* __restrict__ cnt) {
    int i = blockIdx.x * blockDim.x + threadIdx.x;
    if (i < E) atomicAdd(&cnt[dst[i]], 1);
}

__global__ __launch_bounds__(256) void k_dinv(const int* __restrict__ cnt,
                                              float* __restrict__ dinv, int N) {
    int i = blockIdx.x * blockDim.x + threadIdx.x;
    if (i < N) dinv[i] = (float)(1.0 / sqrt((double)(cnt[i] + 1)));
}

__global__ __launch_bounds__(256) void k_scan1(const int* __restrict__ cnt,
                                               int* __restrict__ rowptr,
                                               int* __restrict__ bsum, int N) {
    __shared__ int s[256];
    int tid = threadIdx.x;
    int base = blockIdx.x * SCAN_B + tid * 4;
    int a0 = (base + 0 < N) ? cnt[base + 0] : 0;
    int a1 = (base + 1 < N) ? cnt[base + 1] : 0;
    int a2 = (base + 2 < N) ? cnt[base + 2] : 0;
    int a3 = (base + 3 < N) ? cnt[base + 3] : 0;
    int tsum = a0 + a1 + a2 + a3;
    s[tid] = tsum;
    __syncthreads();
    for (int off = 1; off < 256; off <<= 1) {
        int val = 0;
        if (tid >= off) val = s[tid - off];
        __syncthreads();
        if (tid >= off) s[tid] += val;
        __syncthreads();
    }
    int texcl = s[tid] - tsum;
    if (tid == 255) bsum[blockIdx.x] = s[255];
    if (base + 0 < N) rowptr[base + 0] = texcl;
    if (base + 1 < N) rowptr[base + 1] = texcl + a0;
    if (base + 2 < N) rowptr[base + 2] = texcl + a0 + a1;
    if (base + 3 < N) rowptr[base + 3] = texcl + a0 + a1 + a2;
}

__global__ __launch_bounds__(256) void k_scan2(int* __restrict__ bsum, int NB) {
    __shared__ int s[256];
    int tid = threadIdx.x;
    int v = (tid < NB) ? bsum[tid] : 0;
    s[tid] = v;
    __syncthreads();
    for (int off = 1; off < 256; off <<= 1) {
        int val = 0;
        if (tid >= off) val = s[tid - off];
        __syncthreads();
        if (tid >= off) s[tid] += val;
        __syncthreads();
    }
    if (tid < NB) bsum[tid] = s[tid] - v;
}

__global__ __launch_bounds__(256) void k_scan3(int* __restrict__ rowptr,
                                               const int* __restrict__ bsum, int N, int E) {
    int i = blockIdx.x * blockDim.x + threadIdx.x;
    if (i < N) rowptr[i] += bsum[i >> 10];
    if (i == 0) rowptr[N] = E;
}

__global__ __launch_bounds__(256) void k_fill(const int* __restrict__ src,
                                              const int* __restrict__ dst, int E,
                                              const int* __restrict__ rowptr,
                                              int* __restrict__ fill,
                                              const float* __restrict__ dinv,
                                              int* __restrict__ col,
                                              float* __restrict__ ew) {
    int e = blockIdx.x * blockDim.x + threadIdx.x;
    if (e >= E) return;
    int s = src[e], d = dst[e];
    int pos = atomicAdd(&fill[d], 1);
    int idx = rowptr[d] + pos;
    col[idx] = s;
    ew[idx] = dinv[s] * dinv[d];
}

// ---------------- gather: T[v] = dinv[v]^2 * X[v] + sum_j ew[j]*X[col[j]] ----------------

template <int VW>
__global__ __launch_bounds__(256) void k_gather(const float* __restrict__ X,
                                                const int* __restrict__ rowptr,
                                                const int* __restrict__ col,
                                                const float* __restrict__ ew,
                                                const float* __restrict__ dinv,
                                                float* __restrict__ T, int N, int F) {
    int t = blockIdx.x * blockDim.x + threadIdx.x;
    int FV = F / VW;
    if (t >= N * FV) return;
    int v = t / FV;
    int fi = (t % FV) * VW;
    float dv = dinv[v];
    float s = dv * dv;
    float acc[VW];
    {
        const float* xv = X + (size_t)v * F + fi;
#pragma unroll
        for (int u = 0; u < VW; u++) acc[u] = s * xv[u];
    }
    int beg = rowptr[v], end = rowptr[v + 1];
    for (int j = beg; j < end; j++) {
        int c = col[j];
        float w = ew[j];
        const float* xr = X + (size_t)c * F + fi;
        if (VW == 2) {
            float2 x2 = *(const float2*)xr;
            acc[0] = fmaf(w, x2.x, acc[0]);
            acc[VW - 1] = fmaf(w, x2.y, acc[VW - 1]);
        } else {
#pragma unroll
            for (int u = 0; u < VW; u++) acc[u] = fmaf(w, xr[u], acc[u]);
        }
    }
    float* tv = T + (size_t)v * F + fi;
#pragma unroll
    for (int u = 0; u < VW; u++) tv[u] = acc[u];
}

// ---------------- tiled GEMM: C = relu(A[N,K] @ W[K,Fout] + bias) ----------------

__global__ __launch_bounds__(256) void k_gemm_tiled(const float* __restrict__ A,
                                                    const float* __restrict__ W,
                                                    const float* __restrict__ bias,
                                                    float* __restrict__ C,
                                                    int N, int K, int Fout) {
    __shared__ __align__(16) float sA[KC * SA_STRIDE];
    __shared__ __align__(16) float sW[KC * CT];
    const int t = threadIdx.x;
    const int r0 = blockIdx.x * RT;
    const int c0 = blockIdx.y * CT;
    const int tx = t & 15;
    const int ty = t >> 4;

    float acc[8][8];
#pragma unroll
    for (int i = 0; i < 8; i++)
#pragma unroll
        for (int j = 0; j < 8; j++) acc[i][j] = 0.f;

    for (int kk = 0; kk < K; kk += KC) {
#pragma unroll
        for (int it = 0; it < 8; it++) {
            int i = it * 256 + t;
            int k = i & (KC - 1), row = i >> 4;
            float a = 0.f;
            int gk = kk + k, gr = r0 + row;
            if (gk < K && gr < N) a = A[(size_t)gr * K + gk];
            sA[k * SA_STRIDE + row] = a;
        }
#pragma unroll
        for (int it = 0; it < 8; it++) {
            int i = it * 256 + t;
            int k = i >> 7, c = i & 127;
            float w = 0.f;
            int gk = kk + k, gc = c0 + c;
            if (gk < K && gc < Fout) w = W[(size_t)gk * Fout + gc];
            sW[k * CT + c] = w;
        }
        __syncthreads();
#pragma unroll
        for (int k = 0; k < KC; ++k) {
            float4 av0 = *(const float4*)&sA[k * SA_STRIDE + ty * 8];
            float4 av1 = *(const float4*)&sA[k * SA_STRIDE + ty * 8 + 4];
            float4 wv0 = *(const float4*)&sW[k * CT + tx * 8];
            float4 wv1 = *(const float4*)&sW[k * CT + tx * 8 + 4];
            float ar[8] = {av0.x, av0.y, av0.z, av0.w, av1.x, av1.y, av1.z, av1.w};
            float wr[8] = {wv0.x, wv0.y, wv0.z, wv0.w, wv1.x, wv1.y, wv1.z, wv1.w};
#pragma unroll
            for (int i = 0; i < 8; i++)
#pragma unroll
                for (int j = 0; j < 8; j++) acc[i][j] = fmaf(ar[i], wr[j], acc[i][j]);
        }
        __syncthreads();
    }

    const bool vec4 = ((Fout & 3) == 0) && (c0 + tx * 8 + 7 < Fout);
#pragma unroll
    for (int rr = 0; rr < 8; rr++) {
        int row = r0 + ty * 8 + rr;
        if (row >= N) continue;
        float* crow = C + (size_t)row * Fout;
        if (vec4) {
            int c = c0 + tx * 8;
            float4 o0, o1;
            o0.x = fmaxf(acc[rr][0] + bias[c + 0], 0.f);
            o0.y = fmaxf(acc[rr][1] + bias[c + 1], 0.f);
            o0.z = fmaxf(acc[rr][2] + bias[c + 2], 0.f);
            o0.w = fmaxf(acc[rr][3] + bias[c + 3], 0.f);
            o1.x = fmaxf(acc[rr][4] + bias[c + 4], 0.f);
            o1.y = fmaxf(acc[rr][5] + bias[c + 5], 0.f);
            o1.z = fmaxf(acc[rr][6] + bias[c + 6], 0.f);
            o1.w = fmaxf(acc[rr][7] + bias[c + 7], 0.f);
            *(float4*)&crow[c] = o0;
            *(float4*)&crow[c + 4] = o1;
        } else {
#pragma unroll
            for (int cc = 0; cc < 8; cc++) {
                int c = c0 + tx * 8 + cc;
                if (c < Fout) crow[c] = fmaxf(acc[rr][cc] + bias[c], 0.f);
            }
        }
    }
}

// ---------------- per-graph max pool (batch sorted -> contiguous ranges) ----------------

__device__ __forceinline__ int d_lower_bound(const int* __restrict__ a, int n, int key) {
    int lo = 0, hi = n;
    while (lo < hi) {
        int mid = (lo + hi) >> 1;
        if (a[mid] < key) lo = mid + 1; else hi = mid;
    }
    return lo;
}

__global__ __launch_bounds__(320) void k_pool(const float* __restrict__ T,
                                              const int* __restrict__ batch,
                                              float* __restrict__ G, int N, int F) {
    int g = blockIdx.x;
    int c = threadIdx.x;
    if (c >= F) return;
    int start = d_lower_bound(batch, N, g);
    int end = d_lower_bound(batch, N, g + 1);
    float m = 0.f;  // inputs are relu'd (>=0)
    for (int r = start; r < end; ++r) m = fmaxf(m, T[(size_t)r * F + c]);
    G[(size_t)g * F + c] = m;
}

// ---------------- FC with LDS-staged A rows + unroll-8 W prefetch ----------------
// block stages BM = 256/(Nout/4) rows of A into LDS; thread computes one float4 of C.

__global__ __launch_bounds__(256) void k_fc_lds(const float* __restrict__ A,
                                                const float* __restrict__ W,
                                                const float* __restrict__ bias,
                                                float* __restrict__ C,
                                                int M, int K, int Nout, int do_relu) {
    extern __shared__ float sA[];   // BM * K floats
    const int t = threadIdx.x;
    const int NV = Nout >> 2;       // float4 groups per row (must divide 256)
    const int BM = 256 / NV;        // rows per block
    const int m0 = blockIdx.x * BM;

    for (int i = t; i < BM * K; i += 256) {
        int r = i / K, k = i - r * K;
        int gm = m0 + r;
        sA[i] = (gm < M) ? A[(size_t)gm * K + k] : 0.f;
    }
    __syncthreads();

    const int ml = t / NV;
    const int oc = (t - ml * NV) * 4;
    const int m = m0 + ml;
    if (m >= M) return;
    const float* a = sA + (size_t)ml * K;

    float4 acc = *(const float4*)&bias[oc];
    const int KM = K & ~7;
    int k = 0;
    for (; k < KM; k += 8) {
        float4 w[8];
#pragma unroll
        for (int u = 0; u < 8; u++)
            w[u] = *(const float4*)&W[(size_t)(k + u) * Nout + oc];
#pragma unroll
        for (int u = 0; u < 8; u++) {
            float av = a[k + u];
            acc.x = fmaf(av, w[u].x, acc.x);
            acc.y = fmaf(av, w[u].y, acc.y);
            acc.z = fmaf(av, w[u].z, acc.z);
            acc.w = fmaf(av, w[u].w, acc.w);
        }
    }
    for (; k < K; k++) {
        float4 wv = *(const float4*)&W[(size_t)k * Nout + oc];
        float av = a[k];
        acc.x = fmaf(av, wv.x, acc.x);
        acc.y = fmaf(av, wv.y, acc.y);
        acc.z = fmaf(av, wv.z, acc.z);
        acc.w = fmaf(av, wv.w, acc.w);
    }
    if (do_relu) {
        acc.x = fmaxf(acc.x, 0.f);
        acc.y = fmaxf(acc.y, 0.f);
        acc.z = fmaxf(acc.z, 0.f);
        acc.w = fmaxf(acc.w, 0.f);
    }
    *(float4*)&C[(size_t)m * Nout + oc] = acc;
}

// ---------------- launch ----------------

extern "C" void kernel_launch(void* const* d_in, const int* in_sizes, int n_in,
                              void* d_out, int out_size, void* d_ws, size_t ws_size,
                              hipStream_t stream) {
    const float* x     = (const float*)d_in[0];
    const int*   ei    = (const int*)d_in[1];
    const int*   batch = (const int*)d_in[2];
    const float* W1 = (const float*)d_in[3];
    const float* b1 = (const float*)d_in[4];
    const float* W2 = (const float*)d_in[5];
    const float* b2 = (const float*)d_in[6];
    const float* W3 = (const float*)d_in[7];
    const float* b3 = (const float*)d_in[8];
    const float* Wg1 = (const float*)d_in[9];
    const float* bg1 = (const float*)d_in[10];
    const float* Wg2 = (const float*)d_in[11];
    const float* bg2 = (const float*)d_in[12];

    const int N  = in_sizes[2];          // 50000
    const int E  = in_sizes[1] / 2;      // 800000
    const int F1 = in_sizes[4];          // 75
    const int F2 = in_sizes[6];          // 150
    const int F3 = in_sizes[8];          // 300
    const int H1 = in_sizes[10];         // 1024
    const int OC = in_sizes[12];         // 128
    const int NG = out_size / OC;        // 256
    const int FIN = in_sizes[3] / F1;    // 75

    const int* src = ei;
    const int* dst = ei + E;

    char* base = (char*)d_ws;
    size_t off = 0;
    auto alloc = [&](size_t bytes) -> void* {
        void* p = base + off;
        off = (off + bytes + 255) & ~(size_t)255;
        return p;
    };
    int*   cnt    = (int*)alloc((size_t)N * 4);
    int*   fill   = (int*)alloc((size_t)N * 4);
    int*   rowptr = (int*)alloc((size_t)(N + 1) * 4);
    float* dinv   = (float*)alloc((size_t)N * 4);
    int*   bsum   = (int*)alloc(256 * 4);
    int*   col    = (int*)alloc((size_t)E * 4);
    float* ew     = (float*)alloc((size_t)E * 4);
    float* Gb     = (float*)alloc((size_t)NG * F3 * 4);
    float* g1     = (float*)alloc((size_t)NG * H1 * 4);
    size_t SL = (size_t)N * F2;                    // 7.5M floats = 30MB
    float* big = (float*)alloc(3 * SL * 4);
    float* Xa = big;
    float* Ya = big + SL;
    float* Za = big + 2 * SL;
    float* T1g = Xa;
    float* H1b = Ya;
    float* T2g = Xa;
    float* H2b = Za;
    float* T3g = Xa;
    float* T3  = Ya;   // spans Ya+Za (60MB)

    hipMemsetAsync(cnt, 0, (size_t)N * 4, stream);
    hipMemsetAsync(fill, 0, (size_t)N * 4, stream);

    // ---- CSR ----
    k_count<<<ceil_div_i(E, 256), 256, 0, stream>>>(dst, E, cnt);
    k_dinv<<<ceil_div_i(N, 256), 256, 0, stream>>>(cnt, dinv, N);
    int NB = ceil_div_i(N, SCAN_B);
    k_scan1<<<NB, 256, 0, stream>>>(cnt, rowptr, bsum, N);
    k_scan2<<<1, 256, 0, stream>>>(bsum, NB);
    k_scan3<<<ceil_div_i(N, 256), 256, 0, stream>>>(rowptr, bsum, N, E);
    k_fill<<<ceil_div_i(E, 256), 256, 0, stream>>>(src, dst, E, rowptr, fill, dinv, col, ew);

    dim3 blk(256);

    // conv1
    k_gather<1><<<ceil_div_i((long long)N * FIN, 256), blk, 0, stream>>>(
        x, rowptr, col, ew, dinv, T1g, N, FIN);
    {
        dim3 g(ceil_div_i(N, RT), ceil_div_i(F1, CT));
        k_gemm_tiled<<<g, blk, 0, stream>>>(T1g, W1, b1, H1b, N, FIN, F1);
    }
    // conv2
    k_gather<1><<<ceil_div_i((long long)N * F1, 256), blk, 0, stream>>>(
        H1b, rowptr, col, ew, dinv, T2g, N, F1);
    {
        dim3 g(ceil_div_i(N, RT), ceil_div_i(F2, CT));
        k_gemm_tiled<<<g, blk, 0, stream>>>(T2g, W2, b2, H2b, N, F1, F2);
    }
    // conv3
    k_gather<2><<<ceil_div_i((long long)N * (F2 / 2), 256), blk, 0, stream>>>(
        H2b, rowptr, col, ew, dinv, T3g, N, F2);
    {
        dim3 g(ceil_div_i(N, RT), ceil_div_i(F3, CT));
        k_gemm_tiled<<<g, blk, 0, stream>>>(T3g, W3, b3, T3, N, F2, F3);
    }
    // pool
    k_pool<<<NG, 320, 0, stream>>>(T3, batch, Gb, N, F3);

    // fc_g1: BM = 256/(1024/4) = 1 row/block -> NG blocks, LDS = F3*4 = 1.2KB
    {
        int NV = H1 / 4;
        int BM = 256 / NV;
        int nblk = ceil_div_i(NG, BM);
        size_t lds = (size_t)BM * F3 * 4;
        k_fc_lds<<<nblk, 256, lds, stream>>>(Gb, Wg1, bg1, g1, NG, F3, H1, 1);
    }
    // fc_g2: BM = 256/(128/4) = 8 rows/block -> 32 blocks, LDS = 8*1024*4 = 32KB
    {
        int NV = OC / 4;
        int BM = 256 / NV;
        int nblk = ceil_div_i(NG, BM);
        size_t lds = (size_t)BM * H1 * 4;
        k_fc_lds<<<nblk, 256, lds, stream>>>(g1, Wg2, bg2, (float*)d_out, NG, H1, OC, 0);
    }
}

// Round 5
// 638.957 us; speedup vs baseline: 2.4677x; 1.3310x over previous
//
#include <hip/hip_runtime.h>
#include <math.h>

#define SCAN_B 1024
#define RT 128     // GEMM row tile
#define CT 128     // GEMM col tile
#define KC 16      // GEMM k chunk
#define SA_STRIDE (RT + 4)   // 132: write banks (4k+row)%32 -> 2-way (free); 16B-aligned reads

static inline int ceil_div_i(long long a, int b) { return (int)((a + b - 1) / b); }

// ---------------- CSR construction ----------------

__global__ __launch_bounds__(256) void k_count(const int* __restrict__ dst, int E,
                                               int* __restrict__ cnt) {
    int i = blockIdx.x * blockDim.x + threadIdx.x;
    if (i < E) atomicAdd(&cnt[dst[i]], 1);
}

__global__ __launch_bounds__(256) void k_dinv(const int* __restrict__ cnt,
                                              float* __restrict__ dinv, int N) {
    int i = blockIdx.x * blockDim.x + threadIdx.x;
    if (i < N) dinv[i] = (float)(1.0 / sqrt((double)(cnt[i] + 1)));
}

__global__ __launch_bounds__(256) void k_scan1(const int* __restrict__ cnt,
                                               int* __restrict__ rowptr,
                                               int* __restrict__ bsum, int N) {
    __shared__ int s[256];
    int tid = threadIdx.x;
    int base = blockIdx.x * SCAN_B + tid * 4;
    int a0 = (base + 0 < N) ? cnt[base + 0] : 0;
    int a1 = (base + 1 < N) ? cnt[base + 1] : 0;
    int a2 = (base + 2 < N) ? cnt[base + 2] : 0;
    int a3 = (base + 3 < N) ? cnt[base + 3] : 0;
    int tsum = a0 + a1 + a2 + a3;
    s[tid] = tsum;
    __syncthreads();
    for (int off = 1; off < 256; off <<= 1) {
        int val = 0;
        if (tid >= off) val = s[tid - off];
        __syncthreads();
        if (tid >= off) s[tid] += val;
        __syncthreads();
    }
    int texcl = s[tid] - tsum;
    if (tid == 255) bsum[blockIdx.x] = s[255];
    if (base + 0 < N) rowptr[base + 0] = texcl;
    if (base + 1 < N) rowptr[base + 1] = texcl + a0;
    if (base + 2 < N) rowptr[base + 2] = texcl + a0 + a1;
    if (base + 3 < N) rowptr[base + 3] = texcl + a0 + a1 + a2;
}

__global__ __launch_bounds__(256) void k_scan2(int* __restrict__ bsum, int NB) {
    __shared__ int s[256];
    int tid = threadIdx.x;
    int v = (tid < NB) ? bsum[tid] : 0;
    s[tid] = v;
    __syncthreads();
    for (int off = 1; off < 256; off <<= 1) {
        int val = 0;
        if (tid >= off) val = s[tid - off];
        __syncthreads();
        if (tid >= off) s[tid] += val;
        __syncthreads();
    }
    if (tid < NB) bsum[tid] = s[tid] - v;
}

__global__ __launch_bounds__(256) void k_scan3(int* __restrict__ rowptr,
                                               const int* __restrict__ bsum, int N, int E) {
    int i = blockIdx.x * blockDim.x + threadIdx.x;
    if (i < N) rowptr[i] += bsum[i >> 10];
    if (i == 0) rowptr[N] = E;
}

__global__ __launch_bounds__(256) void k_fill(const int* __restrict__ src,
                                              const int* __restrict__ dst, int E,
                                              const int* __restrict__ rowptr,
                                              int* __restrict__ fill,
                                              const float* __restrict__ dinv,
                                              int* __restrict__ col,
                                              float* __restrict__ ew) {
    int e = blockIdx.x * blockDim.x + threadIdx.x;
    if (e >= E) return;
    int s = src[e], d = dst[e];
    int pos = atomicAdd(&fill[d], 1);
    int idx = rowptr[d] + pos;
    col[idx] = s;
    ew[idx] = dinv[s] * dinv[d];
}

// ---------------- gather (wave-per-node): T[v] = dinv^2*X[v] + sum ew*X[col] ----------------
// One 64-lane wave owns node v; edge indices broadcast-loaded once per wave;
// neighbor rows read coalesced. VW=2 requires F even (float2-aligned rows).

template <int VW, int NCHUNK>
__global__ __launch_bounds__(256) void k_gather_w(const float* __restrict__ X,
                                                  const int* __restrict__ rowptr,
                                                  const int* __restrict__ col,
                                                  const float* __restrict__ ew,
                                                  const float* __restrict__ dinv,
                                                  float* __restrict__ T, int N, int F) {
    const int v = blockIdx.x * 4 + (threadIdx.x >> 6);
    const int lane = threadIdx.x & 63;
    if (v >= N) return;
    const float dv = dinv[v];
    const float s = dv * dv;

    int f0[NCHUNK];
    bool act[NCHUNK];
    float acc[NCHUNK][VW];
#pragma unroll
    for (int ch = 0; ch < NCHUNK; ch++) {
        f0[ch] = (ch * 64 + lane) * VW;
        act[ch] = f0[ch] < F;
#pragma unroll
        for (int u = 0; u < VW; u++) acc[ch][u] = 0.f;
        if (act[ch]) {
            const float* xv = X + (size_t)v * F + f0[ch];
#pragma unroll
            for (int u = 0; u < VW; u++) acc[ch][u] = s * xv[u];
        }
    }

    const int beg = rowptr[v], end = rowptr[v + 1];
    int j = beg;
    for (; j + 1 < end; j += 2) {
        int c0i = col[j], c1i = col[j + 1];
        float w0 = ew[j], w1 = ew[j + 1];
        const float* r0p = X + (size_t)c0i * F;
        const float* r1p = X + (size_t)c1i * F;
#pragma unroll
        for (int ch = 0; ch < NCHUNK; ch++) {
            if (!act[ch]) continue;
            if (VW == 2) {
                float2 x0 = *(const float2*)(r0p + f0[ch]);
                float2 x1 = *(const float2*)(r1p + f0[ch]);
                acc[ch][0] = fmaf(w0, x0.x, acc[ch][0]);
                acc[ch][VW - 1] = fmaf(w0, x0.y, acc[ch][VW - 1]);
                acc[ch][0] = fmaf(w1, x1.x, acc[ch][0]);
                acc[ch][VW - 1] = fmaf(w1, x1.y, acc[ch][VW - 1]);
            } else {
                acc[ch][0] = fmaf(w0, r0p[f0[ch]], acc[ch][0]);
                acc[ch][0] = fmaf(w1, r1p[f0[ch]], acc[ch][0]);
            }
        }
    }
    if (j < end) {
        int c0i = col[j];
        float w0 = ew[j];
        const float* r0p = X + (size_t)c0i * F;
#pragma unroll
        for (int ch = 0; ch < NCHUNK; ch++) {
            if (!act[ch]) continue;
            if (VW == 2) {
                float2 x0 = *(const float2*)(r0p + f0[ch]);
                acc[ch][0] = fmaf(w0, x0.x, acc[ch][0]);
                acc[ch][VW - 1] = fmaf(w0, x0.y, acc[ch][VW - 1]);
            } else {
                acc[ch][0] = fmaf(w0, r0p[f0[ch]], acc[ch][0]);
            }
        }
    }

#pragma unroll
    for (int ch = 0; ch < NCHUNK; ch++) {
        if (!act[ch]) continue;
        float* tv = T + (size_t)v * F + f0[ch];
#pragma unroll
        for (int u = 0; u < VW; u++) tv[u] = acc[ch][u];
    }
}

// ---------------- double-buffered tiled GEMM: C = relu(A[N,K] @ W[K,Fout] + bias) ----------------
// 128x128 / 256 threads / 8x8 micro-tile (split 4+4 rows & cols: conflict-free LDS reads).
// global->reg->LDS double-buffer pipeline, ONE barrier per K-chunk.

__global__ __launch_bounds__(256) void k_gemm_db(const float* __restrict__ A,
                                                 const float* __restrict__ W,
                                                 const float* __restrict__ bias,
                                                 float* __restrict__ C,
                                                 int N, int K, int Fout) {
    __shared__ __align__(16) float sA[2][KC * SA_STRIDE];
    __shared__ __align__(16) float sW[2][KC * CT];
    const int t = threadIdx.x;
    const int r0 = blockIdx.x * RT;
    const int c0 = blockIdx.y * CT;
    const int tx = t & 15;
    const int ty = t >> 4;
    const int nt = (K + KC - 1) / KC;

    float ra[8], rw[8];

    auto loadA = [&](int kk) {
#pragma unroll
        for (int it = 0; it < 8; it++) {
            int i = it * 256 + t;
            int k = i & (KC - 1), row = i >> 4;
            int gk = kk + k, gr = r0 + row;
            ra[it] = (gk < K && gr < N) ? A[(size_t)gr * K + gk] : 0.f;
        }
    };
    auto loadW = [&](int kk) {
#pragma unroll
        for (int it = 0; it < 8; it++) {
            int i = it * 256 + t;
            int k = i >> 7, c = i & 127;
            int gk = kk + k, gc = c0 + c;
            rw[it] = (gk < K && gc < Fout) ? W[(size_t)gk * Fout + gc] : 0.f;
        }
    };
    auto writeLDS = [&](int buf) {
#pragma unroll
        for (int it = 0; it < 8; it++) {
            int i = it * 256 + t;
            int k = i & (KC - 1), row = i >> 4;
            sA[buf][k * SA_STRIDE + row] = ra[it];
        }
#pragma unroll
        for (int it = 0; it < 8; it++) {
            int i = it * 256 + t;
            int k = i >> 7, c = i & 127;
            sW[buf][k * CT + c] = rw[it];
        }
    };

    float acc[8][8];
#pragma unroll
    for (int i = 0; i < 8; i++)
#pragma unroll
        for (int j = 0; j < 8; j++) acc[i][j] = 0.f;

    // prologue: chunk0 -> LDS buf0; chunk1 -> regs
    loadA(0);
    loadW(0);
    writeLDS(0);
    if (nt > 1) { loadA(KC); loadW(KC); }
    __syncthreads();

    int cur = 0;
    for (int tc = 0; tc < nt; ++tc) {
        if (tc + 1 < nt) writeLDS(cur ^ 1);               // regs hold chunk tc+1
        if (tc + 2 < nt) { loadA((tc + 2) * KC); loadW((tc + 2) * KC); }  // in-flight under compute
#pragma unroll
        for (int k = 0; k < KC; ++k) {
            float4 av0 = *(const float4*)&sA[cur][k * SA_STRIDE + ty * 4];
            float4 av1 = *(const float4*)&sA[cur][k * SA_STRIDE + 64 + ty * 4];
            float4 wv0 = *(const float4*)&sW[cur][k * CT + tx * 4];
            float4 wv1 = *(const float4*)&sW[cur][k * CT + 64 + tx * 4];
            float ar[8] = {av0.x, av0.y, av0.z, av0.w, av1.x, av1.y, av1.z, av1.w};
            float wr[8] = {wv0.x, wv0.y, wv0.z, wv0.w, wv1.x, wv1.y, wv1.z, wv1.w};
#pragma unroll
            for (int i = 0; i < 8; i++)
#pragma unroll
                for (int j = 0; j < 8; j++) acc[i][j] = fmaf(ar[i], wr[j], acc[i][j]);
        }
        __syncthreads();
        cur ^= 1;
    }

    // epilogue: bias + relu + store; rows {ty*4, 64+ty*4}, cols {tx*4, 64+tx*4}
#pragma unroll
    for (int rh = 0; rh < 2; rh++) {
#pragma unroll
        for (int rr = 0; rr < 4; rr++) {
            int row = r0 + rh * 64 + ty * 4 + rr;
            if (row >= N) continue;
            float* crow = C + (size_t)row * Fout;
            int ai = rh * 4 + rr;
#pragma unroll
            for (int chf = 0; chf < 2; chf++) {
                int c = c0 + chf * 64 + tx * 4;
                if (c + 3 < Fout) {
                    float4 o;
                    o.x = fmaxf(acc[ai][chf * 4 + 0] + bias[c + 0], 0.f);
                    o.y = fmaxf(acc[ai][chf * 4 + 1] + bias[c + 1], 0.f);
                    o.z = fmaxf(acc[ai][chf * 4 + 2] + bias[c + 2], 0.f);
                    o.w = fmaxf(acc[ai][chf * 4 + 3] + bias[c + 3], 0.f);
                    *(float4*)&crow[c] = o;
                } else {
#pragma unroll
                    for (int cc = 0; cc < 4; cc++) {
                        int gc = c + cc;
                        if (gc < Fout) crow[gc] = fmaxf(acc[ai][chf * 4 + cc] + bias[gc], 0.f);
                    }
                }
            }
        }
    }
}

// ---------------- per-graph max pool (batch sorted -> contiguous ranges) ----------------

__device__ __forceinline__ int d_lower_bound(const int* __restrict__ a, int n, int key) {
    int lo = 0, hi = n;
    while (lo < hi) {
        int mid = (lo + hi) >> 1;
        if (a[mid] < key) lo = mid + 1; else hi = mid;
    }
    return lo;
}

__global__ __launch_bounds__(320) void k_pool(const float* __restrict__ T,
                                              const int* __restrict__ batch,
                                              float* __restrict__ G, int N, int F) {
    int g = blockIdx.x;
    int c = threadIdx.x;
    if (c >= F) return;
    int start = d_lower_bound(batch, N, g);
    int end = d_lower_bound(batch, N, g + 1);
    float m = 0.f;  // inputs are relu'd (>=0)
    for (int r = start; r < end; ++r) m = fmaxf(m, T[(size_t)r * F + c]);
    G[(size_t)g * F + c] = m;
}

// ---------------- FC with LDS-staged A rows + unroll-8 W prefetch ----------------

__global__ __launch_bounds__(256) void k_fc_lds(const float* __restrict__ A,
                                                const float* __restrict__ W,
                                                const float* __restrict__ bias,
                                                float* __restrict__ C,
                                                int M, int K, int Nout, int do_relu) {
    extern __shared__ float sA[];   // BM * K floats
    const int t = threadIdx.x;
    const int NV = Nout >> 2;
    const int BM = 256 / NV;
    const int m0 = blockIdx.x * BM;

    for (int i = t; i < BM * K; i += 256) {
        int r = i / K, k = i - r * K;
        int gm = m0 + r;
        sA[i] = (gm < M) ? A[(size_t)gm * K + k] : 0.f;
    }
    __syncthreads();

    const int ml = t / NV;
    const int oc = (t - ml * NV) * 4;
    const int m = m0 + ml;
    if (m >= M) return;
    const float* a = sA + (size_t)ml * K;

    float4 acc = *(const float4*)&bias[oc];
    const int KM = K & ~7;
    int k = 0;
    for (; k < KM; k += 8) {
        float4 w[8];
#pragma unroll
        for (int u = 0; u < 8; u++)
            w[u] = *(const float4*)&W[(size_t)(k + u) * Nout + oc];
#pragma unroll
        for (int u = 0; u < 8; u++) {
            float av = a[k + u];
            acc.x = fmaf(av, w[u].x, acc.x);
            acc.y = fmaf(av, w[u].y, acc.y);
            acc.z = fmaf(av, w[u].z, acc.z);
            acc.w = fmaf(av, w[u].w, acc.w);
        }
    }
    for (; k < K; k++) {
        float4 wv = *(const float4*)&W[(size_t)k * Nout + oc];
        float av = a[k];
        acc.x = fmaf(av, wv.x, acc.x);
        acc.y = fmaf(av, wv.y, acc.y);
        acc.z = fmaf(av, wv.z, acc.z);
        acc.w = fmaf(av, wv.w, acc.w);
    }
    if (do_relu) {
        acc.x = fmaxf(acc.x, 0.f);
        acc.y = fmaxf(acc.y, 0.f);
        acc.z = fmaxf(acc.z, 0.f);
        acc.w = fmaxf(acc.w, 0.f);
    }
    *(float4*)&C[(size_t)m * Nout + oc] = acc;
}

// ---------------- launch ----------------

extern "C" void kernel_launch(void* const* d_in, const int* in_sizes, int n_in,
                              void* d_out, int out_size, void* d_ws, size_t ws_size,
                              hipStream_t stream) {
    const float* x     = (const float*)d_in[0];
    const int*   ei    = (const int*)d_in[1];
    const int*   batch = (const int*)d_in[2];
    const float* W1 = (const float*)d_in[3];
    const float* b1 = (const float*)d_in[4];
    const float* W2 = (const float*)d_in[5];
    const float* b2 = (const float*)d_in[6];
    const float* W3 = (const float*)d_in[7];
    const float* b3 = (const float*)d_in[8];
    const float* Wg1 = (const float*)d_in[9];
    const float* bg1 = (const float*)d_in[10];
    const float* Wg2 = (const float*)d_in[11];
    const float* bg2 = (const float*)d_in[12];

    const int N  = in_sizes[2];          // 50000
    const int E  = in_sizes[1] / 2;      // 800000
    const int F1 = in_sizes[4];          // 75
    const int F2 = in_sizes[6];          // 150
    const int F3 = in_sizes[8];          // 300
    const int H1 = in_sizes[10];         // 1024
    const int OC = in_sizes[12];         // 128
    const int NG = out_size / OC;        // 256
    const int FIN = in_sizes[3] / F1;    // 75

    const int* src = ei;
    const int* dst = ei + E;

    char* base = (char*)d_ws;
    size_t off = 0;
    auto alloc = [&](size_t bytes) -> void* {
        void* p = base + off;
        off = (off + bytes + 255) & ~(size_t)255;
        return p;
    };
    int*   cnt    = (int*)alloc((size_t)N * 4);
    int*   fill   = (int*)alloc((size_t)N * 4);
    int*   rowptr = (int*)alloc((size_t)(N + 1) * 4);
    float* dinv   = (float*)alloc((size_t)N * 4);
    int*   bsum   = (int*)alloc(256 * 4);
    int*   col    = (int*)alloc((size_t)E * 4);
    float* ew     = (float*)alloc((size_t)E * 4);
    float* Gb     = (float*)alloc((size_t)NG * F3 * 4);
    float* g1     = (float*)alloc((size_t)NG * H1 * 4);
    size_t SL = (size_t)N * F2;                    // 7.5M floats = 30MB
    float* big = (float*)alloc(3 * SL * 4);
    float* Xa = big;
    float* Ya = big + SL;
    float* Za = big + 2 * SL;
    float* T1g = Xa;
    float* H1b = Ya;
    float* T2g = Xa;
    float* H2b = Za;
    float* T3g = Xa;
    float* T3  = Ya;   // spans Ya+Za (60MB)

    hipMemsetAsync(cnt, 0, (size_t)N * 4, stream);
    hipMemsetAsync(fill, 0, (size_t)N * 4, stream);

    // ---- CSR ----
    k_count<<<ceil_div_i(E, 256), 256, 0, stream>>>(dst, E, cnt);
    k_dinv<<<ceil_div_i(N, 256), 256, 0, stream>>>(cnt, dinv, N);
    int NB = ceil_div_i(N, SCAN_B);
    k_scan1<<<NB, 256, 0, stream>>>(cnt, rowptr, bsum, N);
    k_scan2<<<1, 256, 0, stream>>>(bsum, NB);
    k_scan3<<<ceil_div_i(N, 256), 256, 0, stream>>>(rowptr, bsum, N, E);
    k_fill<<<ceil_div_i(E, 256), 256, 0, stream>>>(src, dst, E, rowptr, fill, dinv, col, ew);

    dim3 blk(256);
    int gw = ceil_div_i(N, 4);  // 4 waves per block, wave per node

    // conv1: gather F=75 (scalar lanes), GEMM 75->75
    k_gather_w<1, 2><<<gw, blk, 0, stream>>>(x, rowptr, col, ew, dinv, T1g, N, FIN);
    {
        dim3 g(ceil_div_i(N, RT), ceil_div_i(F1, CT));
        k_gemm_db<<<g, blk, 0, stream>>>(T1g, W1, b1, H1b, N, FIN, F1);
    }
    // conv2: gather F=75, GEMM 75->150
    k_gather_w<1, 2><<<gw, blk, 0, stream>>>(H1b, rowptr, col, ew, dinv, T2g, N, F1);
    {
        dim3 g(ceil_div_i(N, RT), ceil_div_i(F2, CT));
        k_gemm_db<<<g, blk, 0, stream>>>(T2g, W2, b2, H2b, N, F1, F2);
    }
    // conv3: gather F=150 (float2 lanes), GEMM 150->300
    k_gather_w<2, 2><<<gw, blk, 0, stream>>>(H2b, rowptr, col, ew, dinv, T3g, N, F2);
    {
        dim3 g(ceil_div_i(N, RT), ceil_div_i(F3, CT));
        k_gemm_db<<<g, blk, 0, stream>>>(T3g, W3, b3, T3, N, F2, F3);
    }
    // pool
    k_pool<<<NG, 320, 0, stream>>>(T3, batch, Gb, N, F3);

    // fc_g1: BM=1 row/block, LDS = 300*4 = 1.2KB
    {
        int NV = H1 / 4;
        int BM = 256 / NV;
        int nblk = ceil_div_i(NG, BM);
        size_t lds = (size_t)BM * F3 * 4;
        k_fc_lds<<<nblk, 256, lds, stream>>>(Gb, Wg1, bg1, g1, NG, F3, H1, 1);
    }
    // fc_g2: BM=8 rows/block, LDS = 8*1024*4 = 32KB
    {
        int NV = OC / 4;
        int BM = 256 / NV;
        int nblk = ceil_div_i(NG, BM);
        size_t lds = (size_t)BM * H1 * 4;
        k_fc_lds<<<nblk, 256, lds, stream>>>(g1, Wg2, bg2, (float*)d_out, NG, H1, OC, 0);
    }
}

// Round 6
// 506.608 us; speedup vs baseline: 3.1123x; 1.2612x over previous
//
#include <hip/hip_runtime.h>
#include <math.h>

#define SCAN_B 1024
#define LDST 40   // LDS row stride in bf16 elems (32 data + 8 pad)

typedef __attribute__((ext_vector_type(8))) short short8v;
typedef __attribute__((ext_vector_type(8))) unsigned short ushort8v;
typedef __attribute__((ext_vector_type(4))) float f32x4;

static inline int ceil_div_i(long long a, int b) { return (int)((a + b - 1) / b); }

__device__ __forceinline__ unsigned short f2bf(float x) {
    unsigned int u = __float_as_uint(x);
    u += 0x7fffu + ((u >> 16) & 1u);   // round-to-nearest-even
    return (unsigned short)(u >> 16);
}
__device__ __forceinline__ float bf2f(unsigned short h) {
    return __uint_as_float(((unsigned int)h) << 16);
}

// ---------------- CSR construction ----------------

__global__ __launch_bounds__(256) void k_count(const int* __restrict__ dst, int E,
                                               int* __restrict__ cnt) {
    int i = blockIdx.x * blockDim.x + threadIdx.x;
    if (i < E) atomicAdd(&cnt[dst[i]], 1);
}

__global__ __launch_bounds__(256) void k_dinv(const int* __restrict__ cnt,
                                              float* __restrict__ dinv, int N) {
    int i = blockIdx.x * blockDim.x + threadIdx.x;
    if (i < N) dinv[i] = (float)(1.0 / sqrt((double)(cnt[i] + 1)));
}

__global__ __launch_bounds__(256) void k_scan1(const int* __restrict__ cnt,
                                               int* __restrict__ rowptr,
                                               int* __restrict__ bsum, int N) {
    __shared__ int s[256];
    int tid = threadIdx.x;
    int base = blockIdx.x * SCAN_B + tid * 4;
    int a0 = (base + 0 < N) ? cnt[base + 0] : 0;
    int a1 = (base + 1 < N) ? cnt[base + 1] : 0;
    int a2 = (base + 2 < N) ? cnt[base + 2] : 0;
    int a3 = (base + 3 < N) ? cnt[base + 3] : 0;
    int tsum = a0 + a1 + a2 + a3;
    s[tid] = tsum;
    __syncthreads();
    for (int off = 1; off < 256; off <<= 1) {
        int val = 0;
        if (tid >= off) val = s[tid - off];
        __syncthreads();
        if (tid >= off) s[tid] += val;
        __syncthreads();
    }
    int texcl = s[tid] - tsum;
    if (tid == 255) bsum[blockIdx.x] = s[255];
    if (base + 0 < N) rowptr[base + 0] = texcl;
    if (base + 1 < N) rowptr[base + 1] = texcl + a0;
    if (base + 2 < N) rowptr[base + 2] = texcl + a0 + a1;
    if (base + 3 < N) rowptr[base + 3] = texcl + a0 + a1 + a2;
}

__global__ __launch_bounds__(256) void k_scan2(int* __restrict__ bsum, int NB) {
    __shared__ int s[256];
    int tid = threadIdx.x;
    int v = (tid < NB) ? bsum[tid] : 0;
    s[tid] = v;
    __syncthreads();
    for (int off = 1; off < 256; off <<= 1) {
        int val = 0;
        if (tid >= off) val = s[tid - off];
        __syncthreads();
        if (tid >= off) s[tid] += val;
        __syncthreads();
    }
    if (tid < NB) bsum[tid] = s[tid] - v;
}

__global__ __launch_bounds__(256) void k_scan3(int* __restrict__ rowptr,
                                               const int* __restrict__ bsum, int N, int E) {
    int i = blockIdx.x * blockDim.x + threadIdx.x;
    if (i < N) rowptr[i] += bsum[i >> 10];
    if (i == 0) rowptr[N] = E;
}

__global__ __launch_bounds__(256) void k_fill(const int* __restrict__ src,
                                              const int* __restrict__ dst, int E,
                                              const int* __restrict__ rowptr,
                                              int* __restrict__ fill,
                                              const float* __restrict__ dinv,
                                              int* __restrict__ col,
                                              float* __restrict__ ew) {
    int e = blockIdx.x * blockDim.x + threadIdx.x;
    if (e >= E) return;
    int s = src[e], d = dst[e];
    int pos = atomicAdd(&fill[d], 1);
    int idx = rowptr[d] + pos;
    col[idx] = s;
    ew[idx] = dinv[s] * dinv[d];
}

// ---------------- gather (wave-per-node): T[v] = dinv^2*X[v] + sum ew*X[col] ----------------
// Output rows zero-padded to stride KPf (16B-aligned rows for the MFMA GEMM staging).

template <int VW, int NCHUNK>
__global__ __launch_bounds__(256) void k_gather_w(const float* __restrict__ X,
                                                  const int* __restrict__ rowptr,
                                                  const int* __restrict__ col,
                                                  const float* __restrict__ ew,
                                                  const float* __restrict__ dinv,
                                                  float* __restrict__ T, int N, int F,
                                                  int KPf) {
    const int v = blockIdx.x * 4 + (threadIdx.x >> 6);
    const int lane = threadIdx.x & 63;
    if (v >= N) return;
    const float dv = dinv[v];
    const float s = dv * dv;

    int f0[NCHUNK];
    bool act[NCHUNK];
    float acc[NCHUNK][VW];
#pragma unroll
    for (int ch = 0; ch < NCHUNK; ch++) {
        f0[ch] = (ch * 64 + lane) * VW;
        act[ch] = f0[ch] < F;
#pragma unroll
        for (int u = 0; u < VW; u++) acc[ch][u] = 0.f;
        if (act[ch]) {
            const float* xv = X + (size_t)v * F + f0[ch];
#pragma unroll
            for (int u = 0; u < VW; u++) acc[ch][u] = s * xv[u];
        }
    }

    const int beg = rowptr[v], end = rowptr[v + 1];
    int j = beg;
    for (; j + 1 < end; j += 2) {
        int c0i = col[j], c1i = col[j + 1];
        float w0 = ew[j], w1 = ew[j + 1];
        const float* r0p = X + (size_t)c0i * F;
        const float* r1p = X + (size_t)c1i * F;
#pragma unroll
        for (int ch = 0; ch < NCHUNK; ch++) {
            if (!act[ch]) continue;
            if (VW == 2) {
                float2 x0 = *(const float2*)(r0p + f0[ch]);
                float2 x1 = *(const float2*)(r1p + f0[ch]);
                acc[ch][0] = fmaf(w0, x0.x, acc[ch][0]);
                acc[ch][VW - 1] = fmaf(w0, x0.y, acc[ch][VW - 1]);
                acc[ch][0] = fmaf(w1, x1.x, acc[ch][0]);
                acc[ch][VW - 1] = fmaf(w1, x1.y, acc[ch][VW - 1]);
            } else {
                acc[ch][0] = fmaf(w0, r0p[f0[ch]], acc[ch][0]);
                acc[ch][0] = fmaf(w1, r1p[f0[ch]], acc[ch][0]);
            }
        }
    }
    if (j < end) {
        int c0i = col[j];
        float w0 = ew[j];
        const float* r0p = X + (size_t)c0i * F;
#pragma unroll
        for (int ch = 0; ch < NCHUNK; ch++) {
            if (!act[ch]) continue;
            if (VW == 2) {
                float2 x0 = *(const float2*)(r0p + f0[ch]);
                acc[ch][0] = fmaf(w0, x0.x, acc[ch][0]);
                acc[ch][VW - 1] = fmaf(w0, x0.y, acc[ch][VW - 1]);
            } else {
                acc[ch][0] = fmaf(w0, r0p[f0[ch]], acc[ch][0]);
            }
        }
    }

#pragma unroll
    for (int ch = 0; ch < NCHUNK; ch++) {
        if (f0[ch] >= KPf) continue;
        float* tv = T + (size_t)v * KPf + f0[ch];
#pragma unroll
        for (int u = 0; u < VW; u++) tv[u] = acc[ch][u];   // pad lanes hold 0
    }
}

// ---------------- W preprocess: transpose + split into bf16 hi/lo, k-padded to KP --------

__global__ __launch_bounds__(256) void k_wsplit(const float* __restrict__ W,
                                                unsigned short* __restrict__ Wth,
                                                unsigned short* __restrict__ Wtl,
                                                int K, int Fout, int KP) {
    int i = blockIdx.x * blockDim.x + threadIdx.x;
    if (i >= Fout * KP) return;
    int c = i / KP, k = i - c * KP;
    float w = (k < K) ? W[(size_t)k * Fout + c] : 0.f;
    unsigned short h = f2bf(w);
    Wth[i] = h;
    Wtl[i] = f2bf(w - bf2f(h));
}

// ---------------- split-bf16 MFMA GEMM: out = relu(A @ W + bias) ----------------
// 128x128 tile, 256 thr = 4 waves, each wave 4x4 tiles of mfma_f32_16x16x32_bf16.
// D = Ah*Bh + Ah*Bl + Al*Bh (Al*Bl dropped, ~2^-18). A split on the fly from f32.
// MODE 0: store C with relu.  MODE 1: fused relu + per-graph max pool via atomicMax.

template <int MODE>
__global__ __launch_bounds__(256) void k_gemm_mfma(
    const float* __restrict__ A, int KPf,
    const unsigned short* __restrict__ Bth, const unsigned short* __restrict__ Btl,
    const float* __restrict__ bias, float* __restrict__ C,
    const int* __restrict__ batch, float* __restrict__ G,
    int N, int KP, int Fout) {
    __shared__ unsigned short sAh[128 * LDST];
    __shared__ unsigned short sAl[128 * LDST];
    __shared__ unsigned short sBh[128 * LDST];
    __shared__ unsigned short sBl[128 * LDST];
    __shared__ int sBatch[128];

    const int t = threadIdx.x;
    const int r0 = blockIdx.x * 128;
    const int c0 = blockIdx.y * 128;
    const int lane = t & 63;
    const int wv = t >> 6;
    const int wrow = (wv >> 1) * 64;
    const int wcol = (wv & 1) * 64;
    const int l15 = lane & 15;
    const int lk = (lane >> 4) * 8;
    const int nt = KP >> 5;

    const int srow = t >> 1;
    const int sseg = (t & 1) << 4;

    if (MODE == 1 && t < 128) sBatch[t] = (r0 + t < N) ? batch[r0 + t] : -1;

    const bool arow_ok = (r0 + srow) < N;
    const bool bcol_ok = (c0 + srow) < Fout;
    const float* aRow = A + (size_t)(r0 + srow) * KPf;
    const unsigned short* bhRow = Bth + (size_t)(c0 + srow) * KP;
    const unsigned short* blRow = Btl + (size_t)(c0 + srow) * KP;

    float av[16];
    ushort8v rbh0, rbh1, rbl0, rbl1;

    auto gload = [&](int kk) {
#pragma unroll
        for (int u = 0; u < 4; u++) {
            int gk = kk + sseg + u * 4;
            f32x4 f = {0.f, 0.f, 0.f, 0.f};
            if (arow_ok && gk < KPf) f = *(const f32x4*)&aRow[gk];
#pragma unroll
            for (int e = 0; e < 4; e++) av[u * 4 + e] = f[e];
        }
        if (bcol_ok) {
            const ushort8v* p = (const ushort8v*)&bhRow[kk + sseg];
            rbh0 = p[0];
            rbh1 = p[1];
            p = (const ushort8v*)&blRow[kk + sseg];
            rbl0 = p[0];
            rbl1 = p[1];
        } else {
#pragma unroll
            for (int e = 0; e < 8; e++) { rbh0[e] = 0; rbh1[e] = 0; rbl0[e] = 0; rbl1[e] = 0; }
        }
    };

    auto wlds = [&]() {
        int off = srow * LDST + sseg;
        ushort8v h0, h1, l0, l1;
#pragma unroll
        for (int e = 0; e < 8; e++) {
            unsigned short hh = f2bf(av[e]);
            h0[e] = hh;
            l0[e] = f2bf(av[e] - bf2f(hh));
        }
#pragma unroll
        for (int e = 0; e < 8; e++) {
            unsigned short hh = f2bf(av[8 + e]);
            h1[e] = hh;
            l1[e] = f2bf(av[8 + e] - bf2f(hh));
        }
        *(ushort8v*)&sAh[off] = h0;
        *(ushort8v*)&sAh[off + 8] = h1;
        *(ushort8v*)&sAl[off] = l0;
        *(ushort8v*)&sAl[off + 8] = l1;
        *(ushort8v*)&sBh[off] = rbh0;
        *(ushort8v*)&sBh[off + 8] = rbh1;
        *(ushort8v*)&sBl[off] = rbl0;
        *(ushort8v*)&sBl[off + 8] = rbl1;
    };

    f32x4 acc[4][4];
#pragma unroll
    for (int i = 0; i < 4; i++)
#pragma unroll
        for (int j = 0; j < 4; j++) acc[i][j] = (f32x4){0.f, 0.f, 0.f, 0.f};

    gload(0);
    for (int tc = 0; tc < nt; ++tc) {
        wlds();
        __syncthreads();
        if (tc + 1 < nt) gload((tc + 1) * 32);   // latency hides under MFMA below
        short8v ah[4], al[4];
#pragma unroll
        for (int i = 0; i < 4; i++) {
            int ro = (wrow + i * 16 + l15) * LDST + lk;
            ah[i] = *(const short8v*)&sAh[ro];
            al[i] = *(const short8v*)&sAl[ro];
        }
#pragma unroll
        for (int j = 0; j < 4; j++) {
            int co = (wcol + j * 16 + l15) * LDST + lk;
            short8v bh = *(const short8v*)&sBh[co];
            short8v bl = *(const short8v*)&sBl[co];
#pragma unroll
            for (int i = 0; i < 4; i++) {
                acc[i][j] = __builtin_amdgcn_mfma_f32_16x16x32_bf16(al[i], bh, acc[i][j], 0, 0, 0);
                acc[i][j] = __builtin_amdgcn_mfma_f32_16x16x32_bf16(ah[i], bl, acc[i][j], 0, 0, 0);
                acc[i][j] = __builtin_amdgcn_mfma_f32_16x16x32_bf16(ah[i], bh, acc[i][j], 0, 0, 0);
            }
        }
        __syncthreads();
    }

    // epilogue — C/D layout (m89-verified): col = lane&15, row = (lane>>4)*4 + reg
    if (MODE == 0) {
#pragma unroll
        for (int j = 0; j < 4; j++) {
            int gc = c0 + wcol + j * 16 + l15;
            if (gc >= Fout) continue;
            float bv = bias[gc];
#pragma unroll
            for (int i = 0; i < 4; i++) {
                int rb = r0 + wrow + i * 16 + (lane >> 4) * 4;
#pragma unroll
                for (int q = 0; q < 4; q++) {
                    int gr = rb + q;
                    if (gr < N) C[(size_t)gr * Fout + gc] = fmaxf(acc[i][j][q] + bv, 0.f);
                }
            }
        }
    } else {
#pragma unroll
        for (int j = 0; j < 4; j++) {
            int gc = c0 + wcol + j * 16 + l15;
            if (gc >= Fout) continue;
            float bv = bias[gc];
            int gcur = -1;
            float vmax = 0.f;
#pragma unroll
            for (int i = 0; i < 4; i++) {
                int lr = wrow + i * 16 + (lane >> 4) * 4;
#pragma unroll
                for (int q = 0; q < 4; q++) {
                    int g = sBatch[lr + q];
                    float vv = fmaxf(acc[i][j][q] + bv, 0.f);
                    if (g < 0) continue;
                    if (g != gcur) {
                        if (gcur >= 0)
                            atomicMax((int*)&G[(size_t)gcur * Fout + gc], __float_as_int(vmax));
                        gcur = g;
                        vmax = vv;
                    } else {
                        vmax = fmaxf(vmax, vv);
                    }
                }
            }
            if (gcur >= 0) atomicMax((int*)&G[(size_t)gcur * Fout + gc], __float_as_int(vmax));
        }
    }
}

// ---------------- FC: LDS-staged A rows, column-tiled, unroll-8 W prefetch ----------------

__global__ __launch_bounds__(256) void k_fc_lds(const float* __restrict__ A,
                                                const float* __restrict__ W,
                                                const float* __restrict__ bias,
                                                float* __restrict__ C,
                                                int M, int K, int Nout, int CTF, int do_relu) {
    extern __shared__ float sA[];   // BM * K floats
    const int t = threadIdx.x;
    const int NV = CTF >> 2;        // float4 groups per row in this col tile
    const int BM = 256 / NV;        // rows per block
    const int m0 = blockIdx.x * BM;
    const int cb = blockIdx.y * CTF;

    for (int i = t; i < BM * K; i += 256) {
        int r = i / K, k = i - r * K;
        int gm = m0 + r;
        sA[i] = (gm < M) ? A[(size_t)gm * K + k] : 0.f;
    }
    __syncthreads();

    const int ml = t / NV;
    const int oc = cb + (t - ml * NV) * 4;
    const int m = m0 + ml;
    if (m >= M) return;
    const float* a = sA + (size_t)ml * K;

    float4 acc = *(const float4*)&bias[oc];
    const int KM = K & ~7;
    int k = 0;
    for (; k < KM; k += 8) {
        float4 w[8];
#pragma unroll
        for (int u = 0; u < 8; u++)
            w[u] = *(const float4*)&W[(size_t)(k + u) * Nout + oc];
#pragma unroll
        for (int u = 0; u < 8; u++) {
            float avv = a[k + u];
            acc.x = fmaf(avv, w[u].x, acc.x);
            acc.y = fmaf(avv, w[u].y, acc.y);
            acc.z = fmaf(avv, w[u].z, acc.z);
            acc.w = fmaf(avv, w[u].w, acc.w);
        }
    }
    for (; k < K; k++) {
        float4 wv = *(const float4*)&W[(size_t)k * Nout + oc];
        float avv = a[k];
        acc.x = fmaf(avv, wv.x, acc.x);
        acc.y = fmaf(avv, wv.y, acc.y);
        acc.z = fmaf(avv, wv.z, acc.z);
        acc.w = fmaf(avv, wv.w, acc.w);
    }
    if (do_relu) {
        acc.x = fmaxf(acc.x, 0.f);
        acc.y = fmaxf(acc.y, 0.f);
        acc.z = fmaxf(acc.z, 0.f);
        acc.w = fmaxf(acc.w, 0.f);
    }
    *(float4*)&C[(size_t)m * Nout + oc] = acc;
}

// ---------------- launch ----------------

extern "C" void kernel_launch(void* const* d_in, const int* in_sizes, int n_in,
                              void* d_out, int out_size, void* d_ws, size_t ws_size,
                              hipStream_t stream) {
    const float* x     = (const float*)d_in[0];
    const int*   ei    = (const int*)d_in[1];
    const int*   batch = (const int*)d_in[2];
    const float* W1 = (const float*)d_in[3];
    const float* b1 = (const float*)d_in[4];
    const float* W2 = (const float*)d_in[5];
    const float* b2 = (const float*)d_in[6];
    const float* W3 = (const float*)d_in[7];
    const float* b3 = (const float*)d_in[8];
    const float* Wg1 = (const float*)d_in[9];
    const float* bg1 = (const float*)d_in[10];
    const float* Wg2 = (const float*)d_in[11];
    const float* bg2 = (const float*)d_in[12];

    const int N  = in_sizes[2];          // 50000
    const int E  = in_sizes[1] / 2;      // 800000
    const int F1 = in_sizes[4];          // 75
    const int F2 = in_sizes[6];          // 150
    const int F3 = in_sizes[8];          // 300
    const int H1 = in_sizes[10];         // 1024
    const int OC = in_sizes[12];         // 128
    const int NG = out_size / OC;        // 256
    const int FIN = in_sizes[3] / F1;    // 75

    const int KP1 = 96,  KPf1 = 80;      // K=75 padded
    const int KP3 = 160, KPf3 = 152;     // K=150 padded

    const int* src = ei;
    const int* dst = ei + E;

    char* base = (char*)d_ws;
    size_t off = 0;
    auto alloc = [&](size_t bytes) -> void* {
        void* p = base + off;
        off = (off + bytes + 255) & ~(size_t)255;
        return p;
    };
    int*   cnt    = (int*)alloc((size_t)N * 4);
    int*   fill   = (int*)alloc((size_t)N * 4);
    int*   rowptr = (int*)alloc((size_t)(N + 1) * 4);
    float* dinv   = (float*)alloc((size_t)N * 4);
    int*   bsum   = (int*)alloc(256 * 4);
    int*   col    = (int*)alloc((size_t)E * 4);
    float* ew     = (float*)alloc((size_t)E * 4);
    unsigned short* W1th = (unsigned short*)alloc((size_t)F1 * KP1 * 2);
    unsigned short* W1tl = (unsigned short*)alloc((size_t)F1 * KP1 * 2);
    unsigned short* W2th = (unsigned short*)alloc((size_t)F2 * KP1 * 2);
    unsigned short* W2tl = (unsigned short*)alloc((size_t)F2 * KP1 * 2);
    unsigned short* W3th = (unsigned short*)alloc((size_t)F3 * KP3 * 2);
    unsigned short* W3tl = (unsigned short*)alloc((size_t)F3 * KP3 * 2);
    float* Gb  = (float*)alloc((size_t)NG * F3 * 4);
    float* g1  = (float*)alloc((size_t)NG * H1 * 4);
    float* Tg  = (float*)alloc((size_t)N * KPf3 * 4);          // 30.4 MB (holds KPf1 case too)
    float* H1b = (float*)alloc((size_t)N * (F1 + F2) * 4);     // H1 | H2, 45 MB
    float* H2b = H1b + (size_t)N * F1;

    hipMemsetAsync(cnt, 0, (size_t)N * 4, stream);
    hipMemsetAsync(fill, 0, (size_t)N * 4, stream);
    hipMemsetAsync(Gb, 0, (size_t)NG * F3 * 4, stream);

    // ---- CSR ----
    k_count<<<ceil_div_i(E, 256), 256, 0, stream>>>(dst, E, cnt);
    k_dinv<<<ceil_div_i(N, 256), 256, 0, stream>>>(cnt, dinv, N);
    int NB = ceil_div_i(N, SCAN_B);
    k_scan1<<<NB, 256, 0, stream>>>(cnt, rowptr, bsum, N);
    k_scan2<<<1, 256, 0, stream>>>(bsum, NB);
    k_scan3<<<ceil_div_i(N, 256), 256, 0, stream>>>(rowptr, bsum, N, E);
    k_fill<<<ceil_div_i(E, 256), 256, 0, stream>>>(src, dst, E, rowptr, fill, dinv, col, ew);

    // ---- weight splits (tiny) ----
    k_wsplit<<<ceil_div_i((long long)F1 * KP1, 256), 256, 0, stream>>>(W1, W1th, W1tl, FIN, F1, KP1);
    k_wsplit<<<ceil_div_i((long long)F2 * KP1, 256), 256, 0, stream>>>(W2, W2th, W2tl, F1, F2, KP1);
    k_wsplit<<<ceil_div_i((long long)F3 * KP3, 256), 256, 0, stream>>>(W3, W3th, W3tl, F2, F3, KP3);

    dim3 blk(256);
    int gw = ceil_div_i(N, 4);
    int gx = ceil_div_i(N, 128);

    // conv1
    k_gather_w<1, 2><<<gw, blk, 0, stream>>>(x, rowptr, col, ew, dinv, Tg, N, FIN, KPf1);
    {
        dim3 g(gx, ceil_div_i(F1, 128));
        k_gemm_mfma<0><<<g, blk, 0, stream>>>(Tg, KPf1, W1th, W1tl, b1, H1b,
                                              nullptr, nullptr, N, KP1, F1);
    }
    // conv2
    k_gather_w<1, 2><<<gw, blk, 0, stream>>>(H1b, rowptr, col, ew, dinv, Tg, N, F1, KPf1);
    {
        dim3 g(gx, ceil_div_i(F2, 128));
        k_gemm_mfma<0><<<g, blk, 0, stream>>>(Tg, KPf1, W2th, W2tl, b2, H2b,
                                              nullptr, nullptr, N, KP1, F2);
    }
    // conv3 (+ fused relu + per-graph max pool)
    k_gather_w<2, 2><<<gw, blk, 0, stream>>>(H2b, rowptr, col, ew, dinv, Tg, N, F2, KPf3);
    {
        dim3 g(gx, ceil_div_i(F3, 128));
        k_gemm_mfma<1><<<g, blk, 0, stream>>>(Tg, KPf3, W3th, W3tl, b3, nullptr,
                                              batch, Gb, N, KP3, F3);
    }

    // fc_g1: col-tiled CTF=256 -> BM=4, grid (64, 4), LDS 4*300*4
    {
        int CTF = 256;
        int BM = 256 / (CTF / 4);
        dim3 g(ceil_div_i(NG, BM), H1 / CTF);
        size_t lds = (size_t)BM * F3 * 4;
        k_fc_lds<<<g, 256, lds, stream>>>(Gb, Wg1, bg1, g1, NG, F3, H1, CTF, 1);
    }
    // fc_g2: CTF=128 -> BM=8, grid (32, 1), LDS 32KB
    {
        int CTF = OC;
        int BM = 256 / (CTF / 4);
        dim3 g(ceil_div_i(NG, BM), OC / CTF);
        size_t lds = (size_t)BM * H1 * 4;
        k_fc_lds<<<g, 256, lds, stream>>>(g1, Wg2, bg2, (float*)d_out, NG, H1, OC, CTF, 0);
    }
}

// Round 7
// 443.862 us; speedup vs baseline: 3.5523x; 1.1414x over previous
//
#include <hip/hip_runtime.h>
#include <math.h>

#define SCAN_B 1024
#define LDST 40   // LDS row stride in bf16 elems (32 data + 8 pad)

typedef __attribute__((ext_vector_type(8))) short short8v;
typedef __attribute__((ext_vector_type(8))) unsigned short ushort8v;
typedef __attribute__((ext_vector_type(4))) float f32x4;

static inline int ceil_div_i(long long a, int b) { return (int)((a + b - 1) / b); }

__device__ __forceinline__ unsigned short f2bf(float x) {
    unsigned int u = __float_as_uint(x);
    u += 0x7fffu + ((u >> 16) & 1u);   // round-to-nearest-even
    return (unsigned short)(u >> 16);
}
__device__ __forceinline__ float bf2f(unsigned short h) {
    return __uint_as_float(((unsigned int)h) << 16);
}

// ---------------- CSR construction ----------------

__global__ __launch_bounds__(256) void k_count(const int* __restrict__ dst, int E,
                                               int* __restrict__ cnt) {
    int i = blockIdx.x * blockDim.x + threadIdx.x;
    if (i < E) atomicAdd(&cnt[dst[i]], 1);
}

__global__ __launch_bounds__(256) void k_dinv(const int* __restrict__ cnt,
                                              float* __restrict__ dinv, int N) {
    int i = blockIdx.x * blockDim.x + threadIdx.x;
    if (i < N) dinv[i] = (float)(1.0 / sqrt((double)(cnt[i] + 1)));
}

__global__ __launch_bounds__(256) void k_scan1(const int* __restrict__ cnt,
                                               int* __restrict__ rowptr,
                                               int* __restrict__ bsum, int N) {
    __shared__ int s[256];
    int tid = threadIdx.x;
    int base = blockIdx.x * SCAN_B + tid * 4;
    int a0 = (base + 0 < N) ? cnt[base + 0] : 0;
    int a1 = (base + 1 < N) ? cnt[base + 1] : 0;
    int a2 = (base + 2 < N) ? cnt[base + 2] : 0;
    int a3 = (base + 3 < N) ? cnt[base + 3] : 0;
    int tsum = a0 + a1 + a2 + a3;
    s[tid] = tsum;
    __syncthreads();
    for (int off = 1; off < 256; off <<= 1) {
        int val = 0;
        if (tid >= off) val = s[tid - off];
        __syncthreads();
        if (tid >= off) s[tid] += val;
        __syncthreads();
    }
    int texcl = s[tid] - tsum;
    if (tid == 255) bsum[blockIdx.x] = s[255];
    if (base + 0 < N) rowptr[base + 0] = texcl;
    if (base + 1 < N) rowptr[base + 1] = texcl + a0;
    if (base + 2 < N) rowptr[base + 2] = texcl + a0 + a1;
    if (base + 3 < N) rowptr[base + 3] = texcl + a0 + a1 + a2;
}

__global__ __launch_bounds__(256) void k_scan2(int* __restrict__ bsum, int NB) {
    __shared__ int s[256];
    int tid = threadIdx.x;
    int v = (tid < NB) ? bsum[tid] : 0;
    s[tid] = v;
    __syncthreads();
    for (int off = 1; off < 256; off <<= 1) {
        int val = 0;
        if (tid >= off) val = s[tid - off];
        __syncthreads();
        if (tid >= off) s[tid] += val;
        __syncthreads();
    }
    if (tid < NB) bsum[tid] = s[tid] - v;
}

__global__ __launch_bounds__(256) void k_scan3(int* __restrict__ rowptr,
                                               const int* __restrict__ bsum, int N, int E) {
    int i = blockIdx.x * blockDim.x + threadIdx.x;
    if (i < N) rowptr[i] += bsum[i >> 10];
    if (i == 0) rowptr[N] = E;
}

__global__ __launch_bounds__(256) void k_fill(const int* __restrict__ src,
                                              const int* __restrict__ dst, int E,
                                              const int* __restrict__ rowptr,
                                              int* __restrict__ fill,
                                              const float* __restrict__ dinv,
                                              int* __restrict__ col,
                                              float* __restrict__ ew) {
    int e = blockIdx.x * blockDim.x + threadIdx.x;
    if (e >= E) return;
    int s = src[e], d = dst[e];
    int pos = atomicAdd(&fill[d], 1);
    int idx = rowptr[d] + pos;
    col[idx] = s;
    ew[idx] = dinv[s] * dinv[d];
}

// ---------------- gather (wave-per-node, shfl-broadcast edges, unroll-4) ----------------
// T[v] = dinv^2*X[v] + sum ew*X[col]; output rows zero-padded to stride KPf.
// Edge metadata loaded 64-at-a-time by lanes (one coalesced load per ~4 nodes' worth),
// broadcast register-to-register via __shfl; 4 edges * NCHUNK rows of loads in flight.

template <int VW, int NCHUNK>
__global__ __launch_bounds__(256) void k_gather_w(const float* __restrict__ X,
                                                  const int* __restrict__ rowptr,
                                                  const int* __restrict__ col,
                                                  const float* __restrict__ ew,
                                                  const float* __restrict__ dinv,
                                                  float* __restrict__ T, int N, int F,
                                                  int KPf) {
    const int v = blockIdx.x * 4 + (threadIdx.x >> 6);
    const int lane = threadIdx.x & 63;
    if (v >= N) return;
    const float dv = dinv[v];
    const float s = dv * dv;

    int f0[NCHUNK];
    bool act[NCHUNK];
    float acc[NCHUNK][VW];
#pragma unroll
    for (int ch = 0; ch < NCHUNK; ch++) {
        f0[ch] = (ch * 64 + lane) * VW;
        act[ch] = f0[ch] < F;
#pragma unroll
        for (int u = 0; u < VW; u++) acc[ch][u] = 0.f;
        if (act[ch]) {
            const float* xv = X + (size_t)v * F + f0[ch];
#pragma unroll
            for (int u = 0; u < VW; u++) acc[ch][u] = s * xv[u];
        }
    }

    const int beg = rowptr[v], end = rowptr[v + 1];
    for (int jb = beg; jb < end; jb += 64) {
        const int nj = min(64, end - jb);
        int ec = 0;
        float ev = 0.f;
        if (jb + lane < end) {
            ec = col[jb + lane];
            ev = ew[jb + lane];
        }
        int e = 0;
        for (; e + 4 <= nj; e += 4) {
            int c[4];
            float w[4];
#pragma unroll
            for (int u = 0; u < 4; u++) {
                c[u] = __shfl(ec, e + u);
                w[u] = __shfl(ev, e + u);
            }
            const float* rp[4];
#pragma unroll
            for (int u = 0; u < 4; u++) rp[u] = X + (size_t)c[u] * F;
            if (VW == 2) {
                float2 xv[4][NCHUNK];
#pragma unroll
                for (int u = 0; u < 4; u++)
#pragma unroll
                    for (int ch = 0; ch < NCHUNK; ch++)
                        if (act[ch]) xv[u][ch] = *(const float2*)(rp[u] + f0[ch]);
#pragma unroll
                for (int u = 0; u < 4; u++)
#pragma unroll
                    for (int ch = 0; ch < NCHUNK; ch++)
                        if (act[ch]) {
                            acc[ch][0] = fmaf(w[u], xv[u][ch].x, acc[ch][0]);
                            acc[ch][VW - 1] = fmaf(w[u], xv[u][ch].y, acc[ch][VW - 1]);
                        }
            } else {
                float xv[4][NCHUNK];
#pragma unroll
                for (int u = 0; u < 4; u++)
#pragma unroll
                    for (int ch = 0; ch < NCHUNK; ch++)
                        if (act[ch]) xv[u][ch] = rp[u][f0[ch]];
#pragma unroll
                for (int u = 0; u < 4; u++)
#pragma unroll
                    for (int ch = 0; ch < NCHUNK; ch++)
                        if (act[ch]) acc[ch][0] = fmaf(w[u], xv[u][ch], acc[ch][0]);
            }
        }
        for (; e < nj; e++) {
            int c0 = __shfl(ec, e);
            float w0 = __shfl(ev, e);
            const float* rp = X + (size_t)c0 * F;
#pragma unroll
            for (int ch = 0; ch < NCHUNK; ch++) {
                if (!act[ch]) continue;
                if (VW == 2) {
                    float2 x0 = *(const float2*)(rp + f0[ch]);
                    acc[ch][0] = fmaf(w0, x0.x, acc[ch][0]);
                    acc[ch][VW - 1] = fmaf(w0, x0.y, acc[ch][VW - 1]);
                } else {
                    acc[ch][0] = fmaf(w0, rp[f0[ch]], acc[ch][0]);
                }
            }
        }
    }

#pragma unroll
    for (int ch = 0; ch < NCHUNK; ch++) {
        if (f0[ch] >= KPf) continue;
        float* tv = T + (size_t)v * KPf + f0[ch];
#pragma unroll
        for (int u = 0; u < VW; u++) tv[u] = acc[ch][u];   // pad lanes hold 0
    }
}

// ---------------- W preprocess: transpose + split into bf16 hi/lo, k-padded to KP --------

__global__ __launch_bounds__(256) void k_wsplit(const float* __restrict__ W,
                                                unsigned short* __restrict__ Wth,
                                                unsigned short* __restrict__ Wtl,
                                                int K, int Fout, int KP) {
    int i = blockIdx.x * blockDim.x + threadIdx.x;
    if (i >= Fout * KP) return;
    int c = i / KP, k = i - c * KP;
    float w = (k < K) ? W[(size_t)k * Fout + c] : 0.f;
    unsigned short h = f2bf(w);
    Wth[i] = h;
    Wtl[i] = f2bf(w - bf2f(h));
}

// ---------------- split-bf16 MFMA GEMM: out = relu(A @ W + bias) ----------------
// 128x128 tile, 256 thr = 4 waves, each wave 4x4 tiles of mfma_f32_16x16x32_bf16.
// D = Ah*Bh + Ah*Bl + Al*Bh (Al*Bl dropped, ~2^-18). A split on the fly from f32.
// MODE 0: store C with relu.  MODE 1: fused relu + per-graph max pool via atomicMax.

template <int MODE>
__global__ __launch_bounds__(256) void k_gemm_mfma(
    const float* __restrict__ A, int KPf,
    const unsigned short* __restrict__ Bth, const unsigned short* __restrict__ Btl,
    const float* __restrict__ bias, float* __restrict__ C,
    const int* __restrict__ batch, float* __restrict__ G,
    int N, int KP, int Fout) {
    __shared__ unsigned short sAh[128 * LDST];
    __shared__ unsigned short sAl[128 * LDST];
    __shared__ unsigned short sBh[128 * LDST];
    __shared__ unsigned short sBl[128 * LDST];
    __shared__ int sBatch[128];

    const int t = threadIdx.x;
    const int r0 = blockIdx.x * 128;
    const int c0 = blockIdx.y * 128;
    const int lane = t & 63;
    const int wv = t >> 6;
    const int wrow = (wv >> 1) * 64;
    const int wcol = (wv & 1) * 64;
    const int l15 = lane & 15;
    const int lk = (lane >> 4) * 8;
    const int nt = KP >> 5;

    const int srow = t >> 1;
    const int sseg = (t & 1) << 4;

    if (MODE == 1 && t < 128) sBatch[t] = (r0 + t < N) ? batch[r0 + t] : -1;

    const bool arow_ok = (r0 + srow) < N;
    const bool bcol_ok = (c0 + srow) < Fout;
    const float* aRow = A + (size_t)(r0 + srow) * KPf;
    const unsigned short* bhRow = Bth + (size_t)(c0 + srow) * KP;
    const unsigned short* blRow = Btl + (size_t)(c0 + srow) * KP;

    float av[16];
    ushort8v rbh0, rbh1, rbl0, rbl1;

    auto gload = [&](int kk) {
#pragma unroll
        for (int u = 0; u < 4; u++) {
            int gk = kk + sseg + u * 4;
            f32x4 f = {0.f, 0.f, 0.f, 0.f};
            if (arow_ok && gk < KPf) f = *(const f32x4*)&aRow[gk];
#pragma unroll
            for (int e = 0; e < 4; e++) av[u * 4 + e] = f[e];
        }
        if (bcol_ok) {
            const ushort8v* p = (const ushort8v*)&bhRow[kk + sseg];
            rbh0 = p[0];
            rbh1 = p[1];
            p = (const ushort8v*)&blRow[kk + sseg];
            rbl0 = p[0];
            rbl1 = p[1];
        } else {
#pragma unroll
            for (int e = 0; e < 8; e++) { rbh0[e] = 0; rbh1[e] = 0; rbl0[e] = 0; rbl1[e] = 0; }
        }
    };

    auto wlds = [&]() {
        int off = srow * LDST + sseg;
        ushort8v h0, h1, l0, l1;
#pragma unroll
        for (int e = 0; e < 8; e++) {
            unsigned short hh = f2bf(av[e]);
            h0[e] = hh;
            l0[e] = f2bf(av[e] - bf2f(hh));
        }
#pragma unroll
        for (int e = 0; e < 8; e++) {
            unsigned short hh = f2bf(av[8 + e]);
            h1[e] = hh;
            l1[e] = f2bf(av[8 + e] - bf2f(hh));
        }
        *(ushort8v*)&sAh[off] = h0;
        *(ushort8v*)&sAh[off + 8] = h1;
        *(ushort8v*)&sAl[off] = l0;
        *(ushort8v*)&sAl[off + 8] = l1;
        *(ushort8v*)&sBh[off] = rbh0;
        *(ushort8v*)&sBh[off + 8] = rbh1;
        *(ushort8v*)&sBl[off] = rbl0;
        *(ushort8v*)&sBl[off + 8] = rbl1;
    };

    f32x4 acc[4][4];
#pragma unroll
    for (int i = 0; i < 4; i++)
#pragma unroll
        for (int j = 0; j < 4; j++) acc[i][j] = (f32x4){0.f, 0.f, 0.f, 0.f};

    gload(0);
    for (int tc = 0; tc < nt; ++tc) {
        wlds();
        __syncthreads();
        if (tc + 1 < nt) gload((tc + 1) * 32);   // latency hides under MFMA below
        short8v ah[4], al[4];
#pragma unroll
        for (int i = 0; i < 4; i++) {
            int ro = (wrow + i * 16 + l15) * LDST + lk;
            ah[i] = *(const short8v*)&sAh[ro];
            al[i] = *(const short8v*)&sAl[ro];
        }
#pragma unroll
        for (int j = 0; j < 4; j++) {
            int co = (wcol + j * 16 + l15) * LDST + lk;
            short8v bh = *(const short8v*)&sBh[co];
            short8v bl = *(const short8v*)&sBl[co];
#pragma unroll
            for (int i = 0; i < 4; i++) {
                acc[i][j] = __builtin_amdgcn_mfma_f32_16x16x32_bf16(al[i], bh, acc[i][j], 0, 0, 0);
                acc[i][j] = __builtin_amdgcn_mfma_f32_16x16x32_bf16(ah[i], bl, acc[i][j], 0, 0, 0);
                acc[i][j] = __builtin_amdgcn_mfma_f32_16x16x32_bf16(ah[i], bh, acc[i][j], 0, 0, 0);
            }
        }
        __syncthreads();
    }

    // epilogue — C/D layout (m89-verified): col = lane&15, row = (lane>>4)*4 + reg
    if (MODE == 0) {
#pragma unroll
        for (int j = 0; j < 4; j++) {
            int gc = c0 + wcol + j * 16 + l15;
            if (gc >= Fout) continue;
            float bv = bias[gc];
#pragma unroll
            for (int i = 0; i < 4; i++) {
                int rb = r0 + wrow + i * 16 + (lane >> 4) * 4;
#pragma unroll
                for (int q = 0; q < 4; q++) {
                    int gr = rb + q;
                    if (gr < N) C[(size_t)gr * Fout + gc] = fmaxf(acc[i][j][q] + bv, 0.f);
                }
            }
        }
    } else {
#pragma unroll
        for (int j = 0; j < 4; j++) {
            int gc = c0 + wcol + j * 16 + l15;
            if (gc >= Fout) continue;
            float bv = bias[gc];
            int gcur = -1;
            float vmax = 0.f;
#pragma unroll
            for (int i = 0; i < 4; i++) {
                int lr = wrow + i * 16 + (lane >> 4) * 4;
#pragma unroll
                for (int q = 0; q < 4; q++) {
                    int g = sBatch[lr + q];
                    float vv = fmaxf(acc[i][j][q] + bv, 0.f);
                    if (g < 0) continue;
                    if (g != gcur) {
                        if (gcur >= 0)
                            atomicMax((int*)&G[(size_t)gcur * Fout + gc], __float_as_int(vmax));
                        gcur = g;
                        vmax = vv;
                    } else {
                        vmax = fmaxf(vmax, vv);
                    }
                }
            }
            if (gcur >= 0) atomicMax((int*)&G[(size_t)gcur * Fout + gc], __float_as_int(vmax));
        }
    }
}

// ---------------- FC: LDS-staged A rows, column-tiled, unroll-8 W prefetch ----------------

__global__ __launch_bounds__(256) void k_fc_lds(const float* __restrict__ A,
                                                const float* __restrict__ W,
                                                const float* __restrict__ bias,
                                                float* __restrict__ C,
                                                int M, int K, int Nout, int CTF, int do_relu) {
    extern __shared__ float sA[];   // BM * K floats
    const int t = threadIdx.x;
    const int NV = CTF >> 2;        // float4 groups per row in this col tile
    const int BM = 256 / NV;        // rows per block
    const int m0 = blockIdx.x * BM;
    const int cb = blockIdx.y * CTF;

    for (int i = t; i < BM * K; i += 256) {
        int r = i / K, k = i - r * K;
        int gm = m0 + r;
        sA[i] = (gm < M) ? A[(size_t)gm * K + k] : 0.f;
    }
    __syncthreads();

    const int ml = t / NV;
    const int oc = cb + (t - ml * NV) * 4;
    const int m = m0 + ml;
    if (m >= M) return;
    const float* a = sA + (size_t)ml * K;

    float4 acc = *(const float4*)&bias[oc];
    const int KM = K & ~7;
    int k = 0;
    for (; k < KM; k += 8) {
        float4 w[8];
#pragma unroll
        for (int u = 0; u < 8; u++)
            w[u] = *(const float4*)&W[(size_t)(k + u) * Nout + oc];
#pragma unroll
        for (int u = 0; u < 8; u++) {
            float avv = a[k + u];
            acc.x = fmaf(avv, w[u].x, acc.x);
            acc.y = fmaf(avv, w[u].y, acc.y);
            acc.z = fmaf(avv, w[u].z, acc.z);
            acc.w = fmaf(avv, w[u].w, acc.w);
        }
    }
    for (; k < K; k++) {
        float4 wv = *(const float4*)&W[(size_t)k * Nout + oc];
        float avv = a[k];
        acc.x = fmaf(avv, wv.x, acc.x);
        acc.y = fmaf(avv, wv.y, acc.y);
        acc.z = fmaf(avv, wv.z, acc.z);
        acc.w = fmaf(avv, wv.w, acc.w);
    }
    if (do_relu) {
        acc.x = fmaxf(acc.x, 0.f);
        acc.y = fmaxf(acc.y, 0.f);
        acc.z = fmaxf(acc.z, 0.f);
        acc.w = fmaxf(acc.w, 0.f);
    }
    *(float4*)&C[(size_t)m * Nout + oc] = acc;
}

// ---------------- launch ----------------

extern "C" void kernel_launch(void* const* d_in, const int* in_sizes, int n_in,
                              void* d_out, int out_size, void* d_ws, size_t ws_size,
                              hipStream_t stream) {
    const float* x     = (const float*)d_in[0];
    const int*   ei    = (const int*)d_in[1];
    const int*   batch = (const int*)d_in[2];
    const float* W1 = (const float*)d_in[3];
    const float* b1 = (const float*)d_in[4];
    const float* W2 = (const float*)d_in[5];
    const float* b2 = (const float*)d_in[6];
    const float* W3 = (const float*)d_in[7];
    const float* b3 = (const float*)d_in[8];
    const float* Wg1 = (const float*)d_in[9];
    const float* bg1 = (const float*)d_in[10];
    const float* Wg2 = (const float*)d_in[11];
    const float* bg2 = (const float*)d_in[12];

    const int N  = in_sizes[2];          // 50000
    const int E  = in_sizes[1] / 2;      // 800000
    const int F1 = in_sizes[4];          // 75
    const int F2 = in_sizes[6];          // 150
    const int F3 = in_sizes[8];          // 300
    const int H1 = in_sizes[10];         // 1024
    const int OC = in_sizes[12];         // 128
    const int NG = out_size / OC;        // 256
    const int FIN = in_sizes[3] / F1;    // 75

    const int KP1 = 96,  KPf1 = 80;      // K=75 padded
    const int KP3 = 160, KPf3 = 152;     // K=150 padded

    const int* src = ei;
    const int* dst = ei + E;

    char* base = (char*)d_ws;
    size_t off = 0;
    auto alloc = [&](size_t bytes) -> void* {
        void* p = base + off;
        off = (off + bytes + 255) & ~(size_t)255;
        return p;
    };
    int*   cnt    = (int*)alloc((size_t)N * 4);
    int*   fill   = (int*)alloc((size_t)N * 4);
    int*   rowptr = (int*)alloc((size_t)(N + 1) * 4);
    float* dinv   = (float*)alloc((size_t)N * 4);
    int*   bsum   = (int*)alloc(256 * 4);
    int*   col    = (int*)alloc((size_t)E * 4);
    float* ew     = (float*)alloc((size_t)E * 4);
    unsigned short* W1th = (unsigned short*)alloc((size_t)F1 * KP1 * 2);
    unsigned short* W1tl = (unsigned short*)alloc((size_t)F1 * KP1 * 2);
    unsigned short* W2th = (unsigned short*)alloc((size_t)F2 * KP1 * 2);
    unsigned short* W2tl = (unsigned short*)alloc((size_t)F2 * KP1 * 2);
    unsigned short* W3th = (unsigned short*)alloc((size_t)F3 * KP3 * 2);
    unsigned short* W3tl = (unsigned short*)alloc((size_t)F3 * KP3 * 2);
    float* Gb  = (float*)alloc((size_t)NG * F3 * 4);
    float* g1  = (float*)alloc((size_t)NG * H1 * 4);
    float* Tg  = (float*)alloc((size_t)N * KPf3 * 4);          // 30.4 MB (holds KPf1 case too)
    float* H1b = (float*)alloc((size_t)N * (F1 + F2) * 4);     // H1 | H2, 45 MB
    float* H2b = H1b + (size_t)N * F1;

    hipMemsetAsync(cnt, 0, (size_t)N * 4, stream);
    hipMemsetAsync(fill, 0, (size_t)N * 4, stream);
    hipMemsetAsync(Gb, 0, (size_t)NG * F3 * 4, stream);

    // ---- CSR ----
    k_count<<<ceil_div_i(E, 256), 256, 0, stream>>>(dst, E, cnt);
    k_dinv<<<ceil_div_i(N, 256), 256, 0, stream>>>(cnt, dinv, N);
    int NB = ceil_div_i(N, SCAN_B);
    k_scan1<<<NB, 256, 0, stream>>>(cnt, rowptr, bsum, N);
    k_scan2<<<1, 256, 0, stream>>>(bsum, NB);
    k_scan3<<<ceil_div_i(N, 256), 256, 0, stream>>>(rowptr, bsum, N, E);
    k_fill<<<ceil_div_i(E, 256), 256, 0, stream>>>(src, dst, E, rowptr, fill, dinv, col, ew);

    // ---- weight splits (tiny) ----
    k_wsplit<<<ceil_div_i((long long)F1 * KP1, 256), 256, 0, stream>>>(W1, W1th, W1tl, FIN, F1, KP1);
    k_wsplit<<<ceil_div_i((long long)F2 * KP1, 256), 256, 0, stream>>>(W2, W2th, W2tl, F1, F2, KP1);
    k_wsplit<<<ceil_div_i((long long)F3 * KP3, 256), 256, 0, stream>>>(W3, W3th, W3tl, F2, F3, KP3);

    dim3 blk(256);
    int gw = ceil_div_i(N, 4);
    int gx = ceil_div_i(N, 128);

    // conv1
    k_gather_w<1, 2><<<gw, blk, 0, stream>>>(x, rowptr, col, ew, dinv, Tg, N, FIN, KPf1);
    {
        dim3 g(gx, ceil_div_i(F1, 128));
        k_gemm_mfma<0><<<g, blk, 0, stream>>>(Tg, KPf1, W1th, W1tl, b1, H1b,
                                              nullptr, nullptr, N, KP1, F1);
    }
    // conv2
    k_gather_w<1, 2><<<gw, blk, 0, stream>>>(H1b, rowptr, col, ew, dinv, Tg, N, F1, KPf1);
    {
        dim3 g(gx, ceil_div_i(F2, 128));
        k_gemm_mfma<0><<<g, blk, 0, stream>>>(Tg, KPf1, W2th, W2tl, b2, H2b,
                                              nullptr, nullptr, N, KP1, F2);
    }
    // conv3 (+ fused relu + per-graph max pool)
    k_gather_w<2, 2><<<gw, blk, 0, stream>>>(H2b, rowptr, col, ew, dinv, Tg, N, F2, KPf3);
    {
        dim3 g(gx, ceil_div_i(F3, 128));
        k_gemm_mfma<1><<<g, blk, 0, stream>>>(Tg, KPf3, W3th, W3tl, b3, nullptr,
                                              batch, Gb, N, KP3, F3);
    }

    // fc_g1: col-tiled CTF=256 -> BM=4, grid (64, 4), LDS 4*300*4
    {
        int CTF = 256;
        int BM = 256 / (CTF / 4);
        dim3 g(ceil_div_i(NG, BM), H1 / CTF);
        size_t lds = (size_t)BM * F3 * 4;
        k_fc_lds<<<g, 256, lds, stream>>>(Gb, Wg1, bg1, g1, NG, F3, H1, CTF, 1);
    }
    // fc_g2: CTF=128 -> BM=8, grid (32, 1), LDS 32KB
    {
        int CTF = OC;
        int BM = 256 / (CTF / 4);
        dim3 g(ceil_div_i(NG, BM), OC / CTF);
        size_t lds = (size_t)BM * H1 * 4;
        k_fc_lds<<<g, 256, lds, stream>>>(g1, Wg2, bg2, (float*)d_out, NG, H1, OC, CTF, 0);
    }
}

// Round 8
// 441.881 us; speedup vs baseline: 3.5682x; 1.0045x over previous
//
#include <hip/hip_runtime.h>
#include <math.h>

#define SCAN_B 1024
#define LDST 40   // LDS row stride in bf16 elems (32 data + 8 pad)

typedef __attribute__((ext_vector_type(8))) short short8v;
typedef __attribute__((ext_vector_type(8))) unsigned short ushort8v;
typedef __attribute__((ext_vector_type(4))) float f32x4;

static inline int ceil_div_i(long long a, int b) { return (int)((a + b - 1) / b); }

__device__ __forceinline__ unsigned short f2bf(float x) {
    unsigned int u = __float_as_uint(x);
    u += 0x7fffu + ((u >> 16) & 1u);   // round-to-nearest-even
    return (unsigned short)(u >> 16);
}
__device__ __forceinline__ float bf2f(unsigned short h) {
    return __uint_as_float(((unsigned int)h) << 16);
}

// ---------------- CSR construction ----------------

__global__ __launch_bounds__(256) void k_count(const int* __restrict__ dst, int E,
                                               int* __restrict__ cnt) {
    int i = blockIdx.x * blockDim.x + threadIdx.x;
    if (i < E) atomicAdd(&cnt[dst[i]], 1);
}

__global__ __launch_bounds__(256) void k_dinv(const int* __restrict__ cnt,
                                              float* __restrict__ dinv, int N) {
    int i = blockIdx.x * blockDim.x + threadIdx.x;
    if (i < N) dinv[i] = (float)(1.0 / sqrt((double)(cnt[i] + 1)));
}

__global__ __launch_bounds__(256) void k_scan1(const int* __restrict__ cnt,
                                               int* __restrict__ rowptr,
                                               int* __restrict__ bsum, int N) {
    __shared__ int s[256];
    int tid = threadIdx.x;
    int base = blockIdx.x * SCAN_B + tid * 4;
    int a0 = (base + 0 < N) ? cnt[base + 0] : 0;
    int a1 = (base + 1 < N) ? cnt[base + 1] : 0;
    int a2 = (base + 2 < N) ? cnt[base + 2] : 0;
    int a3 = (base + 3 < N) ? cnt[base + 3] : 0;
    int tsum = a0 + a1 + a2 + a3;
    s[tid] = tsum;
    __syncthreads();
    for (int off = 1; off < 256; off <<= 1) {
        int val = 0;
        if (tid >= off) val = s[tid - off];
        __syncthreads();
        if (tid >= off) s[tid] += val;
        __syncthreads();
    }
    int texcl = s[tid] - tsum;
    if (tid == 255) bsum[blockIdx.x] = s[255];
    if (base + 0 < N) rowptr[base + 0] = texcl;
    if (base + 1 < N) rowptr[base + 1] = texcl + a0;
    if (base + 2 < N) rowptr[base + 2] = texcl + a0 + a1;
    if (base + 3 < N) rowptr[base + 3] = texcl + a0 + a1 + a2;
}

__global__ __launch_bounds__(256) void k_scan2(int* __restrict__ bsum, int NB) {
    __shared__ int s[256];
    int tid = threadIdx.x;
    int v = (tid < NB) ? bsum[tid] : 0;
    s[tid] = v;
    __syncthreads();
    for (int off = 1; off < 256; off <<= 1) {
        int val = 0;
        if (tid >= off) val = s[tid - off];
        __syncthreads();
        if (tid >= off) s[tid] += val;
        __syncthreads();
    }
    if (tid < NB) bsum[tid] = s[tid] - v;
}

__global__ __launch_bounds__(256) void k_scan3(int* __restrict__ rowptr,
                                               const int* __restrict__ bsum, int N, int E) {
    int i = blockIdx.x * blockDim.x + threadIdx.x;
    if (i < N) rowptr[i] += bsum[i >> 10];
    if (i == 0) rowptr[N] = E;
}

__global__ __launch_bounds__(256) void k_fill(const int* __restrict__ src,
                                              const int* __restrict__ dst, int E,
                                              const int* __restrict__ rowptr,
                                              int* __restrict__ fill,
                                              const float* __restrict__ dinv,
                                              int* __restrict__ col,
                                              float* __restrict__ ew) {
    int e = blockIdx.x * blockDim.x + threadIdx.x;
    if (e >= E) return;
    int s = src[e], d = dst[e];
    int pos = atomicAdd(&fill[d], 1);
    int idx = rowptr[d] + pos;
    col[idx] = s;
    ew[idx] = dinv[s] * dinv[d];
}

// ---------------- gather (wave-per-node, shfl-broadcast edges, unroll-UNR) -------------
// T[v] = dinv^2*X[v] + sum ew*X[col].  X rows at stride XS (may include pad cols, which
// must be finite); T rows at stride KPf; inactive-lane writes land exact zeros in T pads.
// VW=4 requires XS%4==0 (16B-aligned rows).

template <int VW, int NCHUNK, int UNR>
__global__ __launch_bounds__(256) void k_gather_w(const float* __restrict__ X,
                                                  const int* __restrict__ rowptr,
                                                  const int* __restrict__ col,
                                                  const float* __restrict__ ew,
                                                  const float* __restrict__ dinv,
                                                  float* __restrict__ T, int N, int F,
                                                  int XS, int KPf) {
    const int v = blockIdx.x * 4 + (threadIdx.x >> 6);
    const int lane = threadIdx.x & 63;
    if (v >= N) return;
    const float dv = dinv[v];
    const float s = dv * dv;

    int f0[NCHUNK];
    bool act[NCHUNK];
    float acc[NCHUNK][VW];
#pragma unroll
    for (int ch = 0; ch < NCHUNK; ch++) {
        f0[ch] = (ch * 64 + lane) * VW;
        act[ch] = f0[ch] < F;
#pragma unroll
        for (int u = 0; u < VW; u++) acc[ch][u] = 0.f;
        if (act[ch]) {
            const float* xv = X + (size_t)v * XS + f0[ch];
            if (VW == 4) {
                f32x4 t4 = *(const f32x4*)xv;
#pragma unroll
                for (int u = 0; u < VW; u++) acc[ch][u] = s * t4[u];
            } else {
#pragma unroll
                for (int u = 0; u < VW; u++) acc[ch][u] = s * xv[u];
            }
        }
    }

    const int beg = rowptr[v], end = rowptr[v + 1];
    for (int jb = beg; jb < end; jb += 64) {
        const int nj = min(64, end - jb);
        int ec = 0;
        float ev = 0.f;
        if (lane < nj) {
            ec = col[jb + lane];
            ev = ew[jb + lane];
        }
        int e = 0;
        for (; e + UNR <= nj; e += UNR) {
            int c[UNR];
            float w[UNR];
#pragma unroll
            for (int u = 0; u < UNR; u++) {
                c[u] = __shfl(ec, e + u);
                w[u] = __shfl(ev, e + u);
            }
            if (VW == 4) {
                f32x4 xv[UNR];
#pragma unroll
                for (int u = 0; u < UNR; u++)
                    if (act[0]) xv[u] = *(const f32x4*)(X + (size_t)c[u] * XS + f0[0]);
#pragma unroll
                for (int u = 0; u < UNR; u++)
                    if (act[0]) {
#pragma unroll
                        for (int k = 0; k < VW; k++)
                            acc[0][k] = fmaf(w[u], xv[u][k], acc[0][k]);
                    }
            } else {
                float xv[UNR][NCHUNK];
#pragma unroll
                for (int u = 0; u < UNR; u++)
#pragma unroll
                    for (int ch = 0; ch < NCHUNK; ch++)
                        if (act[ch]) xv[u][ch] = X[(size_t)c[u] * XS + f0[ch]];
#pragma unroll
                for (int u = 0; u < UNR; u++)
#pragma unroll
                    for (int ch = 0; ch < NCHUNK; ch++)
                        if (act[ch]) acc[ch][0] = fmaf(w[u], xv[u][ch], acc[ch][0]);
            }
        }
        for (; e < nj; e++) {
            int c0 = __shfl(ec, e);
            float w0 = __shfl(ev, e);
            const float* rp = X + (size_t)c0 * XS;
#pragma unroll
            for (int ch = 0; ch < NCHUNK; ch++) {
                if (!act[ch]) continue;
                if (VW == 4) {
                    f32x4 x4 = *(const f32x4*)(rp + f0[ch]);
#pragma unroll
                    for (int k = 0; k < VW; k++) acc[ch][k] = fmaf(w0, x4[k], acc[ch][k]);
                } else {
                    acc[ch][0] = fmaf(w0, rp[f0[ch]], acc[ch][0]);
                }
            }
        }
    }

#pragma unroll
    for (int ch = 0; ch < NCHUNK; ch++) {
        if (f0[ch] >= KPf) continue;
        float* tv = T + (size_t)v * KPf + f0[ch];
        if (VW == 4) {
            f32x4 o = {acc[ch][0], acc[ch][1], acc[ch][2], acc[ch][3]};
            *(f32x4*)tv = o;   // inactive lanes (f0 in [F,KPf)) write exact zeros
        } else {
#pragma unroll
            for (int u = 0; u < VW; u++) tv[u] = acc[ch][u];
        }
    }
}

// ---------------- W preprocess: transpose + split into bf16 hi/lo, k-padded to KP --------

__global__ __launch_bounds__(256) void k_wsplit(const float* __restrict__ W,
                                                unsigned short* __restrict__ Wth,
                                                unsigned short* __restrict__ Wtl,
                                                int K, int Fout, int KP) {
    int i = blockIdx.x * blockDim.x + threadIdx.x;
    if (i >= Fout * KP) return;
    int c = i / KP, k = i - c * KP;
    float w = (k < K) ? W[(size_t)k * Fout + c] : 0.f;
    unsigned short h = f2bf(w);
    Wth[i] = h;
    Wtl[i] = f2bf(w - bf2f(h));
}

// ---------------- split-bf16 MFMA GEMM: out = relu(A @ W + bias) ----------------
// 128x128 tile, 256 thr = 4 waves, each wave 4x4 tiles of mfma_f32_16x16x32_bf16.
// D = Ah*Bh + Ah*Bl + Al*Bh (Al*Bl dropped, ~2^-18). A split on the fly from f32.
// MODE 0: store C (row stride CS) with relu.  MODE 1: fused relu + max pool via atomicMax.

template <int MODE>
__global__ __launch_bounds__(256) void k_gemm_mfma(
    const float* __restrict__ A, int KPf,
    const unsigned short* __restrict__ Bth, const unsigned short* __restrict__ Btl,
    const float* __restrict__ bias, float* __restrict__ C, int CS,
    const int* __restrict__ batch, float* __restrict__ G,
    int N, int KP, int Fout) {
    __shared__ unsigned short sAh[128 * LDST];
    __shared__ unsigned short sAl[128 * LDST];
    __shared__ unsigned short sBh[128 * LDST];
    __shared__ unsigned short sBl[128 * LDST];
    __shared__ int sBatch[128];

    const int t = threadIdx.x;
    const int r0 = blockIdx.x * 128;
    const int c0 = blockIdx.y * 128;
    const int lane = t & 63;
    const int wv = t >> 6;
    const int wrow = (wv >> 1) * 64;
    const int wcol = (wv & 1) * 64;
    const int l15 = lane & 15;
    const int lk = (lane >> 4) * 8;
    const int nt = KP >> 5;

    const int srow = t >> 1;
    const int sseg = (t & 1) << 4;

    if (MODE == 1 && t < 128) sBatch[t] = (r0 + t < N) ? batch[r0 + t] : -1;

    const bool arow_ok = (r0 + srow) < N;
    const bool bcol_ok = (c0 + srow) < Fout;
    const float* aRow = A + (size_t)(r0 + srow) * KPf;
    const unsigned short* bhRow = Bth + (size_t)(c0 + srow) * KP;
    const unsigned short* blRow = Btl + (size_t)(c0 + srow) * KP;

    float av[16];
    ushort8v rbh0, rbh1, rbl0, rbl1;

    auto gload = [&](int kk) {
#pragma unroll
        for (int u = 0; u < 4; u++) {
            int gk = kk + sseg + u * 4;
            f32x4 f = {0.f, 0.f, 0.f, 0.f};
            if (arow_ok && gk < KPf) f = *(const f32x4*)&aRow[gk];
#pragma unroll
            for (int e = 0; e < 4; e++) av[u * 4 + e] = f[e];
        }
        if (bcol_ok) {
            const ushort8v* p = (const ushort8v*)&bhRow[kk + sseg];
            rbh0 = p[0];
            rbh1 = p[1];
            p = (const ushort8v*)&blRow[kk + sseg];
            rbl0 = p[0];
            rbl1 = p[1];
        } else {
#pragma unroll
            for (int e = 0; e < 8; e++) { rbh0[e] = 0; rbh1[e] = 0; rbl0[e] = 0; rbl1[e] = 0; }
        }
    };

    auto wlds = [&]() {
        int off = srow * LDST + sseg;
        ushort8v h0, h1, l0, l1;
#pragma unroll
        for (int e = 0; e < 8; e++) {
            unsigned short hh = f2bf(av[e]);
            h0[e] = hh;
            l0[e] = f2bf(av[e] - bf2f(hh));
        }
#pragma unroll
        for (int e = 0; e < 8; e++) {
            unsigned short hh = f2bf(av[8 + e]);
            h1[e] = hh;
            l1[e] = f2bf(av[8 + e] - bf2f(hh));
        }
        *(ushort8v*)&sAh[off] = h0;
        *(ushort8v*)&sAh[off + 8] = h1;
        *(ushort8v*)&sAl[off] = l0;
        *(ushort8v*)&sAl[off + 8] = l1;
        *(ushort8v*)&sBh[off] = rbh0;
        *(ushort8v*)&sBh[off + 8] = rbh1;
        *(ushort8v*)&sBl[off] = rbl0;
        *(ushort8v*)&sBl[off + 8] = rbl1;
    };

    f32x4 acc[4][4];
#pragma unroll
    for (int i = 0; i < 4; i++)
#pragma unroll
        for (int j = 0; j < 4; j++) acc[i][j] = (f32x4){0.f, 0.f, 0.f, 0.f};

    gload(0);
    for (int tc = 0; tc < nt; ++tc) {
        wlds();
        __syncthreads();
        if (tc + 1 < nt) gload((tc + 1) * 32);   // latency hides under MFMA below
        short8v ah[4], al[4];
#pragma unroll
        for (int i = 0; i < 4; i++) {
            int ro = (wrow + i * 16 + l15) * LDST + lk;
            ah[i] = *(const short8v*)&sAh[ro];
            al[i] = *(const short8v*)&sAl[ro];
        }
#pragma unroll
        for (int j = 0; j < 4; j++) {
            int co = (wcol + j * 16 + l15) * LDST + lk;
            short8v bh = *(const short8v*)&sBh[co];
            short8v bl = *(const short8v*)&sBl[co];
#pragma unroll
            for (int i = 0; i < 4; i++) {
                acc[i][j] = __builtin_amdgcn_mfma_f32_16x16x32_bf16(al[i], bh, acc[i][j], 0, 0, 0);
                acc[i][j] = __builtin_amdgcn_mfma_f32_16x16x32_bf16(ah[i], bl, acc[i][j], 0, 0, 0);
                acc[i][j] = __builtin_amdgcn_mfma_f32_16x16x32_bf16(ah[i], bh, acc[i][j], 0, 0, 0);
            }
        }
        __syncthreads();
    }

    // epilogue — C/D layout (m89-verified): col = lane&15, row = (lane>>4)*4 + reg
    if (MODE == 0) {
#pragma unroll
        for (int j = 0; j < 4; j++) {
            int gc = c0 + wcol + j * 16 + l15;
            if (gc >= Fout) continue;
            float bv = bias[gc];
#pragma unroll
            for (int i = 0; i < 4; i++) {
                int rb = r0 + wrow + i * 16 + (lane >> 4) * 4;
#pragma unroll
                for (int q = 0; q < 4; q++) {
                    int gr = rb + q;
                    if (gr < N) C[(size_t)gr * CS + gc] = fmaxf(acc[i][j][q] + bv, 0.f);
                }
            }
        }
    } else {
#pragma unroll
        for (int j = 0; j < 4; j++) {
            int gc = c0 + wcol + j * 16 + l15;
            if (gc >= Fout) continue;
            float bv = bias[gc];
            int gcur = -1;
            float vmax = 0.f;
#pragma unroll
            for (int i = 0; i < 4; i++) {
                int lr = wrow + i * 16 + (lane >> 4) * 4;
#pragma unroll
                for (int q = 0; q < 4; q++) {
                    int g = sBatch[lr + q];
                    float vv = fmaxf(acc[i][j][q] + bv, 0.f);
                    if (g < 0) continue;
                    if (g != gcur) {
                        if (gcur >= 0)
                            atomicMax((int*)&G[(size_t)gcur * Fout + gc], __float_as_int(vmax));
                        gcur = g;
                        vmax = vv;
                    } else {
                        vmax = fmaxf(vmax, vv);
                    }
                }
            }
            if (gcur >= 0) atomicMax((int*)&G[(size_t)gcur * Fout + gc], __float_as_int(vmax));
        }
    }
}

// ---------------- FC: LDS-staged A rows, column-tiled, unroll-8 W prefetch ----------------

__global__ __launch_bounds__(256) void k_fc_lds(const float* __restrict__ A,
                                                const float* __restrict__ W,
                                                const float* __restrict__ bias,
                                                float* __restrict__ C,
                                                int M, int K, int Nout, int CTF, int do_relu) {
    extern __shared__ float sA[];   // BM * K floats
    const int t = threadIdx.x;
    const int NV = CTF >> 2;        // float4 groups per row in this col tile
    const int BM = 256 / NV;        // rows per block
    const int m0 = blockIdx.x * BM;
    const int cb = blockIdx.y * CTF;

    for (int i = t; i < BM * K; i += 256) {
        int r = i / K, k = i - r * K;
        int gm = m0 + r;
        sA[i] = (gm < M) ? A[(size_t)gm * K + k] : 0.f;
    }
    __syncthreads();

    const int ml = t / NV;
    const int oc = cb + (t - ml * NV) * 4;
    const int m = m0 + ml;
    if (m >= M) return;
    const float* a = sA + (size_t)ml * K;

    float4 acc = *(const float4*)&bias[oc];
    const int KM = K & ~7;
    int k = 0;
    for (; k < KM; k += 8) {
        float4 w[8];
#pragma unroll
        for (int u = 0; u < 8; u++)
            w[u] = *(const float4*)&W[(size_t)(k + u) * Nout + oc];
#pragma unroll
        for (int u = 0; u < 8; u++) {
            float avv = a[k + u];
            acc.x = fmaf(avv, w[u].x, acc.x);
            acc.y = fmaf(avv, w[u].y, acc.y);
            acc.z = fmaf(avv, w[u].z, acc.z);
            acc.w = fmaf(avv, w[u].w, acc.w);
        }
    }
    for (; k < K; k++) {
        float4 wv = *(const float4*)&W[(size_t)k * Nout + oc];
        float avv = a[k];
        acc.x = fmaf(avv, wv.x, acc.x);
        acc.y = fmaf(avv, wv.y, acc.y);
        acc.z = fmaf(avv, wv.z, acc.z);
        acc.w = fmaf(avv, wv.w, acc.w);
    }
    if (do_relu) {
        acc.x = fmaxf(acc.x, 0.f);
        acc.y = fmaxf(acc.y, 0.f);
        acc.z = fmaxf(acc.z, 0.f);
        acc.w = fmaxf(acc.w, 0.f);
    }
    *(float4*)&C[(size_t)m * Nout + oc] = acc;
}

// ---------------- launch ----------------

extern "C" void kernel_launch(void* const* d_in, const int* in_sizes, int n_in,
                              void* d_out, int out_size, void* d_ws, size_t ws_size,
                              hipStream_t stream) {
    const float* x     = (const float*)d_in[0];
    const int*   ei    = (const int*)d_in[1];
    const int*   batch = (const int*)d_in[2];
    const float* W1 = (const float*)d_in[3];
    const float* b1 = (const float*)d_in[4];
    const float* W2 = (const float*)d_in[5];
    const float* b2 = (const float*)d_in[6];
    const float* W3 = (const float*)d_in[7];
    const float* b3 = (const float*)d_in[8];
    const float* Wg1 = (const float*)d_in[9];
    const float* bg1 = (const float*)d_in[10];
    const float* Wg2 = (const float*)d_in[11];
    const float* bg2 = (const float*)d_in[12];

    const int N  = in_sizes[2];          // 50000
    const int E  = in_sizes[1] / 2;      // 800000
    const int F1 = in_sizes[4];          // 75
    const int F2 = in_sizes[6];          // 150
    const int F3 = in_sizes[8];          // 300
    const int H1 = in_sizes[10];         // 1024
    const int OC = in_sizes[12];         // 128
    const int NG = out_size / OC;        // 256
    const int FIN = in_sizes[3] / F1;    // 75

    const int KP1 = 96,  KPf1 = 80;      // K=75 padded (GEMM loop / A stride)
    const int KP3 = 160, KPf3 = 152;     // K=150 padded
    const int HS1 = 76;                  // H1 row stride (19 float4)
    const int HS2 = 152;                 // H2 row stride (38 float4)

    const int* src = ei;
    const int* dst = ei + E;

    char* base = (char*)d_ws;
    size_t off = 0;
    auto alloc = [&](size_t bytes) -> void* {
        void* p = base + off;
        off = (off + bytes + 255) & ~(size_t)255;
        return p;
    };
    int*   cnt    = (int*)alloc((size_t)N * 4);
    int*   fill   = (int*)alloc((size_t)N * 4);
    int*   rowptr = (int*)alloc((size_t)(N + 1) * 4);
    float* dinv   = (float*)alloc((size_t)N * 4);
    int*   bsum   = (int*)alloc(256 * 4);
    int*   col    = (int*)alloc((size_t)E * 4);
    float* ew     = (float*)alloc((size_t)E * 4);
    unsigned short* W1th = (unsigned short*)alloc((size_t)F1 * KP1 * 2);
    unsigned short* W1tl = (unsigned short*)alloc((size_t)F1 * KP1 * 2);
    unsigned short* W2th = (unsigned short*)alloc((size_t)F2 * KP1 * 2);
    unsigned short* W2tl = (unsigned short*)alloc((size_t)F2 * KP1 * 2);
    unsigned short* W3th = (unsigned short*)alloc((size_t)F3 * KP3 * 2);
    unsigned short* W3tl = (unsigned short*)alloc((size_t)F3 * KP3 * 2);
    float* Gb  = (float*)alloc((size_t)NG * F3 * 4);
    float* g1  = (float*)alloc((size_t)NG * H1 * 4);
    float* Tg  = (float*)alloc((size_t)N * KPf3 * 4);          // 30.4 MB (covers stride-80 too)
    float* H1b = (float*)alloc((size_t)N * HS1 * 4);           // 15.2 MB
    float* H2b = (float*)alloc((size_t)N * HS2 * 4);           // 30.4 MB

    hipMemsetAsync(cnt, 0, (size_t)N * 4, stream);
    hipMemsetAsync(fill, 0, (size_t)N * 4, stream);
    hipMemsetAsync(Gb, 0, (size_t)NG * F3 * 4, stream);

    // ---- CSR ----
    k_count<<<ceil_div_i(E, 256), 256, 0, stream>>>(dst, E, cnt);
    k_dinv<<<ceil_div_i(N, 256), 256, 0, stream>>>(cnt, dinv, N);
    int NB = ceil_div_i(N, SCAN_B);
    k_scan1<<<NB, 256, 0, stream>>>(cnt, rowptr, bsum, N);
    k_scan2<<<1, 256, 0, stream>>>(bsum, NB);
    k_scan3<<<ceil_div_i(N, 256), 256, 0, stream>>>(rowptr, bsum, N, E);
    k_fill<<<ceil_div_i(E, 256), 256, 0, stream>>>(src, dst, E, rowptr, fill, dinv, col, ew);

    // ---- weight splits (tiny) ----
    k_wsplit<<<ceil_div_i((long long)F1 * KP1, 256), 256, 0, stream>>>(W1, W1th, W1tl, FIN, F1, KP1);
    k_wsplit<<<ceil_div_i((long long)F2 * KP1, 256), 256, 0, stream>>>(W2, W2th, W2tl, F1, F2, KP1);
    k_wsplit<<<ceil_div_i((long long)F3 * KP3, 256), 256, 0, stream>>>(W3, W3th, W3tl, F2, F3, KP3);

    dim3 blk(256);
    int gw = ceil_div_i(N, 4);
    int gx = ceil_div_i(N, 128);

    // conv1: gather x (stride 75, scalar 2-chunk, unroll 8) -> T stride 80
    k_gather_w<1, 2, 8><<<gw, blk, 0, stream>>>(x, rowptr, col, ew, dinv, Tg,
                                                N, FIN, FIN, KPf1);
    {
        dim3 g(gx, ceil_div_i(F1, 128));
        k_gemm_mfma<0><<<g, blk, 0, stream>>>(Tg, KPf1, W1th, W1tl, b1, H1b, HS1,
                                              nullptr, nullptr, N, KP1, F1);
    }
    // conv2: gather H1 (stride 76, float4 1-chunk, unroll 8) -> T stride 80
    k_gather_w<4, 1, 8><<<gw, blk, 0, stream>>>(H1b, rowptr, col, ew, dinv, Tg,
                                                N, HS1, HS1, KPf1);
    {
        dim3 g(gx, ceil_div_i(F2, 128));
        k_gemm_mfma<0><<<g, blk, 0, stream>>>(Tg, KPf1, W2th, W2tl, b2, H2b, HS2,
                                              nullptr, nullptr, N, KP1, F2);
    }
    // conv3: gather H2 (stride 152, float4 1-chunk, unroll 8) -> T stride 152
    k_gather_w<4, 1, 8><<<gw, blk, 0, stream>>>(H2b, rowptr, col, ew, dinv, Tg,
                                                N, HS2, HS2, KPf3);
    {
        dim3 g(gx, ceil_div_i(F3, 128));
        k_gemm_mfma<1><<<g, blk, 0, stream>>>(Tg, KPf3, W3th, W3tl, b3, nullptr, 0,
                                              batch, Gb, N, KP3, F3);
    }

    // fc_g1: col-tiled CTF=256 -> BM=4, grid (64, 4), LDS 4*300*4
    {
        int CTF = 256;
        int BM = 256 / (CTF / 4);
        dim3 g(ceil_div_i(NG, BM), H1 / CTF);
        size_t lds = (size_t)BM * F3 * 4;
        k_fc_lds<<<g, 256, lds, stream>>>(Gb, Wg1, bg1, g1, NG, F3, H1, CTF, 1);
    }
    // fc_g2: CTF=128 -> BM=8, grid (32, 1), LDS 32KB
    {
        int CTF = OC;
        int BM = 256 / (CTF / 4);
        dim3 g(ceil_div_i(NG, BM), OC / CTF);
        size_t lds = (size_t)BM * H1 * 4;
        k_fc_lds<<<g, 256, lds, stream>>>(g1, Wg2, bg2, (float*)d_out, NG, H1, OC, CTF, 0);
    }
}

// Round 9
// 418.381 us; speedup vs baseline: 3.7686x; 1.0562x over previous
//
#include <hip/hip_runtime.h>
#include <math.h>

#define SCAN_B 1024
#define LDST 40   // LDS row stride in bf16 elems (32 data + 8 pad)

typedef __attribute__((ext_vector_type(8))) short short8v;
typedef __attribute__((ext_vector_type(8))) unsigned short ushort8v;
typedef __attribute__((ext_vector_type(4))) float f32x4;

static inline int ceil_div_i(long long a, int b) { return (int)((a + b - 1) / b); }

__device__ __forceinline__ unsigned short f2bf(float x) {
    unsigned int u = __float_as_uint(x);
    u += 0x7fffu + ((u >> 16) & 1u);   // round-to-nearest-even
    return (unsigned short)(u >> 16);
}
__device__ __forceinline__ float bf2f(unsigned short h) {
    return __uint_as_float(((unsigned int)h) << 16);
}

// ---------------- CSR construction ----------------

__global__ __launch_bounds__(256) void k_count(const int* __restrict__ dst, int E,
                                               int* __restrict__ cnt) {
    int i = blockIdx.x * blockDim.x + threadIdx.x;
    if (i < E) atomicAdd(&cnt[dst[i]], 1);
}

__global__ __launch_bounds__(256) void k_dinv(const int* __restrict__ cnt,
                                              float* __restrict__ dinv, int N) {
    int i = blockIdx.x * blockDim.x + threadIdx.x;
    if (i < N) dinv[i] = (float)(1.0 / sqrt((double)(cnt[i] + 1)));
}

__global__ __launch_bounds__(256) void k_scan1(const int* __restrict__ cnt,
                                               int* __restrict__ rowptr,
                                               int* __restrict__ bsum, int N) {
    __shared__ int s[256];
    int tid = threadIdx.x;
    int base = blockIdx.x * SCAN_B + tid * 4;
    int a0 = (base + 0 < N) ? cnt[base + 0] : 0;
    int a1 = (base + 1 < N) ? cnt[base + 1] : 0;
    int a2 = (base + 2 < N) ? cnt[base + 2] : 0;
    int a3 = (base + 3 < N) ? cnt[base + 3] : 0;
    int tsum = a0 + a1 + a2 + a3;
    s[tid] = tsum;
    __syncthreads();
    for (int off = 1; off < 256; off <<= 1) {
        int val = 0;
        if (tid >= off) val = s[tid - off];
        __syncthreads();
        if (tid >= off) s[tid] += val;
        __syncthreads();
    }
    int texcl = s[tid] - tsum;
    if (tid == 255) bsum[blockIdx.x] = s[255];
    if (base + 0 < N) rowptr[base + 0] = texcl;
    if (base + 1 < N) rowptr[base + 1] = texcl + a0;
    if (base + 2 < N) rowptr[base + 2] = texcl + a0 + a1;
    if (base + 3 < N) rowptr[base + 3] = texcl + a0 + a1 + a2;
}

__global__ __launch_bounds__(256) void k_scan2(int* __restrict__ bsum, int NB) {
    __shared__ int s[256];
    int tid = threadIdx.x;
    int v = (tid < NB) ? bsum[tid] : 0;
    s[tid] = v;
    __syncthreads();
    for (int off = 1; off < 256; off <<= 1) {
        int val = 0;
        if (tid >= off) val = s[tid - off];
        __syncthreads();
        if (tid >= off) s[tid] += val;
        __syncthreads();
    }
    if (tid < NB) bsum[tid] = s[tid] - v;
}

__global__ __launch_bounds__(256) void k_scan3(int* __restrict__ rowptr,
                                               const int* __restrict__ bsum, int N, int E) {
    int i = blockIdx.x * blockDim.x + threadIdx.x;
    if (i < N) rowptr[i] += bsum[i >> 10];
    if (i == 0) rowptr[N] = E;
}

__global__ __launch_bounds__(256) void k_fill(const int* __restrict__ src,
                                              const int* __restrict__ dst, int E,
                                              const int* __restrict__ rowptr,
                                              int* __restrict__ fill,
                                              const float* __restrict__ dinv,
                                              int* __restrict__ col,
                                              float* __restrict__ ew) {
    int e = blockIdx.x * blockDim.x + threadIdx.x;
    if (e >= E) return;
    int s = src[e], d = dst[e];
    int pos = atomicAdd(&fill[d], 1);
    int idx = rowptr[d] + pos;
    col[idx] = s;
    ew[idx] = dinv[s] * dinv[d];
}

// ---------------- pad-copy x: [N,75] -> [N,76] f32 (col 75 = 0) ----------------

__global__ __launch_bounds__(256) void k_xpad(const float* __restrict__ x,
                                              float* __restrict__ xp, int N, int F, int XS) {
    int i = blockIdx.x * blockDim.x + threadIdx.x;
    int v = i / XS, c = i - v * XS;
    if (v >= N) return;
    xp[i] = (c < F) ? x[(size_t)v * F + c] : 0.f;
}

// ---------------- gather (wave-per-node, shfl edges, UNR in flight) ----------------
// T[v] = dinv^2*X[v] + sum ew*X[col].  BF16IN=0: f32 rows, VW=4. BF16IN=1: bf16 rows, VW=8.
// X row stride XS elems (incl. zero pads); T f32 rows stride KPf (zero-padded).

template <int BF16IN, int UNR>
__global__ __launch_bounds__(256) void k_gather_v(const void* __restrict__ Xv,
                                                  const int* __restrict__ rowptr,
                                                  const int* __restrict__ col,
                                                  const float* __restrict__ ew,
                                                  const float* __restrict__ dinv,
                                                  float* __restrict__ T, int N,
                                                  int XS, int KPf) {
    const int v = blockIdx.x * 4 + (threadIdx.x >> 6);
    const int lane = threadIdx.x & 63;
    if (v >= N) return;
    const float dv = dinv[v];
    const float s = dv * dv;
    constexpr int VW = BF16IN ? 8 : 4;
    const int f0 = lane * VW;
    const bool act = f0 < XS;
    const float* Xf = (const float*)Xv;
    const unsigned short* Xb = (const unsigned short*)Xv;

    float acc[VW];
#pragma unroll
    for (int u = 0; u < VW; u++) acc[u] = 0.f;
    if (act) {
        if (BF16IN) {
            ushort8v h = *(const ushort8v*)(Xb + (size_t)v * XS + f0);
#pragma unroll
            for (int u = 0; u < VW; u++) acc[u] = s * bf2f(h[u]);
        } else {
            f32x4 t4 = *(const f32x4*)(Xf + (size_t)v * XS + f0);
#pragma unroll
            for (int u = 0; u < VW; u++) acc[u] = s * t4[u];
        }
    }

    const int beg = rowptr[v], end = rowptr[v + 1];
    for (int jb = beg; jb < end; jb += 64) {
        const int nj = min(64, end - jb);
        int ec = 0;
        float ev = 0.f;
        if (lane < nj) {
            ec = col[jb + lane];
            ev = ew[jb + lane];
        }
        int e = 0;
        for (; e + UNR <= nj; e += UNR) {
            int c[UNR];
            float w[UNR];
#pragma unroll
            for (int u = 0; u < UNR; u++) {
                c[u] = __shfl(ec, e + u);
                w[u] = __shfl(ev, e + u);
            }
            if (BF16IN) {
                ushort8v xv[UNR];
#pragma unroll
                for (int u = 0; u < UNR; u++)
                    if (act) xv[u] = *(const ushort8v*)(Xb + (size_t)c[u] * XS + f0);
#pragma unroll
                for (int u = 0; u < UNR; u++)
                    if (act) {
#pragma unroll
                        for (int k = 0; k < VW; k++)
                            acc[k] = fmaf(w[u], bf2f(xv[u][k]), acc[k]);
                    }
            } else {
                f32x4 xv[UNR];
#pragma unroll
                for (int u = 0; u < UNR; u++)
                    if (act) xv[u] = *(const f32x4*)(Xf + (size_t)c[u] * XS + f0);
#pragma unroll
                for (int u = 0; u < UNR; u++)
                    if (act) {
#pragma unroll
                        for (int k = 0; k < VW; k++)
                            acc[k] = fmaf(w[u], xv[u][k], acc[k]);
                    }
            }
        }
        for (; e + 2 <= nj; e += 2) {
            int c0 = __shfl(ec, e), c1 = __shfl(ec, e + 1);
            float w0 = __shfl(ev, e), w1 = __shfl(ev, e + 1);
            if (act) {
                if (BF16IN) {
                    ushort8v x0 = *(const ushort8v*)(Xb + (size_t)c0 * XS + f0);
                    ushort8v x1 = *(const ushort8v*)(Xb + (size_t)c1 * XS + f0);
#pragma unroll
                    for (int k = 0; k < VW; k++) {
                        acc[k] = fmaf(w0, bf2f(x0[k]), acc[k]);
                        acc[k] = fmaf(w1, bf2f(x1[k]), acc[k]);
                    }
                } else {
                    f32x4 x0 = *(const f32x4*)(Xf + (size_t)c0 * XS + f0);
                    f32x4 x1 = *(const f32x4*)(Xf + (size_t)c1 * XS + f0);
#pragma unroll
                    for (int k = 0; k < VW; k++) {
                        acc[k] = fmaf(w0, x0[k], acc[k]);
                        acc[k] = fmaf(w1, x1[k], acc[k]);
                    }
                }
            }
        }
        if (e < nj) {
            int c0 = __shfl(ec, e);
            float w0 = __shfl(ev, e);
            if (act) {
                if (BF16IN) {
                    ushort8v x0 = *(const ushort8v*)(Xb + (size_t)c0 * XS + f0);
#pragma unroll
                    for (int k = 0; k < VW; k++) acc[k] = fmaf(w0, bf2f(x0[k]), acc[k]);
                } else {
                    f32x4 x0 = *(const f32x4*)(Xf + (size_t)c0 * XS + f0);
#pragma unroll
                    for (int k = 0; k < VW; k++) acc[k] = fmaf(w0, x0[k], acc[k]);
                }
            }
        }
    }

    if (f0 < KPf) {
        float* tv = T + (size_t)v * KPf + f0;
        f32x4 o0 = {acc[0], acc[1], acc[2], acc[3]};
        *(f32x4*)tv = o0;                         // inactive lanes write exact zeros
        if (VW == 8) {
            f32x4 o1 = {acc[4], acc[5], acc[6], acc[7]};
            *(f32x4*)(tv + 4) = o1;
        }
    }
}

// ---------------- W preprocess: transpose + split into bf16 hi/lo, k-padded to KP --------

__global__ __launch_bounds__(256) void k_wsplit(const float* __restrict__ W,
                                                unsigned short* __restrict__ Wth,
                                                unsigned short* __restrict__ Wtl,
                                                int K, int Fout, int KP) {
    int i = blockIdx.x * blockDim.x + threadIdx.x;
    if (i >= Fout * KP) return;
    int c = i / KP, k = i - c * KP;
    float w = (k < K) ? W[(size_t)k * Fout + c] : 0.f;
    unsigned short h = f2bf(w);
    Wth[i] = h;
    Wtl[i] = f2bf(w - bf2f(h));
}

// ---------------- split-bf16 MFMA GEMM: out = relu(A @ W + bias) ----------------
// 128x128 tile, 4 waves, mfma_f32_16x16x32_bf16; D = Al*Bh + Ah*Bl + Ah*Bh.
// MODE 0: store bf16 C (row stride CSbf, cols [Fout,CSbf) zeroed).
// MODE 1: fused relu + per-graph max pool via atomicMax (f32 G).

template <int MODE>
__global__ __launch_bounds__(256) void k_gemm_mfma(
    const float* __restrict__ A, int KPf,
    const unsigned short* __restrict__ Bth, const unsigned short* __restrict__ Btl,
    const float* __restrict__ bias, unsigned short* __restrict__ Cb, int CSbf,
    const int* __restrict__ batch, float* __restrict__ G,
    int N, int KP, int Fout) {
    __shared__ unsigned short sAh[128 * LDST];
    __shared__ unsigned short sAl[128 * LDST];
    __shared__ unsigned short sBh[128 * LDST];
    __shared__ unsigned short sBl[128 * LDST];
    __shared__ int sBatch[128];

    const int t = threadIdx.x;
    const int r0 = blockIdx.x * 128;
    const int c0 = blockIdx.y * 128;
    const int lane = t & 63;
    const int wv = t >> 6;
    const int wrow = (wv >> 1) * 64;
    const int wcol = (wv & 1) * 64;
    const int l15 = lane & 15;
    const int lk = (lane >> 4) * 8;
    const int nt = KP >> 5;

    const int srow = t >> 1;
    const int sseg = (t & 1) << 4;

    if (MODE == 1 && t < 128) sBatch[t] = (r0 + t < N) ? batch[r0 + t] : -1;

    const bool arow_ok = (r0 + srow) < N;
    const bool bcol_ok = (c0 + srow) < Fout;
    const float* aRow = A + (size_t)(r0 + srow) * KPf;
    const unsigned short* bhRow = Bth + (size_t)(c0 + srow) * KP;
    const unsigned short* blRow = Btl + (size_t)(c0 + srow) * KP;

    float av[16];
    ushort8v rbh0, rbh1, rbl0, rbl1;

    auto gload = [&](int kk) {
#pragma unroll
        for (int u = 0; u < 4; u++) {
            int gk = kk + sseg + u * 4;
            f32x4 f = {0.f, 0.f, 0.f, 0.f};
            if (arow_ok && gk < KPf) f = *(const f32x4*)&aRow[gk];
#pragma unroll
            for (int e = 0; e < 4; e++) av[u * 4 + e] = f[e];
        }
        if (bcol_ok) {
            const ushort8v* p = (const ushort8v*)&bhRow[kk + sseg];
            rbh0 = p[0];
            rbh1 = p[1];
            p = (const ushort8v*)&blRow[kk + sseg];
            rbl0 = p[0];
            rbl1 = p[1];
        } else {
#pragma unroll
            for (int e = 0; e < 8; e++) { rbh0[e] = 0; rbh1[e] = 0; rbl0[e] = 0; rbl1[e] = 0; }
        }
    };

    auto wlds = [&]() {
        int off = srow * LDST + sseg;
        ushort8v h0, h1, l0, l1;
#pragma unroll
        for (int e = 0; e < 8; e++) {
            unsigned short hh = f2bf(av[e]);
            h0[e] = hh;
            l0[e] = f2bf(av[e] - bf2f(hh));
        }
#pragma unroll
        for (int e = 0; e < 8; e++) {
            unsigned short hh = f2bf(av[8 + e]);
            h1[e] = hh;
            l1[e] = f2bf(av[8 + e] - bf2f(hh));
        }
        *(ushort8v*)&sAh[off] = h0;
        *(ushort8v*)&sAh[off + 8] = h1;
        *(ushort8v*)&sAl[off] = l0;
        *(ushort8v*)&sAl[off + 8] = l1;
        *(ushort8v*)&sBh[off] = rbh0;
        *(ushort8v*)&sBh[off + 8] = rbh1;
        *(ushort8v*)&sBl[off] = rbl0;
        *(ushort8v*)&sBl[off + 8] = rbl1;
    };

    f32x4 acc[4][4];
#pragma unroll
    for (int i = 0; i < 4; i++)
#pragma unroll
        for (int j = 0; j < 4; j++) acc[i][j] = (f32x4){0.f, 0.f, 0.f, 0.f};

    gload(0);
    for (int tc = 0; tc < nt; ++tc) {
        wlds();
        __syncthreads();
        if (tc + 1 < nt) gload((tc + 1) * 32);   // latency hides under MFMA below
        short8v ah[4], al[4];
#pragma unroll
        for (int i = 0; i < 4; i++) {
            int ro = (wrow + i * 16 + l15) * LDST + lk;
            ah[i] = *(const short8v*)&sAh[ro];
            al[i] = *(const short8v*)&sAl[ro];
        }
#pragma unroll
        for (int j = 0; j < 4; j++) {
            int co = (wcol + j * 16 + l15) * LDST + lk;
            short8v bh = *(const short8v*)&sBh[co];
            short8v bl = *(const short8v*)&sBl[co];
#pragma unroll
            for (int i = 0; i < 4; i++) {
                acc[i][j] = __builtin_amdgcn_mfma_f32_16x16x32_bf16(al[i], bh, acc[i][j], 0, 0, 0);
                acc[i][j] = __builtin_amdgcn_mfma_f32_16x16x32_bf16(ah[i], bl, acc[i][j], 0, 0, 0);
                acc[i][j] = __builtin_amdgcn_mfma_f32_16x16x32_bf16(ah[i], bh, acc[i][j], 0, 0, 0);
            }
        }
        __syncthreads();
    }

    // epilogue — C/D layout (m89-verified): col = lane&15, row = (lane>>4)*4 + reg
    if (MODE == 0) {
#pragma unroll
        for (int j = 0; j < 4; j++) {
            int gc = c0 + wcol + j * 16 + l15;
            if (gc >= CSbf) continue;
            float bv = (gc < Fout) ? bias[gc] : 0.f;
#pragma unroll
            for (int i = 0; i < 4; i++) {
                int rb = r0 + wrow + i * 16 + (lane >> 4) * 4;
#pragma unroll
                for (int q = 0; q < 4; q++) {
                    int gr = rb + q;
                    if (gr >= N) continue;
                    float vv = (gc < Fout) ? fmaxf(acc[i][j][q] + bv, 0.f) : 0.f;
                    Cb[(size_t)gr * CSbf + gc] = f2bf(vv);
                }
            }
        }
    } else {
#pragma unroll
        for (int j = 0; j < 4; j++) {
            int gc = c0 + wcol + j * 16 + l15;
            if (gc >= Fout) continue;
            float bv = bias[gc];
            int gcur = -1;
            float vmax = 0.f;
#pragma unroll
            for (int i = 0; i < 4; i++) {
                int lr = wrow + i * 16 + (lane >> 4) * 4;
#pragma unroll
                for (int q = 0; q < 4; q++) {
                    int g = sBatch[lr + q];
                    float vv = fmaxf(acc[i][j][q] + bv, 0.f);
                    if (g < 0) continue;
                    if (g != gcur) {
                        if (gcur >= 0)
                            atomicMax((int*)&G[(size_t)gcur * Fout + gc], __float_as_int(vmax));
                        gcur = g;
                        vmax = vv;
                    } else {
                        vmax = fmaxf(vmax, vv);
                    }
                }
            }
            if (gcur >= 0) atomicMax((int*)&G[(size_t)gcur * Fout + gc], __float_as_int(vmax));
        }
    }
}

// ---------------- FC: LDS-staged A rows, column-tiled, unroll-8 W prefetch ----------------

__global__ __launch_bounds__(256) void k_fc_lds(const float* __restrict__ A,
                                                const float* __restrict__ W,
                                                const float* __restrict__ bias,
                                                float* __restrict__ C,
                                                int M, int K, int Nout, int CTF, int do_relu) {
    extern __shared__ float sA[];   // BM * K floats
    const int t = threadIdx.x;
    const int NV = CTF >> 2;        // float4 groups per row in this col tile
    const int BM = 256 / NV;        // rows per block
    const int m0 = blockIdx.x * BM;
    const int cb = blockIdx.y * CTF;

    for (int i = t; i < BM * K; i += 256) {
        int r = i / K, k = i - r * K;
        int gm = m0 + r;
        sA[i] = (gm < M) ? A[(size_t)gm * K + k] : 0.f;
    }
    __syncthreads();

    const int ml = t / NV;
    const int oc = cb + (t - ml * NV) * 4;
    const int m = m0 + ml;
    if (m >= M) return;
    const float* a = sA + (size_t)ml * K;

    float4 acc = *(const float4*)&bias[oc];
    const int KM = K & ~7;
    int k = 0;
    for (; k < KM; k += 8) {
        float4 w[8];
#pragma unroll
        for (int u = 0; u < 8; u++)
            w[u] = *(const float4*)&W[(size_t)(k + u) * Nout + oc];
#pragma unroll
        for (int u = 0; u < 8; u++) {
            float avv = a[k + u];
            acc.x = fmaf(avv, w[u].x, acc.x);
            acc.y = fmaf(avv, w[u].y, acc.y);
            acc.z = fmaf(avv, w[u].z, acc.z);
            acc.w = fmaf(avv, w[u].w, acc.w);
        }
    }
    for (; k < K; k++) {
        float4 wv = *(const float4*)&W[(size_t)k * Nout + oc];
        float avv = a[k];
        acc.x = fmaf(avv, wv.x, acc.x);
        acc.y = fmaf(avv, wv.y, acc.y);
        acc.z = fmaf(avv, wv.z, acc.z);
        acc.w = fmaf(avv, wv.w, acc.w);
    }
    if (do_relu) {
        acc.x = fmaxf(acc.x, 0.f);
        acc.y = fmaxf(acc.y, 0.f);
        acc.z = fmaxf(acc.z, 0.f);
        acc.w = fmaxf(acc.w, 0.f);
    }
    *(float4*)&C[(size_t)m * Nout + oc] = acc;
}

// ---------------- launch ----------------

extern "C" void kernel_launch(void* const* d_in, const int* in_sizes, int n_in,
                              void* d_out, int out_size, void* d_ws, size_t ws_size,
                              hipStream_t stream) {
    const float* x     = (const float*)d_in[0];
    const int*   ei    = (const int*)d_in[1];
    const int*   batch = (const int*)d_in[2];
    const float* W1 = (const float*)d_in[3];
    const float* b1 = (const float*)d_in[4];
    const float* W2 = (const float*)d_in[5];
    const float* b2 = (const float*)d_in[6];
    const float* W3 = (const float*)d_in[7];
    const float* b3 = (const float*)d_in[8];
    const float* Wg1 = (const float*)d_in[9];
    const float* bg1 = (const float*)d_in[10];
    const float* Wg2 = (const float*)d_in[11];
    const float* bg2 = (const float*)d_in[12];

    const int N  = in_sizes[2];          // 50000
    const int E  = in_sizes[1] / 2;      // 800000
    const int F1 = in_sizes[4];          // 75
    const int F2 = in_sizes[6];          // 150
    const int F3 = in_sizes[8];          // 300
    const int H1 = in_sizes[10];         // 1024
    const int OC = in_sizes[12];         // 128
    const int NG = out_size / OC;        // 256
    const int FIN = in_sizes[3] / F1;    // 75

    const int KP1 = 96,  KPf1 = 80;      // K=75 padded (GEMM loop / A stride)
    const int KP3 = 160, KPf3 = 152;     // K=150 padded
    const int XSP = 76;                  // padded x stride (f32)
    const int HS1 = 80;                  // H1 bf16 row stride (10 x ushort8)
    const int HS2 = 152;                 // H2 bf16 row stride (19 x ushort8)

    const int* src = ei;
    const int* dst = ei + E;

    char* base = (char*)d_ws;
    size_t off = 0;
    auto alloc = [&](size_t bytes) -> void* {
        void* p = base + off;
        off = (off + bytes + 255) & ~(size_t)255;
        return p;
    };
    int*   cnt    = (int*)alloc((size_t)N * 4);
    int*   fill   = (int*)alloc((size_t)N * 4);
    int*   rowptr = (int*)alloc((size_t)(N + 1) * 4);
    float* dinv   = (float*)alloc((size_t)N * 4);
    int*   bsum   = (int*)alloc(256 * 4);
    int*   col    = (int*)alloc((size_t)E * 4);
    float* ew     = (float*)alloc((size_t)E * 4);
    unsigned short* W1th = (unsigned short*)alloc((size_t)F1 * KP1 * 2);
    unsigned short* W1tl = (unsigned short*)alloc((size_t)F1 * KP1 * 2);
    unsigned short* W2th = (unsigned short*)alloc((size_t)F2 * KP1 * 2);
    unsigned short* W2tl = (unsigned short*)alloc((size_t)F2 * KP1 * 2);
    unsigned short* W3th = (unsigned short*)alloc((size_t)F3 * KP3 * 2);
    unsigned short* W3tl = (unsigned short*)alloc((size_t)F3 * KP3 * 2);
    float* Gb  = (float*)alloc((size_t)NG * F3 * 4);
    float* g1  = (float*)alloc((size_t)NG * H1 * 4);
    float* Tg  = (float*)alloc((size_t)N * KPf3 * 4);            // 30.4 MB (covers stride-80)
    float* xp  = (float*)alloc((size_t)N * XSP * 4);             // 15.2 MB padded x
    unsigned short* H1b = (unsigned short*)alloc((size_t)N * HS1 * 2);  // 8 MB bf16
    unsigned short* H2b = (unsigned short*)alloc((size_t)N * HS2 * 2);  // 15.2 MB bf16

    hipMemsetAsync(cnt, 0, (size_t)N * 4, stream);
    hipMemsetAsync(fill, 0, (size_t)N * 4, stream);
    hipMemsetAsync(Gb, 0, (size_t)NG * F3 * 4, stream);

    // ---- CSR ----
    k_count<<<ceil_div_i(E, 256), 256, 0, stream>>>(dst, E, cnt);
    k_dinv<<<ceil_div_i(N, 256), 256, 0, stream>>>(cnt, dinv, N);
    int NB = ceil_div_i(N, SCAN_B);
    k_scan1<<<NB, 256, 0, stream>>>(cnt, rowptr, bsum, N);
    k_scan2<<<1, 256, 0, stream>>>(bsum, NB);
    k_scan3<<<ceil_div_i(N, 256), 256, 0, stream>>>(rowptr, bsum, N, E);
    k_fill<<<ceil_div_i(E, 256), 256, 0, stream>>>(src, dst, E, rowptr, fill, dinv, col, ew);

    // ---- weight splits + x pad-copy (small) ----
    k_wsplit<<<ceil_div_i((long long)F1 * KP1, 256), 256, 0, stream>>>(W1, W1th, W1tl, FIN, F1, KP1);
    k_wsplit<<<ceil_div_i((long long)F2 * KP1, 256), 256, 0, stream>>>(W2, W2th, W2tl, F1, F2, KP1);
    k_wsplit<<<ceil_div_i((long long)F3 * KP3, 256), 256, 0, stream>>>(W3, W3th, W3tl, F2, F3, KP3);
    k_xpad<<<ceil_div_i((long long)N * XSP, 256), 256, 0, stream>>>(x, xp, N, FIN, XSP);

    dim3 blk(256);
    int gw = ceil_div_i(N, 4);
    int gx = ceil_div_i(N, 128);

    // conv1: gather padded x (f32, float4/lane) -> Tg stride 80
    k_gather_v<0, 8><<<gw, blk, 0, stream>>>(xp, rowptr, col, ew, dinv, Tg, N, XSP, KPf1);
    {
        dim3 g(gx, ceil_div_i(F1, 128));
        k_gemm_mfma<0><<<g, blk, 0, stream>>>(Tg, KPf1, W1th, W1tl, b1, H1b, HS1,
                                              nullptr, nullptr, N, KP1, F1);
    }
    // conv2: gather H1 (bf16, ushort8/lane) -> Tg stride 80
    k_gather_v<1, 8><<<gw, blk, 0, stream>>>(H1b, rowptr, col, ew, dinv, Tg, N, HS1, KPf1);
    {
        dim3 g(gx, ceil_div_i(F2, 128));
        k_gemm_mfma<0><<<g, blk, 0, stream>>>(Tg, KPf1, W2th, W2tl, b2, H2b, HS2,
                                              nullptr, nullptr, N, KP1, F2);
    }
    // conv3: gather H2 (bf16) -> Tg stride 152; GEMM fused relu+pool
    k_gather_v<1, 8><<<gw, blk, 0, stream>>>(H2b, rowptr, col, ew, dinv, Tg, N, HS2, KPf3);
    {
        dim3 g(gx, ceil_div_i(F3, 128));
        k_gemm_mfma<1><<<g, blk, 0, stream>>>(Tg, KPf3, W3th, W3tl, b3, nullptr, 0,
                                              batch, Gb, N, KP3, F3);
    }

    // fc_g1: col-tiled CTF=256 -> BM=4, grid (64, 4), LDS 4*300*4
    {
        int CTF = 256;
        int BM = 256 / (CTF / 4);
        dim3 g(ceil_div_i(NG, BM), H1 / CTF);
        size_t lds = (size_t)BM * F3 * 4;
        k_fc_lds<<<g, 256, lds, stream>>>(Gb, Wg1, bg1, g1, NG, F3, H1, CTF, 1);
    }
    // fc_g2: CTF=128 -> BM=8, grid (32, 1), LDS 32KB
    {
        int CTF = OC;
        int BM = 256 / (CTF / 4);
        dim3 g(ceil_div_i(NG, BM), OC / CTF);
        size_t lds = (size_t)BM * H1 * 4;
        k_fc_lds<<<g, 256, lds, stream>>>(g1, Wg2, bg2, (float*)d_out, NG, H1, OC, CTF, 0);
    }
}

// Round 10
// 356.554 us; speedup vs baseline: 4.4221x; 1.1734x over previous
//
#include <hip/hip_runtime.h>
#include <math.h>

#define SCAN_B 1024
#define LDST 40   // LDS row stride in bf16 elems (32 data + 8 pad)

typedef __attribute__((ext_vector_type(8))) short short8v;
typedef __attribute__((ext_vector_type(8))) unsigned short ushort8v;
typedef __attribute__((ext_vector_type(4))) float f32x4;

static inline int ceil_div_i(long long a, int b) { return (int)((a + b - 1) / b); }

__device__ __forceinline__ unsigned short f2bf(float x) {
    unsigned int u = __float_as_uint(x);
    u += 0x7fffu + ((u >> 16) & 1u);   // round-to-nearest-even
    return (unsigned short)(u >> 16);
}
__device__ __forceinline__ float bf2f(unsigned short h) {
    return __uint_as_float(((unsigned int)h) << 16);
}

// ---------------- CSR construction ----------------

__global__ __launch_bounds__(256) void k_count(const int* __restrict__ dst, int E,
                                               int* __restrict__ cnt) {
    int i = blockIdx.x * blockDim.x + threadIdx.x;
    if (i < E) atomicAdd(&cnt[dst[i]], 1);
}

__global__ __launch_bounds__(256) void k_dinv(const int* __restrict__ cnt,
                                              float* __restrict__ dinv, int N) {
    int i = blockIdx.x * blockDim.x + threadIdx.x;
    if (i < N) dinv[i] = (float)(1.0 / sqrt((double)(cnt[i] + 1)));
}

__global__ __launch_bounds__(256) void k_scan1(const int* __restrict__ cnt,
                                               int* __restrict__ rowptr,
                                               int* __restrict__ bsum, int N) {
    __shared__ int s[256];
    int tid = threadIdx.x;
    int base = blockIdx.x * SCAN_B + tid * 4;
    int a0 = (base + 0 < N) ? cnt[base + 0] : 0;
    int a1 = (base + 1 < N) ? cnt[base + 1] : 0;
    int a2 = (base + 2 < N) ? cnt[base + 2] : 0;
    int a3 = (base + 3 < N) ? cnt[base + 3] : 0;
    int tsum = a0 + a1 + a2 + a3;
    s[tid] = tsum;
    __syncthreads();
    for (int off = 1; off < 256; off <<= 1) {
        int val = 0;
        if (tid >= off) val = s[tid - off];
        __syncthreads();
        if (tid >= off) s[tid] += val;
        __syncthreads();
    }
    int texcl = s[tid] - tsum;
    if (tid == 255) bsum[blockIdx.x] = s[255];
    if (base + 0 < N) rowptr[base + 0] = texcl;
    if (base + 1 < N) rowptr[base + 1] = texcl + a0;
    if (base + 2 < N) rowptr[base + 2] = texcl + a0 + a1;
    if (base + 3 < N) rowptr[base + 3] = texcl + a0 + a1 + a2;
}

__global__ __launch_bounds__(256) void k_scan2(int* __restrict__ bsum, int NB) {
    __shared__ int s[256];
    int tid = threadIdx.x;
    int v = (tid < NB) ? bsum[tid] : 0;
    s[tid] = v;
    __syncthreads();
    for (int off = 1; off < 256; off <<= 1) {
        int val = 0;
        if (tid >= off) val = s[tid - off];
        __syncthreads();
        if (tid >= off) s[tid] += val;
        __syncthreads();
    }
    if (tid < NB) bsum[tid] = s[tid] - v;
}

__global__ __launch_bounds__(256) void k_scan3(int* __restrict__ rowptr,
                                               const int* __restrict__ bsum, int N, int E) {
    int i = blockIdx.x * blockDim.x + threadIdx.x;
    if (i < N) rowptr[i] += bsum[i >> 10];
    if (i == 0) rowptr[N] = E;
}

__global__ __launch_bounds__(256) void k_fill(const int* __restrict__ src,
                                              const int* __restrict__ dst, int E,
                                              const int* __restrict__ rowptr,
                                              int* __restrict__ fill,
                                              const float* __restrict__ dinv,
                                              int* __restrict__ col,
                                              float* __restrict__ ew) {
    int e = blockIdx.x * blockDim.x + threadIdx.x;
    if (e >= E) return;
    int s = src[e], d = dst[e];
    int pos = atomicAdd(&fill[d], 1);
    int idx = rowptr[d] + pos;
    col[idx] = s;
    ew[idx] = dinv[s] * dinv[d];
}

// ---------------- pad-copy x: [N,75] -> [N,76] f32 (col 75 = 0) ----------------

__global__ __launch_bounds__(256) void k_xpad(const float* __restrict__ x,
                                              float* __restrict__ xp, int N, int F, int XS) {
    int i = blockIdx.x * blockDim.x + threadIdx.x;
    int v = i / XS, c = i - v * XS;
    if (v >= N) return;
    xp[i] = (c < F) ? x[(size_t)v * F + c] : 0.f;
}

// ---------------- gather: multi-edge slots per wave ----------------
// T[v] = dinv^2*X[v] + sum ew*X[col].  Lane = (slot, chunk): SLOTS edges processed
// simultaneously, CHUNKS lanes each covering VW elems. Cross-slot shfl reduce at end.
// BF16IN=1: bf16 rows (VW=8); else f32 rows (VW=4). XS = X row stride (elems).

template <int BF16IN, int CHUNKS, int SLOTS, int UNR>
__global__ __launch_bounds__(256) void k_gather_s(const void* __restrict__ Xv,
                                                  const int* __restrict__ rowptr,
                                                  const int* __restrict__ col,
                                                  const float* __restrict__ ew,
                                                  const float* __restrict__ dinv,
                                                  float* __restrict__ T, int N,
                                                  int XS, int KPf) {
    const int v = blockIdx.x * 4 + (threadIdx.x >> 6);
    const int lane = threadIdx.x & 63;
    if (v >= N) return;
    constexpr int VW = BF16IN ? 8 : 4;
    const int slot = lane / CHUNKS;
    const int chunk = lane - slot * CHUNKS;
    const bool act = lane < CHUNKS * SLOTS;
    const int f0 = chunk * VW;
    const float* Xf = (const float*)Xv;
    const unsigned short* Xb = (const unsigned short*)Xv;
    const float dv = dinv[v];
    const float s = dv * dv;

    float acc[VW];
#pragma unroll
    for (int u = 0; u < VW; u++) acc[u] = 0.f;
    if (slot == 0) {   // self term (slot-0 lanes cover all chunks)
        if (BF16IN) {
            ushort8v h = *(const ushort8v*)(Xb + (size_t)v * XS + f0);
#pragma unroll
            for (int u = 0; u < VW; u++) acc[u] = s * bf2f(h[u]);
        } else {
            f32x4 t4 = *(const f32x4*)(Xf + (size_t)v * XS + f0);
#pragma unroll
            for (int u = 0; u < VW; u++) acc[u] = s * t4[u];
        }
    }

    const int beg = rowptr[v], end = rowptr[v + 1];
    for (int jb = beg; jb < end; jb += 64) {
        const int nj = min(64, end - jb);
        int ec = 0;
        float emeta = 0.f;
        if (lane < nj) {
            ec = col[jb + lane];
            emeta = ew[jb + lane];
        }
        for (int e = 0; e < nj; e += SLOTS * UNR) {
            int cs[UNR];
            float ws[UNR];
            bool vs[UNR];
#pragma unroll
            for (int u = 0; u < UNR; u++) {
                int srcl = e + u * SLOTS + slot;
                vs[u] = act && (srcl < nj);
                int sl = srcl & 63;
                cs[u] = __shfl(ec, sl);
                ws[u] = __shfl(emeta, sl);
                if (!vs[u]) ws[u] = 0.f;
            }
            if (BF16IN) {
                ushort8v xv[UNR];
#pragma unroll
                for (int u = 0; u < UNR; u++) {
#pragma unroll
                    for (int k2 = 0; k2 < 8; k2++) xv[u][k2] = 0;
                    if (vs[u]) xv[u] = *(const ushort8v*)(Xb + (size_t)cs[u] * XS + f0);
                }
#pragma unroll
                for (int u = 0; u < UNR; u++)
#pragma unroll
                    for (int k2 = 0; k2 < VW; k2++)
                        acc[k2] = fmaf(ws[u], bf2f(xv[u][k2]), acc[k2]);
            } else {
                f32x4 xv[UNR];
#pragma unroll
                for (int u = 0; u < UNR; u++) {
                    xv[u] = (f32x4){0.f, 0.f, 0.f, 0.f};
                    if (vs[u]) xv[u] = *(const f32x4*)(Xf + (size_t)cs[u] * XS + f0);
                }
#pragma unroll
                for (int u = 0; u < UNR; u++)
#pragma unroll
                    for (int k2 = 0; k2 < VW; k2++)
                        acc[k2] = fmaf(ws[u], xv[u][k2], acc[k2]);
            }
        }
    }

    // reduce across slots (valid on slot 0)
#pragma unroll
    for (int k2 = 0; k2 < VW; k2++) {
        float t2 = acc[k2];
#pragma unroll
        for (int s2 = 1; s2 < SLOTS; s2++) t2 += __shfl(acc[k2], chunk + s2 * CHUNKS);
        acc[k2] = t2;
    }

    if (slot == 0 && f0 < KPf) {
        float* tv = T + (size_t)v * KPf + f0;
        f32x4 o0 = {acc[0], acc[1], acc[2], acc[3]};
        *(f32x4*)tv = o0;
        if (VW == 8) {
            f32x4 o1 = {acc[4], acc[5], acc[6], acc[7]};
            *(f32x4*)(tv + 4) = o1;
        }
    }
}

// ---------------- W preprocess: transpose + split into bf16 hi/lo, k-padded to KP --------

__global__ __launch_bounds__(256) void k_wsplit(const float* __restrict__ W,
                                                unsigned short* __restrict__ Wth,
                                                unsigned short* __restrict__ Wtl,
                                                int K, int Fout, int KP) {
    int i = blockIdx.x * blockDim.x + threadIdx.x;
    if (i >= Fout * KP) return;
    int c = i / KP, k = i - c * KP;
    float w = (k < K) ? W[(size_t)k * Fout + c] : 0.f;
    unsigned short h = f2bf(w);
    Wth[i] = h;
    Wtl[i] = f2bf(w - bf2f(h));
}

// ---------------- split-bf16 MFMA GEMM: out = relu(A @ W + bias) ----------------
// 128x128 tile, 4 waves, mfma_f32_16x16x32_bf16; D = Al*Bh + Ah*Bl + Ah*Bh.
// MODE 0: store bf16 C (row stride CSbf, cols [Fout,CSbf) zeroed).
// MODE 1: fused relu + per-graph max pool via atomicMax (f32 G).

template <int MODE>
__global__ __launch_bounds__(256) void k_gemm_mfma(
    const float* __restrict__ A, int KPf,
    const unsigned short* __restrict__ Bth, const unsigned short* __restrict__ Btl,
    const float* __restrict__ bias, unsigned short* __restrict__ Cb, int CSbf,
    const int* __restrict__ batch, float* __restrict__ G,
    int N, int KP, int Fout) {
    __shared__ unsigned short sAh[128 * LDST];
    __shared__ unsigned short sAl[128 * LDST];
    __shared__ unsigned short sBh[128 * LDST];
    __shared__ unsigned short sBl[128 * LDST];
    __shared__ int sBatch[128];

    const int t = threadIdx.x;
    const int r0 = blockIdx.x * 128;
    const int c0 = blockIdx.y * 128;
    const int lane = t & 63;
    const int wv = t >> 6;
    const int wrow = (wv >> 1) * 64;
    const int wcol = (wv & 1) * 64;
    const int l15 = lane & 15;
    const int lk = (lane >> 4) * 8;
    const int nt = KP >> 5;

    const int srow = t >> 1;
    const int sseg = (t & 1) << 4;

    if (MODE == 1 && t < 128) sBatch[t] = (r0 + t < N) ? batch[r0 + t] : -1;

    const bool arow_ok = (r0 + srow) < N;
    const bool bcol_ok = (c0 + srow) < Fout;
    const float* aRow = A + (size_t)(r0 + srow) * KPf;
    const unsigned short* bhRow = Bth + (size_t)(c0 + srow) * KP;
    const unsigned short* blRow = Btl + (size_t)(c0 + srow) * KP;

    float av[16];
    ushort8v rbh0, rbh1, rbl0, rbl1;

    auto gload = [&](int kk) {
#pragma unroll
        for (int u = 0; u < 4; u++) {
            int gk = kk + sseg + u * 4;
            f32x4 f = {0.f, 0.f, 0.f, 0.f};
            if (arow_ok && gk < KPf) f = *(const f32x4*)&aRow[gk];
#pragma unroll
            for (int e = 0; e < 4; e++) av[u * 4 + e] = f[e];
        }
        if (bcol_ok) {
            const ushort8v* p = (const ushort8v*)&bhRow[kk + sseg];
            rbh0 = p[0];
            rbh1 = p[1];
            p = (const ushort8v*)&blRow[kk + sseg];
            rbl0 = p[0];
            rbl1 = p[1];
        } else {
#pragma unroll
            for (int e = 0; e < 8; e++) { rbh0[e] = 0; rbh1[e] = 0; rbl0[e] = 0; rbl1[e] = 0; }
        }
    };

    auto wlds = [&]() {
        int off = srow * LDST + sseg;
        ushort8v h0, h1, l0, l1;
#pragma unroll
        for (int e = 0; e < 8; e++) {
            unsigned short hh = f2bf(av[e]);
            h0[e] = hh;
            l0[e] = f2bf(av[e] - bf2f(hh));
        }
#pragma unroll
        for (int e = 0; e < 8; e++) {
            unsigned short hh = f2bf(av[8 + e]);
            h1[e] = hh;
            l1[e] = f2bf(av[8 + e] - bf2f(hh));
        }
        *(ushort8v*)&sAh[off] = h0;
        *(ushort8v*)&sAh[off + 8] = h1;
        *(ushort8v*)&sAl[off] = l0;
        *(ushort8v*)&sAl[off + 8] = l1;
        *(ushort8v*)&sBh[off] = rbh0;
        *(ushort8v*)&sBh[off + 8] = rbh1;
        *(ushort8v*)&sBl[off] = rbl0;
        *(ushort8v*)&sBl[off + 8] = rbl1;
    };

    f32x4 acc[4][4];
#pragma unroll
    for (int i = 0; i < 4; i++)
#pragma unroll
        for (int j = 0; j < 4; j++) acc[i][j] = (f32x4){0.f, 0.f, 0.f, 0.f};

    gload(0);
    for (int tc = 0; tc < nt; ++tc) {
        wlds();
        __syncthreads();
        if (tc + 1 < nt) gload((tc + 1) * 32);   // latency hides under MFMA below
        short8v ah[4], al[4];
#pragma unroll
        for (int i = 0; i < 4; i++) {
            int ro = (wrow + i * 16 + l15) * LDST + lk;
            ah[i] = *(const short8v*)&sAh[ro];
            al[i] = *(const short8v*)&sAl[ro];
        }
#pragma unroll
        for (int j = 0; j < 4; j++) {
            int co = (wcol + j * 16 + l15) * LDST + lk;
            short8v bh = *(const short8v*)&sBh[co];
            short8v bl = *(const short8v*)&sBl[co];
#pragma unroll
            for (int i = 0; i < 4; i++) {
                acc[i][j] = __builtin_amdgcn_mfma_f32_16x16x32_bf16(al[i], bh, acc[i][j], 0, 0, 0);
                acc[i][j] = __builtin_amdgcn_mfma_f32_16x16x32_bf16(ah[i], bl, acc[i][j], 0, 0, 0);
                acc[i][j] = __builtin_amdgcn_mfma_f32_16x16x32_bf16(ah[i], bh, acc[i][j], 0, 0, 0);
            }
        }
        __syncthreads();
    }

    // epilogue — C/D layout (m89-verified): col = lane&15, row = (lane>>4)*4 + reg
    if (MODE == 0) {
#pragma unroll
        for (int j = 0; j < 4; j++) {
            int gc = c0 + wcol + j * 16 + l15;
            if (gc >= CSbf) continue;
            float bv = (gc < Fout) ? bias[gc] : 0.f;
#pragma unroll
            for (int i = 0; i < 4; i++) {
                int rb = r0 + wrow + i * 16 + (lane >> 4) * 4;
#pragma unroll
                for (int q = 0; q < 4; q++) {
                    int gr = rb + q;
                    if (gr >= N) continue;
                    float vv = (gc < Fout) ? fmaxf(acc[i][j][q] + bv, 0.f) : 0.f;
                    Cb[(size_t)gr * CSbf + gc] = f2bf(vv);
                }
            }
        }
    } else {
#pragma unroll
        for (int j = 0; j < 4; j++) {
            int gc = c0 + wcol + j * 16 + l15;
            if (gc >= Fout) continue;
            float bv = bias[gc];
            int gcur = -1;
            float vmax = 0.f;
#pragma unroll
            for (int i = 0; i < 4; i++) {
                int lr = wrow + i * 16 + (lane >> 4) * 4;
#pragma unroll
                for (int q = 0; q < 4; q++) {
                    int g = sBatch[lr + q];
                    float vv = fmaxf(acc[i][j][q] + bv, 0.f);
                    if (g < 0) continue;
                    if (g != gcur) {
                        if (gcur >= 0)
                            atomicMax((int*)&G[(size_t)gcur * Fout + gc], __float_as_int(vmax));
                        gcur = g;
                        vmax = vv;
                    } else {
                        vmax = fmaxf(vmax, vv);
                    }
                }
            }
            if (gcur >= 0) atomicMax((int*)&G[(size_t)gcur * Fout + gc], __float_as_int(vmax));
        }
    }
}

// ---------------- fc_g1: C[M,Nout] = relu(A@W + b); 2 rows x 256 cols per block ----------

__global__ __launch_bounds__(256) void k_fc1(const float* __restrict__ A,
                                             const float* __restrict__ W,
                                             const float* __restrict__ bias,
                                             float* __restrict__ C,
                                             int M, int K, int Nout) {
    __shared__ float sA[2 * 304];
    const int t = threadIdx.x;
    const int m0 = blockIdx.x * 2;
    const int oc = blockIdx.y * 256 + t;

    for (int i = t; i < 2 * K; i += 256) {
        int r = i / K, k = i - r * K;
        sA[r * 304 + k] = (m0 + r < M) ? A[(size_t)(m0 + r) * K + k] : 0.f;
    }
    __syncthreads();

    float acc0 = 0.f, acc1 = 0.f;
    int k = 0;
    for (; k + 8 <= K; k += 8) {
        float w[8];
#pragma unroll
        for (int u = 0; u < 8; u++) w[u] = W[(size_t)(k + u) * Nout + oc];
#pragma unroll
        for (int u = 0; u < 8; u++) {
            acc0 = fmaf(sA[k + u], w[u], acc0);
            acc1 = fmaf(sA[304 + k + u], w[u], acc1);
        }
    }
    for (; k < K; k++) {
        float w = W[(size_t)k * Nout + oc];
        acc0 = fmaf(sA[k], w, acc0);
        acc1 = fmaf(sA[304 + k], w, acc1);
    }
    float bv = bias[oc];
    if (m0 < M) C[(size_t)m0 * Nout + oc] = fmaxf(acc0 + bv, 0.f);
    if (m0 + 1 < M) C[(size_t)(m0 + 1) * Nout + oc] = fmaxf(acc1 + bv, 0.f);
}

// ---------------- fc_g2: split-K partial (KS=256) + deterministic reduce ----------------

__global__ __launch_bounds__(256) void k_fc2p(const float* __restrict__ A,
                                              const float* __restrict__ W,
                                              float* __restrict__ P,
                                              int M, int K, int Nout) {
    __shared__ float sA[2 * 256];
    const int t = threadIdx.x;
    const int m0 = blockIdx.x * 2;
    const int sk = blockIdx.y;
    const int k0 = sk * 256;
    const int row = t >> 7;
    const int oc = t & 127;

    for (int i = t; i < 2 * 256; i += 256) {
        int r = i >> 8, k = i & 255;
        sA[i] = (m0 + r < M) ? A[(size_t)(m0 + r) * K + k0 + k] : 0.f;
    }
    __syncthreads();

    const float* a = sA + row * 256;
    float acc = 0.f;
    for (int k = 0; k < 256; k += 8) {
        float w[8];
#pragma unroll
        for (int u = 0; u < 8; u++) w[u] = W[(size_t)(k0 + k + u) * Nout + oc];
#pragma unroll
        for (int u = 0; u < 8; u++) acc = fmaf(a[k + u], w[u], acc);
    }
    int m = m0 + row;
    if (m < M) P[((size_t)sk * M + m) * Nout + oc] = acc;
}

__global__ __launch_bounds__(256) void k_fc2r(const float* __restrict__ P,
                                              const float* __restrict__ bias,
                                              float* __restrict__ C,
                                              int M, int Nout, int SK) {
    int i = blockIdx.x * blockDim.x + threadIdx.x;
    if (i >= M * Nout) return;
    int oc = i % Nout;
    float acc = bias[oc];
    for (int s2 = 0; s2 < SK; s2++) acc += P[(size_t)s2 * M * Nout + i];
    C[i] = acc;
}

// ---------------- launch ----------------

extern "C" void kernel_launch(void* const* d_in, const int* in_sizes, int n_in,
                              void* d_out, int out_size, void* d_ws, size_t ws_size,
                              hipStream_t stream) {
    const float* x     = (const float*)d_in[0];
    const int*   ei    = (const int*)d_in[1];
    const int*   batch = (const int*)d_in[2];
    const float* W1 = (const float*)d_in[3];
    const float* b1 = (const float*)d_in[4];
    const float* W2 = (const float*)d_in[5];
    const float* b2 = (const float*)d_in[6];
    const float* W3 = (const float*)d_in[7];
    const float* b3 = (const float*)d_in[8];
    const float* Wg1 = (const float*)d_in[9];
    const float* bg1 = (const float*)d_in[10];
    const float* Wg2 = (const float*)d_in[11];
    const float* bg2 = (const float*)d_in[12];

    const int N  = in_sizes[2];          // 50000
    const int E  = in_sizes[1] / 2;      // 800000
    const int F1 = in_sizes[4];          // 75
    const int F2 = in_sizes[6];          // 150
    const int F3 = in_sizes[8];          // 300
    const int H1 = in_sizes[10];         // 1024
    const int OC = in_sizes[12];         // 128
    const int NG = out_size / OC;        // 256
    const int FIN = in_sizes[3] / F1;    // 75

    const int KP1 = 96,  KPf1 = 80;      // K=75 padded (GEMM loop / A stride)
    const int KP3 = 160, KPf3 = 152;     // K=150 padded
    const int XSP = 76;                  // padded x stride (f32): 19 x float4
    const int HS1 = 80;                  // H1 bf16 row stride: 10 x ushort8
    const int HS2 = 152;                 // H2 bf16 row stride: 19 x ushort8

    const int* src = ei;
    const int* dst = ei + E;

    char* base = (char*)d_ws;
    size_t off = 0;
    auto alloc = [&](size_t bytes) -> void* {
        void* p = base + off;
        off = (off + bytes + 255) & ~(size_t)255;
        return p;
    };
    int*   cnt    = (int*)alloc((size_t)N * 4);
    int*   fill   = (int*)alloc((size_t)N * 4);
    int*   rowptr = (int*)alloc((size_t)(N + 1) * 4);
    float* dinv   = (float*)alloc((size_t)N * 4);
    int*   bsum   = (int*)alloc(256 * 4);
    int*   col    = (int*)alloc((size_t)E * 4);
    float* ew     = (float*)alloc((size_t)E * 4);
    unsigned short* W1th = (unsigned short*)alloc((size_t)F1 * KP1 * 2);
    unsigned short* W1tl = (unsigned short*)alloc((size_t)F1 * KP1 * 2);
    unsigned short* W2th = (unsigned short*)alloc((size_t)F2 * KP1 * 2);
    unsigned short* W2tl = (unsigned short*)alloc((size_t)F2 * KP1 * 2);
    unsigned short* W3th = (unsigned short*)alloc((size_t)F3 * KP3 * 2);
    unsigned short* W3tl = (unsigned short*)alloc((size_t)F3 * KP3 * 2);
    float* Gb  = (float*)alloc((size_t)NG * F3 * 4);
    float* g1  = (float*)alloc((size_t)NG * H1 * 4);
    float* P2  = (float*)alloc((size_t)4 * NG * OC * 4);         // split-K partials
    float* Tg  = (float*)alloc((size_t)N * KPf3 * 4);            // 30.4 MB
    float* xp  = (float*)alloc((size_t)N * XSP * 4);             // 15.2 MB padded x
    unsigned short* H1b = (unsigned short*)alloc((size_t)N * HS1 * 2);  // 8 MB bf16
    unsigned short* H2b = (unsigned short*)alloc((size_t)N * HS2 * 2);  // 15.2 MB bf16

    hipMemsetAsync(cnt, 0, (size_t)N * 4, stream);
    hipMemsetAsync(fill, 0, (size_t)N * 4, stream);
    hipMemsetAsync(Gb, 0, (size_t)NG * F3 * 4, stream);

    // ---- CSR ----
    k_count<<<ceil_div_i(E, 256), 256, 0, stream>>>(dst, E, cnt);
    k_dinv<<<ceil_div_i(N, 256), 256, 0, stream>>>(cnt, dinv, N);
    int NB = ceil_div_i(N, SCAN_B);
    k_scan1<<<NB, 256, 0, stream>>>(cnt, rowptr, bsum, N);
    k_scan2<<<1, 256, 0, stream>>>(bsum, NB);
    k_scan3<<<ceil_div_i(N, 256), 256, 0, stream>>>(rowptr, bsum, N, E);
    k_fill<<<ceil_div_i(E, 256), 256, 0, stream>>>(src, dst, E, rowptr, fill, dinv, col, ew);

    // ---- weight splits + x pad-copy (small) ----
    k_wsplit<<<ceil_div_i((long long)F1 * KP1, 256), 256, 0, stream>>>(W1, W1th, W1tl, FIN, F1, KP1);
    k_wsplit<<<ceil_div_i((long long)F2 * KP1, 256), 256, 0, stream>>>(W2, W2th, W2tl, F1, F2, KP1);
    k_wsplit<<<ceil_div_i((long long)F3 * KP3, 256), 256, 0, stream>>>(W3, W3th, W3tl, F2, F3, KP3);
    k_xpad<<<ceil_div_i((long long)N * XSP, 256), 256, 0, stream>>>(x, xp, N, FIN, XSP);

    dim3 blk(256);
    int gw = ceil_div_i(N, 4);
    int gx = ceil_div_i(N, 128);

    // conv1: gather padded x (f32; 19 chunks x 3 slots) -> Tg stride 80
    k_gather_s<0, 19, 3, 4><<<gw, blk, 0, stream>>>(xp, rowptr, col, ew, dinv, Tg,
                                                    N, XSP, KPf1);
    {
        dim3 g(gx, ceil_div_i(F1, 128));
        k_gemm_mfma<0><<<g, blk, 0, stream>>>(Tg, KPf1, W1th, W1tl, b1, H1b, HS1,
                                              nullptr, nullptr, N, KP1, F1);
    }
    // conv2: gather H1 (bf16; 10 chunks x 6 slots) -> Tg stride 80
    k_gather_s<1, 10, 6, 2><<<gw, blk, 0, stream>>>(H1b, rowptr, col, ew, dinv, Tg,
                                                    N, HS1, KPf1);
    {
        dim3 g(gx, ceil_div_i(F2, 128));
        k_gemm_mfma<0><<<g, blk, 0, stream>>>(Tg, KPf1, W2th, W2tl, b2, H2b, HS2,
                                              nullptr, nullptr, N, KP1, F2);
    }
    // conv3: gather H2 (bf16; 19 chunks x 3 slots) -> Tg stride 152; fused relu+pool
    k_gather_s<1, 19, 3, 4><<<gw, blk, 0, stream>>>(H2b, rowptr, col, ew, dinv, Tg,
                                                    N, HS2, KPf3);
    {
        dim3 g(gx, ceil_div_i(F3, 128));
        k_gemm_mfma<1><<<g, blk, 0, stream>>>(Tg, KPf3, W3th, W3tl, b3, nullptr, 0,
                                              batch, Gb, N, KP3, F3);
    }

    // fc_g1: 2 rows x 256 cols per block -> grid (128, 4) = 512 blocks
    {
        dim3 g(ceil_div_i(NG, 2), H1 / 256);
        k_fc1<<<g, 256, 0, stream>>>(Gb, Wg1, bg1, g1, NG, F3, H1);
    }
    // fc_g2: split-K=4 partials (512 blocks) + deterministic reduce
    {
        dim3 g(ceil_div_i(NG, 2), 4);
        k_fc2p<<<g, 256, 0, stream>>>(g1, Wg2, P2, NG, H1, OC);
        k_fc2r<<<ceil_div_i((long long)NG * OC, 256), 256, 0, stream>>>(
            P2, bg2, (float*)d_out, NG, OC, 4);
    }
}

// Round 11
// 336.315 us; speedup vs baseline: 4.6882x; 1.0602x over previous
//
#include <hip/hip_runtime.h>
#include <math.h>

#define SCAN_B 1024
#define LDST 40   // LDS row stride in bf16 elems (32 data + 8 pad)

typedef __attribute__((ext_vector_type(8))) short short8v;
typedef __attribute__((ext_vector_type(8))) unsigned short ushort8v;
typedef __attribute__((ext_vector_type(4))) float f32x4;

static inline int ceil_div_i(long long a, int b) { return (int)((a + b - 1) / b); }

__device__ __forceinline__ unsigned short f2bf(float x) {
    unsigned int u = __float_as_uint(x);
    u += 0x7fffu + ((u >> 16) & 1u);   // round-to-nearest-even
    return (unsigned short)(u >> 16);
}
__device__ __forceinline__ float bf2f(unsigned short h) {
    return __uint_as_float(((unsigned int)h) << 16);
}

// ---------------- CSR construction ----------------

__global__ __launch_bounds__(256) void k_count(const int* __restrict__ dst, int E,
                                               int* __restrict__ cnt) {
    int i = blockIdx.x * blockDim.x + threadIdx.x;
    if (i < E) atomicAdd(&cnt[dst[i]], 1);
}

__global__ __launch_bounds__(256) void k_dinv(const int* __restrict__ cnt,
                                              float* __restrict__ dinv, int N) {
    int i = blockIdx.x * blockDim.x + threadIdx.x;
    if (i < N) dinv[i] = (float)(1.0 / sqrt((double)(cnt[i] + 1)));
}

__global__ __launch_bounds__(256) void k_scan1(const int* __restrict__ cnt,
                                               int* __restrict__ rowptr,
                                               int* __restrict__ bsum, int N) {
    __shared__ int s[256];
    int tid = threadIdx.x;
    int base = blockIdx.x * SCAN_B + tid * 4;
    int a0 = (base + 0 < N) ? cnt[base + 0] : 0;
    int a1 = (base + 1 < N) ? cnt[base + 1] : 0;
    int a2 = (base + 2 < N) ? cnt[base + 2] : 0;
    int a3 = (base + 3 < N) ? cnt[base + 3] : 0;
    int tsum = a0 + a1 + a2 + a3;
    s[tid] = tsum;
    __syncthreads();
    for (int off = 1; off < 256; off <<= 1) {
        int val = 0;
        if (tid >= off) val = s[tid - off];
        __syncthreads();
        if (tid >= off) s[tid] += val;
        __syncthreads();
    }
    int texcl = s[tid] - tsum;
    if (tid == 255) bsum[blockIdx.x] = s[255];
    if (base + 0 < N) rowptr[base + 0] = texcl;
    if (base + 1 < N) rowptr[base + 1] = texcl + a0;
    if (base + 2 < N) rowptr[base + 2] = texcl + a0 + a1;
    if (base + 3 < N) rowptr[base + 3] = texcl + a0 + a1 + a2;
}

__global__ __launch_bounds__(256) void k_scan2(int* __restrict__ bsum, int NB) {
    __shared__ int s[256];
    int tid = threadIdx.x;
    int v = (tid < NB) ? bsum[tid] : 0;
    s[tid] = v;
    __syncthreads();
    for (int off = 1; off < 256; off <<= 1) {
        int val = 0;
        if (tid >= off) val = s[tid - off];
        __syncthreads();
        if (tid >= off) s[tid] += val;
        __syncthreads();
    }
    if (tid < NB) bsum[tid] = s[tid] - v;
}

__global__ __launch_bounds__(256) void k_scan3(int* __restrict__ rowptr,
                                               const int* __restrict__ bsum, int N, int E) {
    int i = blockIdx.x * blockDim.x + threadIdx.x;
    if (i < N) rowptr[i] += bsum[i >> 10];
    if (i == 0) rowptr[N] = E;
}

// fill writes ONLY col (edge weights eliminated algebraically via dinv pre-scaling)
__global__ __launch_bounds__(256) void k_fill(const int* __restrict__ src,
                                              const int* __restrict__ dst, int E,
                                              const int* __restrict__ rowptr,
                                              int* __restrict__ fill,
                                              int* __restrict__ col) {
    int e = blockIdx.x * blockDim.x + threadIdx.x;
    if (e >= E) return;
    int s = src[e], d = dst[e];
    int pos = atomicAdd(&fill[d], 1);
    col[rowptr[d] + pos] = s;
}

// ---------------- scale+pad x -> bf16: Y[v][c] = bf16(dinv[v]*x[v][c]), stride XS ------

__global__ __launch_bounds__(256) void k_xscale(const float* __restrict__ x,
                                                const float* __restrict__ dinv,
                                                unsigned short* __restrict__ xb,
                                                int N, int F, int XS) {
    int i = blockIdx.x * blockDim.x + threadIdx.x;
    int v = i / XS, c = i - v * XS;
    if (v >= N) return;
    float val = (c < F) ? dinv[v] * x[(size_t)v * F + c] : 0.f;
    xb[i] = f2bf(val);
}

// ---------------- gather: S[v] = Y[v] + sum_j Y[col[j]]  (unweighted) ----------------
// Lane = (slot, chunk): SLOTS edges at once, CHUNKS lanes x 8 bf16 elems each.
// Cross-slot shfl reduce at end. X rows bf16 stride XS; T f32 rows stride KPf.

template <int CHUNKS, int SLOTS, int UNR>
__global__ __launch_bounds__(256) void k_gather_s(const unsigned short* __restrict__ Xb,
                                                  const int* __restrict__ rowptr,
                                                  const int* __restrict__ col,
                                                  float* __restrict__ T, int N,
                                                  int XS, int KPf) {
    const int v = blockIdx.x * 4 + (threadIdx.x >> 6);
    const int lane = threadIdx.x & 63;
    if (v >= N) return;
    constexpr int VW = 8;
    const int slot = lane / CHUNKS;
    const int chunk = lane - slot * CHUNKS;
    const bool act = lane < CHUNKS * SLOTS;
    const int f0 = chunk * VW;

    float acc[VW];
#pragma unroll
    for (int u = 0; u < VW; u++) acc[u] = 0.f;
    if (slot == 0) {   // self term, coefficient 1
        ushort8v h = *(const ushort8v*)(Xb + (size_t)v * XS + f0);
#pragma unroll
        for (int u = 0; u < VW; u++) acc[u] = bf2f(h[u]);
    }

    const int beg = rowptr[v], end = rowptr[v + 1];
    for (int jb = beg; jb < end; jb += 64) {
        const int nj = min(64, end - jb);
        int ec = 0;
        if (lane < nj) ec = col[jb + lane];
        for (int e = 0; e < nj; e += SLOTS * UNR) {
            int cs[UNR];
            bool vs[UNR];
#pragma unroll
            for (int u = 0; u < UNR; u++) {
                int srcl = e + u * SLOTS + slot;
                vs[u] = act && (srcl < nj);
                cs[u] = __shfl(ec, srcl & 63);
            }
            ushort8v xv[UNR];
#pragma unroll
            for (int u = 0; u < UNR; u++) {
#pragma unroll
                for (int k2 = 0; k2 < 8; k2++) xv[u][k2] = 0;
                if (vs[u]) xv[u] = *(const ushort8v*)(Xb + (size_t)cs[u] * XS + f0);
            }
#pragma unroll
            for (int u = 0; u < UNR; u++)
#pragma unroll
                for (int k2 = 0; k2 < VW; k2++)
                    acc[k2] += bf2f(xv[u][k2]);
        }
    }

    // reduce across slots (valid on slot 0)
#pragma unroll
    for (int k2 = 0; k2 < VW; k2++) {
        float t2 = acc[k2];
#pragma unroll
        for (int s2 = 1; s2 < SLOTS; s2++) t2 += __shfl(acc[k2], chunk + s2 * CHUNKS);
        acc[k2] = t2;
    }

    if (slot == 0 && f0 < KPf) {
        float* tv = T + (size_t)v * KPf + f0;
        f32x4 o0 = {acc[0], acc[1], acc[2], acc[3]};
        f32x4 o1 = {acc[4], acc[5], acc[6], acc[7]};
        *(f32x4*)tv = o0;
        *(f32x4*)(tv + 4) = o1;
    }
}

// ---------------- W preprocess: transpose + split into bf16 hi/lo, k-padded to KP --------

__global__ __launch_bounds__(256) void k_wsplit(const float* __restrict__ W,
                                                unsigned short* __restrict__ Wth,
                                                unsigned short* __restrict__ Wtl,
                                                int K, int Fout, int KP) {
    int i = blockIdx.x * blockDim.x + threadIdx.x;
    if (i >= Fout * KP) return;
    int c = i / KP, k = i - c * KP;
    float w = (k < K) ? W[(size_t)k * Fout + c] : 0.f;
    unsigned short h = f2bf(w);
    Wth[i] = h;
    Wtl[i] = f2bf(w - bf2f(h));
}

// ---------------- split-bf16 MFMA GEMM with row scaling ----------------
// X' = relu(dinv[row]*(S@W) + bias).
// MODE 0: store bf16 Y' = dinv[row]*X' (row stride CSbf, pad cols zeroed).
// MODE 1: per-graph max pool of X' via atomicMax (f32 G).

template <int MODE>
__global__ __launch_bounds__(256) void k_gemm_mfma(
    const float* __restrict__ A, int KPf,
    const unsigned short* __restrict__ Bth, const unsigned short* __restrict__ Btl,
    const float* __restrict__ bias, const float* __restrict__ dinvp,
    unsigned short* __restrict__ Cb, int CSbf,
    const int* __restrict__ batch, float* __restrict__ G,
    int N, int KP, int Fout) {
    __shared__ unsigned short sAh[128 * LDST];
    __shared__ unsigned short sAl[128 * LDST];
    __shared__ unsigned short sBh[128 * LDST];
    __shared__ unsigned short sBl[128 * LDST];
    __shared__ int sBatch[128];

    const int t = threadIdx.x;
    const int r0 = blockIdx.x * 128;
    const int c0 = blockIdx.y * 128;
    const int lane = t & 63;
    const int wv = t >> 6;
    const int wrow = (wv >> 1) * 64;
    const int wcol = (wv & 1) * 64;
    const int l15 = lane & 15;
    const int lk = (lane >> 4) * 8;
    const int nt = KP >> 5;

    const int srow = t >> 1;
    const int sseg = (t & 1) << 4;

    if (MODE == 1 && t < 128) sBatch[t] = (r0 + t < N) ? batch[r0 + t] : -1;

    const bool arow_ok = (r0 + srow) < N;
    const bool bcol_ok = (c0 + srow) < Fout;
    const float* aRow = A + (size_t)(r0 + srow) * KPf;
    const unsigned short* bhRow = Bth + (size_t)(c0 + srow) * KP;
    const unsigned short* blRow = Btl + (size_t)(c0 + srow) * KP;

    float av[16];
    ushort8v rbh0, rbh1, rbl0, rbl1;

    auto gload = [&](int kk) {
#pragma unroll
        for (int u = 0; u < 4; u++) {
            int gk = kk + sseg + u * 4;
            f32x4 f = {0.f, 0.f, 0.f, 0.f};
            if (arow_ok && gk < KPf) f = *(const f32x4*)&aRow[gk];
#pragma unroll
            for (int e = 0; e < 4; e++) av[u * 4 + e] = f[e];
        }
        if (bcol_ok) {
            const ushort8v* p = (const ushort8v*)&bhRow[kk + sseg];
            rbh0 = p[0];
            rbh1 = p[1];
            p = (const ushort8v*)&blRow[kk + sseg];
            rbl0 = p[0];
            rbl1 = p[1];
        } else {
#pragma unroll
            for (int e = 0; e < 8; e++) { rbh0[e] = 0; rbh1[e] = 0; rbl0[e] = 0; rbl1[e] = 0; }
        }
    };

    auto wlds = [&]() {
        int off = srow * LDST + sseg;
        ushort8v h0, h1, l0, l1;
#pragma unroll
        for (int e = 0; e < 8; e++) {
            unsigned short hh = f2bf(av[e]);
            h0[e] = hh;
            l0[e] = f2bf(av[e] - bf2f(hh));
        }
#pragma unroll
        for (int e = 0; e < 8; e++) {
            unsigned short hh = f2bf(av[8 + e]);
            h1[e] = hh;
            l1[e] = f2bf(av[8 + e] - bf2f(hh));
        }
        *(ushort8v*)&sAh[off] = h0;
        *(ushort8v*)&sAh[off + 8] = h1;
        *(ushort8v*)&sAl[off] = l0;
        *(ushort8v*)&sAl[off + 8] = l1;
        *(ushort8v*)&sBh[off] = rbh0;
        *(ushort8v*)&sBh[off + 8] = rbh1;
        *(ushort8v*)&sBl[off] = rbl0;
        *(ushort8v*)&sBl[off + 8] = rbl1;
    };

    f32x4 acc[4][4];
#pragma unroll
    for (int i = 0; i < 4; i++)
#pragma unroll
        for (int j = 0; j < 4; j++) acc[i][j] = (f32x4){0.f, 0.f, 0.f, 0.f};

    gload(0);
    for (int tc = 0; tc < nt; ++tc) {
        wlds();
        __syncthreads();
        if (tc + 1 < nt) gload((tc + 1) * 32);   // latency hides under MFMA below
        short8v ah[4], al[4];
#pragma unroll
        for (int i = 0; i < 4; i++) {
            int ro = (wrow + i * 16 + l15) * LDST + lk;
            ah[i] = *(const short8v*)&sAh[ro];
            al[i] = *(const short8v*)&sAl[ro];
        }
#pragma unroll
        for (int j = 0; j < 4; j++) {
            int co = (wcol + j * 16 + l15) * LDST + lk;
            short8v bh = *(const short8v*)&sBh[co];
            short8v bl = *(const short8v*)&sBl[co];
#pragma unroll
            for (int i = 0; i < 4; i++) {
                acc[i][j] = __builtin_amdgcn_mfma_f32_16x16x32_bf16(al[i], bh, acc[i][j], 0, 0, 0);
                acc[i][j] = __builtin_amdgcn_mfma_f32_16x16x32_bf16(ah[i], bl, acc[i][j], 0, 0, 0);
                acc[i][j] = __builtin_amdgcn_mfma_f32_16x16x32_bf16(ah[i], bh, acc[i][j], 0, 0, 0);
            }
        }
        __syncthreads();
    }

    // per-thread row scales (C/D layout: row = (lane>>4)*4 + q within 16-tile i)
    float drw[16];
#pragma unroll
    for (int i = 0; i < 4; i++)
#pragma unroll
        for (int q = 0; q < 4; q++) {
            int gr = r0 + wrow + i * 16 + (lane >> 4) * 4 + q;
            drw[i * 4 + q] = (gr < N) ? dinvp[gr] : 0.f;
        }

    if (MODE == 0) {
#pragma unroll
        for (int j = 0; j < 4; j++) {
            int gc = c0 + wcol + j * 16 + l15;
            if (gc >= CSbf) continue;
            float bv = (gc < Fout) ? bias[gc] : 0.f;
#pragma unroll
            for (int i = 0; i < 4; i++) {
                int rb = r0 + wrow + i * 16 + (lane >> 4) * 4;
#pragma unroll
                for (int q = 0; q < 4; q++) {
                    int gr = rb + q;
                    if (gr >= N) continue;
                    float dr = drw[i * 4 + q];
                    float vv = (gc < Fout) ? fmaxf(fmaf(acc[i][j][q], dr, bv), 0.f) * dr : 0.f;
                    Cb[(size_t)gr * CSbf + gc] = f2bf(vv);
                }
            }
        }
    } else {
#pragma unroll
        for (int j = 0; j < 4; j++) {
            int gc = c0 + wcol + j * 16 + l15;
            if (gc >= Fout) continue;
            float bv = bias[gc];
            int gcur = -1;
            float vmax = 0.f;
#pragma unroll
            for (int i = 0; i < 4; i++) {
                int lr = wrow + i * 16 + (lane >> 4) * 4;
#pragma unroll
                for (int q = 0; q < 4; q++) {
                    int g = sBatch[lr + q];
                    float vv = fmaxf(fmaf(acc[i][j][q], drw[i * 4 + q], bv), 0.f);
                    if (g < 0) continue;
                    if (g != gcur) {
                        if (gcur >= 0)
                            atomicMax((int*)&G[(size_t)gcur * Fout + gc], __float_as_int(vmax));
                        gcur = g;
                        vmax = vv;
                    } else {
                        vmax = fmaxf(vmax, vv);
                    }
                }
            }
            if (gcur >= 0) atomicMax((int*)&G[(size_t)gcur * Fout + gc], __float_as_int(vmax));
        }
    }
}

// ---------------- fc_g1: C[M,Nout] = relu(A@W + b); 2 rows x 256 cols per block ----------

__global__ __launch_bounds__(256) void k_fc1(const float* __restrict__ A,
                                             const float* __restrict__ W,
                                             const float* __restrict__ bias,
                                             float* __restrict__ C,
                                             int M, int K, int Nout) {
    __shared__ float sA[2 * 304];
    const int t = threadIdx.x;
    const int m0 = blockIdx.x * 2;
    const int oc = blockIdx.y * 256 + t;

    for (int i = t; i < 2 * K; i += 256) {
        int r = i / K, k = i - r * K;
        sA[r * 304 + k] = (m0 + r < M) ? A[(size_t)(m0 + r) * K + k] : 0.f;
    }
    __syncthreads();

    float acc0 = 0.f, acc1 = 0.f;
    int k = 0;
    for (; k + 8 <= K; k += 8) {
        float w[8];
#pragma unroll
        for (int u = 0; u < 8; u++) w[u] = W[(size_t)(k + u) * Nout + oc];
#pragma unroll
        for (int u = 0; u < 8; u++) {
            acc0 = fmaf(sA[k + u], w[u], acc0);
            acc1 = fmaf(sA[304 + k + u], w[u], acc1);
        }
    }
    for (; k < K; k++) {
        float w = W[(size_t)k * Nout + oc];
        acc0 = fmaf(sA[k], w, acc0);
        acc1 = fmaf(sA[304 + k], w, acc1);
    }
    float bv = bias[oc];
    if (m0 < M) C[(size_t)m0 * Nout + oc] = fmaxf(acc0 + bv, 0.f);
    if (m0 + 1 < M) C[(size_t)(m0 + 1) * Nout + oc] = fmaxf(acc1 + bv, 0.f);
}

// ---------------- fc_g2: split-K partial (KS=256) + deterministic reduce ----------------

__global__ __launch_bounds__(256) void k_fc2p(const float* __restrict__ A,
                                              const float* __restrict__ W,
                                              float* __restrict__ P,
                                              int M, int K, int Nout) {
    __shared__ float sA[2 * 256];
    const int t = threadIdx.x;
    const int m0 = blockIdx.x * 2;
    const int sk = blockIdx.y;
    const int k0 = sk * 256;
    const int row = t >> 7;
    const int oc = t & 127;

    for (int i = t; i < 2 * 256; i += 256) {
        int r = i >> 8, k = i & 255;
        sA[i] = (m0 + r < M) ? A[(size_t)(m0 + r) * K + k0 + k] : 0.f;
    }
    __syncthreads();

    const float* a = sA + row * 256;
    float acc = 0.f;
    for (int k = 0; k < 256; k += 8) {
        float w[8];
#pragma unroll
        for (int u = 0; u < 8; u++) w[u] = W[(size_t)(k0 + k + u) * Nout + oc];
#pragma unroll
        for (int u = 0; u < 8; u++) acc = fmaf(a[k + u], w[u], acc);
    }
    int m = m0 + row;
    if (m < M) P[((size_t)sk * M + m) * Nout + oc] = acc;
}

__global__ __launch_bounds__(256) void k_fc2r(const float* __restrict__ P,
                                              const float* __restrict__ bias,
                                              float* __restrict__ C,
                                              int M, int Nout, int SK) {
    int i = blockIdx.x * blockDim.x + threadIdx.x;
    if (i >= M * Nout) return;
    int oc = i % Nout;
    float acc = bias[oc];
    for (int s2 = 0; s2 < SK; s2++) acc += P[(size_t)s2 * M * Nout + i];
    C[i] = acc;
}

// ---------------- launch ----------------

extern "C" void kernel_launch(void* const* d_in, const int* in_sizes, int n_in,
                              void* d_out, int out_size, void* d_ws, size_t ws_size,
                              hipStream_t stream) {
    const float* x     = (const float*)d_in[0];
    const int*   ei    = (const int*)d_in[1];
    const int*   batch = (const int*)d_in[2];
    const float* W1 = (const float*)d_in[3];
    const float* b1 = (const float*)d_in[4];
    const float* W2 = (const float*)d_in[5];
    const float* b2 = (const float*)d_in[6];
    const float* W3 = (const float*)d_in[7];
    const float* b3 = (const float*)d_in[8];
    const float* Wg1 = (const float*)d_in[9];
    const float* bg1 = (const float*)d_in[10];
    const float* Wg2 = (const float*)d_in[11];
    const float* bg2 = (const float*)d_in[12];

    const int N  = in_sizes[2];          // 50000
    const int E  = in_sizes[1] / 2;      // 800000
    const int F1 = in_sizes[4];          // 75
    const int F2 = in_sizes[6];          // 150
    const int F3 = in_sizes[8];          // 300
    const int H1 = in_sizes[10];         // 1024
    const int OC = in_sizes[12];         // 128
    const int NG = out_size / OC;        // 256
    const int FIN = in_sizes[3] / F1;    // 75

    const int KP1 = 96,  KPf1 = 80;      // K=75 padded (GEMM loop / A stride)
    const int KP3 = 160, KPf3 = 152;     // K=150 padded
    const int XS0 = 80;                  // x bf16 (pre-scaled) row stride: 10 x ushort8
    const int HS1 = 80;                  // Y1 bf16 row stride
    const int HS2 = 152;                 // Y2 bf16 row stride

    const int* src = ei;
    const int* dst = ei + E;

    char* base = (char*)d_ws;
    size_t off = 0;
    auto alloc = [&](size_t bytes) -> void* {
        void* p = base + off;
        off = (off + bytes + 255) & ~(size_t)255;
        return p;
    };
    int*   cnt    = (int*)alloc((size_t)N * 4);
    int*   fill   = (int*)alloc((size_t)N * 4);
    int*   rowptr = (int*)alloc((size_t)(N + 1) * 4);
    float* dinv   = (float*)alloc((size_t)N * 4);
    int*   bsum   = (int*)alloc(256 * 4);
    int*   col    = (int*)alloc((size_t)E * 4);
    unsigned short* W1th = (unsigned short*)alloc((size_t)F1 * KP1 * 2);
    unsigned short* W1tl = (unsigned short*)alloc((size_t)F1 * KP1 * 2);
    unsigned short* W2th = (unsigned short*)alloc((size_t)F2 * KP1 * 2);
    unsigned short* W2tl = (unsigned short*)alloc((size_t)F2 * KP1 * 2);
    unsigned short* W3th = (unsigned short*)alloc((size_t)F3 * KP3 * 2);
    unsigned short* W3tl = (unsigned short*)alloc((size_t)F3 * KP3 * 2);
    float* Gb  = (float*)alloc((size_t)NG * F3 * 4);
    float* g1  = (float*)alloc((size_t)NG * H1 * 4);
    float* P2  = (float*)alloc((size_t)4 * NG * OC * 4);         // split-K partials
    float* Tg  = (float*)alloc((size_t)N * KPf3 * 4);            // 30.4 MB
    unsigned short* Xb  = (unsigned short*)alloc((size_t)N * XS0 * 2);  // 8 MB bf16 scaled x
    unsigned short* H1b = (unsigned short*)alloc((size_t)N * HS1 * 2);  // 8 MB bf16
    unsigned short* H2b = (unsigned short*)alloc((size_t)N * HS2 * 2);  // 15.2 MB bf16

    hipMemsetAsync(cnt, 0, (size_t)N * 4, stream);
    hipMemsetAsync(fill, 0, (size_t)N * 4, stream);
    hipMemsetAsync(Gb, 0, (size_t)NG * F3 * 4, stream);

    // ---- CSR ----
    k_count<<<ceil_div_i(E, 256), 256, 0, stream>>>(dst, E, cnt);
    k_dinv<<<ceil_div_i(N, 256), 256, 0, stream>>>(cnt, dinv, N);
    int NB = ceil_div_i(N, SCAN_B);
    k_scan1<<<NB, 256, 0, stream>>>(cnt, rowptr, bsum, N);
    k_scan2<<<1, 256, 0, stream>>>(bsum, NB);
    k_scan3<<<ceil_div_i(N, 256), 256, 0, stream>>>(rowptr, bsum, N, E);
    k_fill<<<ceil_div_i(E, 256), 256, 0, stream>>>(src, dst, E, rowptr, fill, col);

    // ---- weight splits + scaled-x (small) ----
    k_wsplit<<<ceil_div_i((long long)F1 * KP1, 256), 256, 0, stream>>>(W1, W1th, W1tl, FIN, F1, KP1);
    k_wsplit<<<ceil_div_i((long long)F2 * KP1, 256), 256, 0, stream>>>(W2, W2th, W2tl, F1, F2, KP1);
    k_wsplit<<<ceil_div_i((long long)F3 * KP3, 256), 256, 0, stream>>>(W3, W3th, W3tl, F2, F3, KP3);
    k_xscale<<<ceil_div_i((long long)N * XS0, 256), 256, 0, stream>>>(x, dinv, Xb, N, FIN, XS0);

    dim3 blk(256);
    int gw = ceil_div_i(N, 4);
    int gx = ceil_div_i(N, 128);

    // conv1: gather Xb (bf16; 10 chunks x 6 slots) -> Tg stride 80
    k_gather_s<10, 6, 2><<<gw, blk, 0, stream>>>(Xb, rowptr, col, Tg, N, XS0, KPf1);
    {
        dim3 g(gx, ceil_div_i(F1, 128));
        k_gemm_mfma<0><<<g, blk, 0, stream>>>(Tg, KPf1, W1th, W1tl, b1, dinv, H1b, HS1,
                                              nullptr, nullptr, N, KP1, F1);
    }
    // conv2: gather Y1 (bf16; 10 chunks x 6 slots) -> Tg stride 80
    k_gather_s<10, 6, 2><<<gw, blk, 0, stream>>>(H1b, rowptr, col, Tg, N, HS1, KPf1);
    {
        dim3 g(gx, ceil_div_i(F2, 128));
        k_gemm_mfma<0><<<g, blk, 0, stream>>>(Tg, KPf1, W2th, W2tl, b2, dinv, H2b, HS2,
                                              nullptr, nullptr, N, KP1, F2);
    }
    // conv3: gather Y2 (bf16; 19 chunks x 3 slots) -> Tg stride 152; fused relu+pool
    k_gather_s<19, 3, 4><<<gw, blk, 0, stream>>>(H2b, rowptr, col, Tg, N, HS2, KPf3);
    {
        dim3 g(gx, ceil_div_i(F3, 128));
        k_gemm_mfma<1><<<g, blk, 0, stream>>>(Tg, KPf3, W3th, W3tl, b3, dinv, nullptr, 0,
                                              batch, Gb, N, KP3, F3);
    }

    // fc_g1: 2 rows x 256 cols per block -> grid (128, 4) = 512 blocks
    {
        dim3 g(ceil_div_i(NG, 2), H1 / 256);
        k_fc1<<<g, 256, 0, stream>>>(Gb, Wg1, bg1, g1, NG, F3, H1);
    }
    // fc_g2: split-K=4 partials (512 blocks) + deterministic reduce
    {
        dim3 g(ceil_div_i(NG, 2), 4);
        k_fc2p<<<g, 256, 0, stream>>>(g1, Wg2, P2, NG, H1, OC);
        k_fc2r<<<ceil_div_i((long long)NG * OC, 256), 256, 0, stream>>>(
            P2, bg2, (float*)d_out, NG, OC, 4);
    }
}